// Round 2
// baseline (2551.744 us; speedup 1.0000x reference)
//
#include <hip/hip_runtime.h>
#include <hip/hip_bf16.h>

#define NN 4096
#define EE 16384
#define ET 20480   // EE + NN

typedef __hip_bfloat16 bf16;

__device__ __forceinline__ float warp_max(float v){
#pragma unroll
  for (int o = 32; o; o >>= 1) v = fmaxf(v, __shfl_xor(v, o));
  return v;
}
__device__ __forceinline__ float warp_sum(float v){
#pragma unroll
  for (int o = 32; o; o >>= 1) v += __shfl_xor(v, o);
  return v;
}

// ---------------- graph preprocessing ----------------

__global__ void k_deg_esum(const int* __restrict__ dst0, const float* __restrict__ eattr,
                           int* deg, float* esum){
  int e = blockIdx.x * 256 + threadIdx.x;
  if (e >= EE) return;
  int d = dst0[e];
  atomicAdd(&deg[d], 1);
  const float* ar = eattr + (size_t)e * 11;
  float* er = esum + (size_t)d * 11;
#pragma unroll
  for (int j = 0; j < 11; j++) atomicAdd(&er[j], ar[j]);
}

__global__ void k_loop_attr(const float* __restrict__ esum, const int* __restrict__ deg,
                            float* lattr){
  int n = blockIdx.x * 256 + threadIdx.x;
  if (n >= NN) return;
  float c = fmaxf((float)deg[n], 1.0f);
#pragma unroll
  for (int j = 0; j < 11; j++) lattr[n * 11 + j] = esum[n * 11 + j] / c;
}

// offsets = exclusive scan of (deg+1); one block of 256, 16 elems/thread
__global__ void k_scan(const int* __restrict__ deg, int* offsets){
  __shared__ int sums[256];
  int t = threadIdx.x;
  int base = t * 16;
  int vals[16];
  int s = 0;
#pragma unroll
  for (int j = 0; j < 16; j++){ vals[j] = s; s += deg[base + j] + 1; }
  sums[t] = s;
  __syncthreads();
  for (int off = 1; off < 256; off <<= 1){
    int v = (t >= off) ? sums[t - off] : 0;
    __syncthreads();
    sums[t] += v;
    __syncthreads();
  }
  int pre = (t == 0) ? 0 : sums[t - 1];
#pragma unroll
  for (int j = 0; j < 16; j++) offsets[base + j] = pre + vals[j];
  if (t == 255) offsets[NN] = sums[255];
}

__global__ void k_scatter(const int* __restrict__ src0, const int* __restrict__ dst0,
                          const int* __restrict__ offsets, int* cursor,
                          int* csr_src, int* csr_eid){
  int t = blockIdx.x * 256 + threadIdx.x;
  if (t < EE){
    int d = dst0[t];
    int pos = offsets[d] + atomicAdd(&cursor[d], 1);
    csr_src[pos] = src0[t];
    csr_eid[pos] = t;
  } else if (t < EE + NN){
    int n = t - EE;
    int pos = offsets[n + 1] - 1;   // last slot of segment reserved for self-loop
    csr_src[pos] = n;
    csr_eid[pos] = EE + n;
  }
}

// ---------------- folded attention weight vectors ----------------

__global__ void k_fold1(const float* __restrict__ W1, const float* __restrict__ as1,
                        const float* __restrict__ ad1, const float* __restrict__ We1,
                        const float* __restrict__ ae1,
                        float* wse1, float* wsd1, float* wee1){
  int t = blockIdx.x * 256 + threadIdx.x;
  if (t < 930){
    int k = t / 10, h = t % 10;
    const float* wr = W1 + (size_t)k * 5120 + h * 512;
    const float* asr = as1 + h * 512;
    const float* adr = ad1 + h * 512;
    float ss = 0, sd = 0;
    for (int c = 0; c < 512; c++){ float w = wr[c]; ss += w * asr[c]; sd += w * adr[c]; }
    wse1[t] = ss; wsd1[t] = sd;
  } else if (t < 1040){
    int u = t - 930;
    int k = u / 10, h = u % 10;
    const float* wr = We1 + (size_t)k * 5120 + h * 512;
    const float* aer = ae1 + h * 512;
    float se = 0;
    for (int c = 0; c < 512; c++) se += wr[c] * aer[c];
    wee1[u] = se;
  }
}

__global__ void k_fold2(const float* __restrict__ W2, const float* __restrict__ as2,
                        const float* __restrict__ ad2, const float* __restrict__ We2,
                        const float* __restrict__ ae2,
                        float* w2s, float* w2d, float* we2e){
  int t = blockIdx.x * 256 + threadIdx.x;
  if (t < 5120){
    const float* wr = W2 + (size_t)t * 512;
    float ss = 0, sd = 0;
    for (int c = 0; c < 512; c++){ float w = wr[c]; ss += w * as2[c]; sd += w * ad2[c]; }
    w2s[t] = ss; w2d[t] = sd;
  } else if (t < 5131){
    int k = t - 5120;
    const float* wr = We2 + (size_t)k * 512;
    float se = 0;
    for (int c = 0; c < 512; c++) se += wr[c] * ae2[c];
    we2e[k] = se;
  }
}

__global__ void k_logits1(const float* __restrict__ x1, const float* __restrict__ wse1,
                          const float* __restrict__ wsd1, float* S1, float* D1){
  int t = blockIdx.x * 256 + threadIdx.x;  // t < NN*10
  int n = t / 10, h = t % 10;
  const float* xr = x1 + (size_t)n * 93;
  float s = 0, d = 0;
  for (int k = 0; k < 93; k++){ float x = xr[k]; s += x * wse1[k * 10 + h]; d += x * wsd1[k * 10 + h]; }
  S1[t] = s; D1[t] = d;
}

// ---------------- GAT layer 1: per-(node,head) softmax + 93-wide aggregate ----------------

__global__ __launch_bounds__(256) void k_gat1(
    const int* __restrict__ offsets, const int* __restrict__ csr_src,
    const int* __restrict__ csr_eid, const float* __restrict__ eattr,
    const float* __restrict__ lattr, const float* __restrict__ S1,
    const float* __restrict__ D1, const float* __restrict__ wee1,
    const float* __restrict__ x1, float* __restrict__ xagg){
  int wid = (blockIdx.x * 256 + threadIdx.x) >> 6;   // (n*10+h)
  int lane = threadIdx.x & 63;
  int n = wid / 10, h = wid % 10;
  int start = offsets[n], end = offsets[n + 1];
  float dl = D1[wid];
  float wl[11];
#pragma unroll
  for (int j = 0; j < 11; j++) wl[j] = wee1[j * 10 + h];

  float m = -1e30f;
  for (int pos = start + lane; pos < end; pos += 64){
    int s = csr_src[pos]; int eid = csr_eid[pos];
    const float* ea = (eid < EE) ? eattr + (size_t)eid * 11 : lattr + (size_t)(eid - EE) * 11;
    float eel = 0;
#pragma unroll
    for (int j = 0; j < 11; j++) eel += ea[j] * wl[j];
    float lg = S1[s * 10 + h] + dl + eel;
    lg = lg > 0.f ? lg : 0.2f * lg;
    m = fmaxf(m, lg);
  }
  m = warp_max(m);

  float ps = 0;
  for (int pos = start + lane; pos < end; pos += 64){
    int s = csr_src[pos]; int eid = csr_eid[pos];
    const float* ea = (eid < EE) ? eattr + (size_t)eid * 11 : lattr + (size_t)(eid - EE) * 11;
    float eel = 0;
#pragma unroll
    for (int j = 0; j < 11; j++) eel += ea[j] * wl[j];
    float lg = S1[s * 10 + h] + dl + eel;
    lg = lg > 0.f ? lg : 0.2f * lg;
    ps += __expf(lg - m);
  }
  ps = warp_sum(ps);
  float inv = 1.0f / ps;

  float acc0 = 0, acc1 = 0;
  for (int pos = start; pos < end; pos++){
    int s = csr_src[pos]; int eid = csr_eid[pos];
    const float* ea = (eid < EE) ? eattr + (size_t)eid * 11 : lattr + (size_t)(eid - EE) * 11;
    float eel = 0;
#pragma unroll
    for (int j = 0; j < 11; j++) eel += ea[j] * wl[j];
    float lg = S1[s * 10 + h] + dl + eel;
    lg = lg > 0.f ? lg : 0.2f * lg;
    float alpha = __expf(lg - m) * inv;
    const float* xr = x1 + (size_t)s * 93;
    acc0 += alpha * xr[lane];
    if (lane < 29) acc1 += alpha * xr[64 + lane];
  }
  float* o = xagg + (size_t)wid * 93;
  o[lane] = acc0;
  if (lane < 29) o[64 + lane] = acc1;
}

// ---------------- layer-2 node logits (wave per node over 5120 dims) ----------------

__global__ __launch_bounds__(256) void k_logits2(const bf16* __restrict__ h1,
                                                 const float* __restrict__ w2s,
                                                 const float* __restrict__ w2d,
                                                 float* s2, float* d2){
  int wid = (blockIdx.x * 256 + threadIdx.x) >> 6;
  int lane = threadIdx.x & 63;
  const bf16* hr = h1 + (size_t)wid * 5120;
  float a = 0, b = 0;
  for (int k = lane; k < 5120; k += 64){
    float v = __bfloat162float(hr[k]);
    a += v * w2s[k]; b += v * w2d[k];
  }
  a = warp_sum(a); b = warp_sum(b);
  if (lane == 0){ s2[wid] = a; d2[wid] = b; }
}

// ---------------- GAT layer 2: softmax + 512-wide aggregate + alpha2 output ----------------

__global__ __launch_bounds__(256) void k_gat2(
    const int* __restrict__ offsets, const int* __restrict__ csr_src,
    const int* __restrict__ csr_eid, const float* __restrict__ eattr,
    const float* __restrict__ lattr, const float* __restrict__ s2,
    const float* __restrict__ d2, const float* __restrict__ we2e,
    const float* __restrict__ xs2, const float* __restrict__ b2,
    float* __restrict__ h2, float* __restrict__ alpha_out){
  int n = (blockIdx.x * 256 + threadIdx.x) >> 6;
  int lane = threadIdx.x & 63;
  int start = offsets[n], end = offsets[n + 1];
  float dl = d2[n];
  float wl[11];
#pragma unroll
  for (int j = 0; j < 11; j++) wl[j] = we2e[j];

  float m = -1e30f;
  for (int pos = start + lane; pos < end; pos += 64){
    int s = csr_src[pos]; int eid = csr_eid[pos];
    const float* ea = (eid < EE) ? eattr + (size_t)eid * 11 : lattr + (size_t)(eid - EE) * 11;
    float eel = 0;
#pragma unroll
    for (int j = 0; j < 11; j++) eel += ea[j] * wl[j];
    float lg = s2[s] + dl + eel;
    lg = lg > 0.f ? lg : 0.2f * lg;
    m = fmaxf(m, lg);
  }
  m = warp_max(m);

  float ps = 0;
  for (int pos = start + lane; pos < end; pos += 64){
    int s = csr_src[pos]; int eid = csr_eid[pos];
    const float* ea = (eid < EE) ? eattr + (size_t)eid * 11 : lattr + (size_t)(eid - EE) * 11;
    float eel = 0;
#pragma unroll
    for (int j = 0; j < 11; j++) eel += ea[j] * wl[j];
    float lg = s2[s] + dl + eel;
    lg = lg > 0.f ? lg : 0.2f * lg;
    ps += __expf(lg - m);
  }
  ps = warp_sum(ps);
  float inv = 1.0f / ps;

  float acc[8] = {0, 0, 0, 0, 0, 0, 0, 0};
  for (int pos = start; pos < end; pos++){
    int s = csr_src[pos]; int eid = csr_eid[pos];
    const float* ea = (eid < EE) ? eattr + (size_t)eid * 11 : lattr + (size_t)(eid - EE) * 11;
    float eel = 0;
#pragma unroll
    for (int j = 0; j < 11; j++) eel += ea[j] * wl[j];
    float lg = s2[s] + dl + eel;
    lg = lg > 0.f ? lg : 0.2f * lg;
    float alpha = __expf(lg - m) * inv;
    if (lane == 0) alpha_out[eid] = alpha;
    const float* xr = xs2 + (size_t)s * 512;
#pragma unroll
    for (int j = 0; j < 8; j++) acc[j] += alpha * xr[lane + j * 64];
  }
#pragma unroll
  for (int j = 0; j < 8; j++){
    int c = lane + j * 64;
    float v = acc[j] + b2[c];
    h2[(size_t)n * 512 + c] = v > 0.f ? v : (__expf(v) - 1.f);
  }
}

// ---------------- generic tiled f32 GEMM: C = act(A@B + bias + res) ----------------
// BM=128, BN=64, BK=16, 256 threads, 8x4 micro-tile.

__device__ __forceinline__ float ldA_elem(float v){ return v; }
__device__ __forceinline__ float ldA_elem(bf16 v){ return __bfloat162float(v); }
__device__ __forceinline__ void stC_elem(float* p, float v){ *p = v; }
__device__ __forceinline__ void stC_elem(bf16* p, float v){ *p = __float2bfloat16(v); }

template <typename TA, typename TC, int ACT>   // ACT: 0 none, 1 relu, 2 elu
__global__ __launch_bounds__(256) void k_gemm(
    const TA* __restrict__ A, const float* __restrict__ B,
    const float* __restrict__ bias, const float* __restrict__ res,
    TC* __restrict__ C, int M, int Nn, int K,
    int lda, int ldb, int ldc, int ldr,
    long aZ, long bZ, long cZ, long biasZ){
  __shared__ float As[16][128];
  __shared__ float Bs[16][64];
  int z = blockIdx.z;
  A += (size_t)z * aZ;
  B += (size_t)z * bZ;
  C += (size_t)z * cZ;
  const float* biasp = bias ? bias + (size_t)z * biasZ : nullptr;

  int bm = blockIdx.y * 128, bn = blockIdx.x * 64;
  int tid = threadIdx.x;
  int tx = tid & 15, ty = tid >> 4;
  float acc[8][4] = {};

  for (int k0 = 0; k0 < K; k0 += 16){
    {
      int r = tid >> 1;
      int cb = (tid & 1) * 8;
      int gm = bm + r;
#pragma unroll
      for (int j = 0; j < 8; j++){
        int gk = k0 + cb + j;
        float v = 0.f;
        if (gm < M && gk < K) v = ldA_elem(A[(size_t)gm * lda + gk]);
        As[cb + j][r] = v;
      }
    }
    {
      int r = tid >> 4;
      int cb = (tid & 15) * 4;
      int gk = k0 + r;
#pragma unroll
      for (int j = 0; j < 4; j++){
        int gn = bn + cb + j;
        float v = 0.f;
        if (gk < K && gn < Nn) v = B[(size_t)gk * ldb + gn];
        Bs[r][cb + j] = v;
      }
    }
    __syncthreads();
#pragma unroll
    for (int kk = 0; kk < 16; kk++){
      float4 a0 = *(const float4*)&As[kk][ty * 8];
      float4 a1 = *(const float4*)&As[kk][ty * 8 + 4];
      float4 b0 = *(const float4*)&Bs[kk][tx * 4];
      float av[8] = {a0.x, a0.y, a0.z, a0.w, a1.x, a1.y, a1.z, a1.w};
      float bv[4] = {b0.x, b0.y, b0.z, b0.w};
#pragma unroll
      for (int i = 0; i < 8; i++)
#pragma unroll
        for (int j = 0; j < 4; j++) acc[i][j] += av[i] * bv[j];
    }
    __syncthreads();
  }

#pragma unroll
  for (int i = 0; i < 8; i++){
    int gm = bm + ty * 8 + i;
    if (gm >= M) continue;
#pragma unroll
    for (int j = 0; j < 4; j++){
      int gn = bn + tx * 4 + j;
      if (gn >= Nn) continue;
      float v = acc[i][j];
      if (biasp) v += biasp[gn];
      if (res) v += res[(size_t)gm * ldr + gn];
      if (ACT == 1) v = fmaxf(v, 0.f);
      if (ACT == 2) v = v > 0.f ? v : (__expf(v) - 1.f);
      stC_elem(&C[(size_t)gm * ldc + gn], v);
    }
  }
}

// ---------------- misc: bvo fold, layernorm, pool ----------------

__global__ void k_bvo(const float* __restrict__ in_b, const float* __restrict__ out_w,
                      const float* __restrict__ out_b, float* bvo){
  int t = blockIdx.x * 256 + threadIdx.x;
  if (t >= 1024) return;
  int i = t >> 9, c = t & 511;
  const float* ib = in_b + i * 1536 + 1024;
  const float* ow = out_w + (size_t)i * 262144;
  float s = out_b[i * 512 + c];
  for (int k = 0; k < 512; k++) s += ib[k] * ow[(size_t)k * 512 + c];
  bvo[t] = s;
}

__global__ __launch_bounds__(256) void k_ln(const float* __restrict__ x,
                                            const float* __restrict__ g,
                                            const float* __restrict__ b,
                                            float* __restrict__ y){
  int wid = (blockIdx.x * 256 + threadIdx.x) >> 6;
  int lane = threadIdx.x & 63;
  const float* xr = x + (size_t)wid * 512;
  float v[8];
  float s = 0;
#pragma unroll
  for (int j = 0; j < 8; j++){ v[j] = xr[lane + j * 64]; s += v[j]; }
  s = warp_sum(s);
  float mu = s * (1.0f / 512.0f);
  float var = 0;
#pragma unroll
  for (int j = 0; j < 8; j++){ float d = v[j] - mu; var += d * d; }
  var = warp_sum(var) * (1.0f / 512.0f);
  float inv = rsqrtf(var + 1e-5f);
  float* yr = y + (size_t)wid * 512;
#pragma unroll
  for (int j = 0; j < 8; j++){
    int c = lane + j * 64;
    yr[c] = (v[j] - mu) * inv * g[c] + b[c];
  }
}

__global__ void k_pool(const float* __restrict__ h, float* __restrict__ out){
  int b = blockIdx.x;
  int c = threadIdx.x;   // 512 threads
  const float* hr = h + (size_t)b * 64 * 512;
  float m = -1e30f;
  for (int i = 0; i < 64; i++) m = fmaxf(m, hr[i * 512 + c]);
  out[(size_t)b * 512 + c] = m;
}

// ---------------- launcher ----------------

extern "C" void kernel_launch(void* const* d_in, const int* in_sizes, int n_in,
                              void* d_out, int out_size, void* d_ws, size_t ws_size,
                              hipStream_t stream){
  const float* x1    = (const float*)d_in[0];
  const int*   ei    = (const int*)d_in[1];
  const float* eattr = (const float*)d_in[2];
  const float* W1    = (const float*)d_in[4];
  const float* as1   = (const float*)d_in[5];
  const float* ad1   = (const float*)d_in[6];
  const float* We1   = (const float*)d_in[7];
  const float* ae1   = (const float*)d_in[8];
  const float* b1    = (const float*)d_in[9];
  const float* W2    = (const float*)d_in[10];
  const float* as2   = (const float*)d_in[11];
  const float* ad2   = (const float*)d_in[12];
  const float* We2   = (const float*)d_in[13];
  const float* ae2   = (const float*)d_in[14];
  const float* b2    = (const float*)d_in[15];
  const float* in_w  = (const float*)d_in[16];
  const float* in_b  = (const float*)d_in[17];
  const float* out_w = (const float*)d_in[18];
  const float* out_b = (const float*)d_in[19];
  const float* ln1g  = (const float*)d_in[20];
  const float* ln1b  = (const float*)d_in[21];
  const float* f1w   = (const float*)d_in[22];
  const float* f1b   = (const float*)d_in[23];
  const float* f2w   = (const float*)d_in[24];
  const float* f2b   = (const float*)d_in[25];
  const float* ln2g  = (const float*)d_in[26];
  const float* ln2b  = (const float*)d_in[27];

  const int* src0 = ei;
  const int* dst0 = ei + EE;

  char* p = (char*)d_ws;
  auto alloc = [&](size_t bytes) -> void* {
    void* r = p;
    p += (bytes + 255) & ~(size_t)255;
    return r;
  };
  float* esum    = (float*)alloc(NN * 11 * 4);
  float* lattr   = (float*)alloc(NN * 11 * 4);
  int*   deg     = (int*)alloc(NN * 4);
  int*   offsets = (int*)alloc((NN + 1) * 4);
  int*   cursor  = (int*)alloc(NN * 4);
  int*   csr_src = (int*)alloc(ET * 4);
  int*   csr_eid = (int*)alloc(ET * 4);
  float* wse1    = (float*)alloc(930 * 4);
  float* wsd1    = (float*)alloc(930 * 4);
  float* wee1    = (float*)alloc(110 * 4);
  float* S1      = (float*)alloc(NN * 10 * 4);
  float* D1b     = (float*)alloc(NN * 10 * 4);
  float* xagg    = (float*)alloc((size_t)NN * 10 * 93 * 4);
  bf16*  h1      = (bf16*)alloc((size_t)NN * 5120 * 2);
  float* w2s     = (float*)alloc(5120 * 4);
  float* w2d     = (float*)alloc(5120 * 4);
  float* we2e    = (float*)alloc(16 * 4);
  float* s2      = (float*)alloc(NN * 4);
  float* d2v     = (float*)alloc(NN * 4);
  float* xs2     = (float*)alloc((size_t)NN * 512 * 4);
  float* h2      = (float*)alloc((size_t)NN * 512 * 4);
  float* tmp     = (float*)alloc((size_t)NN * 512 * 4);
  bf16*  fbuf    = (bf16*)alloc((size_t)NN * 2048 * 2);
  float* Wvo     = (float*)alloc((size_t)2 * 512 * 512 * 4);
  float* bvo     = (float*)alloc(2 * 512 * 4);

  float* out_pool = (float*)d_out;
  float* alpha2   = out_pool + 64 * 512;

  hipMemsetAsync(deg, 0, NN * 4, stream);
  hipMemsetAsync(esum, 0, NN * 11 * 4, stream);
  hipMemsetAsync(cursor, 0, NN * 4, stream);

  k_deg_esum<<<EE / 256, 256, 0, stream>>>(dst0, eattr, deg, esum);
  k_loop_attr<<<NN / 256, 256, 0, stream>>>(esum, deg, lattr);
  k_scan<<<1, 256, 0, stream>>>(deg, offsets);
  k_scatter<<<(EE + NN) / 256, 256, 0, stream>>>(src0, dst0, offsets, cursor, csr_src, csr_eid);
  k_fold1<<<5, 256, 0, stream>>>(W1, as1, ad1, We1, ae1, wse1, wsd1, wee1);
  k_fold2<<<21, 256, 0, stream>>>(W2, as2, ad2, We2, ae2, w2s, w2d, we2e);
  k_logits1<<<160, 256, 0, stream>>>(x1, wse1, wsd1, S1, D1b);
  k_gat1<<<(NN * 10) / 4, 256, 0, stream>>>(offsets, csr_src, csr_eid, eattr, lattr,
                                            S1, D1b, wee1, x1, xagg);
  // h1 = elu(xagg @ W1_head + b1), batched over 10 heads
  k_gemm<float, bf16, 2><<<dim3(8, 32, 10), 256, 0, stream>>>(
      xagg, W1, b1, nullptr, h1, NN, 512, 93, 930, 5120, 5120, 0, 93, 512, 512, 512);
  k_logits2<<<NN / 4, 256, 0, stream>>>(h1, w2s, w2d, s2, d2v);
  // xs2 = h1 @ W2
  k_gemm<bf16, float, 0><<<dim3(8, 32, 1), 256, 0, stream>>>(
      h1, W2, nullptr, nullptr, xs2, NN, 512, 5120, 5120, 512, 512, 0, 0, 0, 0, 0);
  k_gat2<<<NN / 4, 256, 0, stream>>>(offsets, csr_src, csr_eid, eattr, lattr,
                                     s2, d2v, we2e, xs2, b2, h2, alpha2);
  // Wvo[i] = in_w[i][:,2D:] @ out_w[i]
  k_gemm<float, float, 0><<<dim3(8, 4, 2), 256, 0, stream>>>(
      in_w + 1024, out_w, nullptr, nullptr, Wvo, 512, 512, 512, 1536, 512, 512, 0,
      786432, 262144, 262144, 0);
  k_bvo<<<4, 256, 0, stream>>>(in_b, out_w, out_b, bvo);

  for (int i = 0; i < 2; i++){
    // tmp = h2 + h2 @ Wvo + bvo
    k_gemm<float, float, 0><<<dim3(8, 32, 1), 256, 0, stream>>>(
        h2, Wvo + (size_t)i * 262144, bvo + i * 512, h2, tmp,
        NN, 512, 512, 512, 512, 512, 512, 0, 0, 0, 0);
    k_ln<<<NN / 4, 256, 0, stream>>>(tmp, ln1g + i * 512, ln1b + i * 512, h2);
    // fbuf = relu(h2 @ f1w + f1b)
    k_gemm<float, bf16, 1><<<dim3(32, 32, 1), 256, 0, stream>>>(
        h2, f1w + (size_t)i * 512 * 2048, f1b + i * 2048, nullptr, fbuf,
        NN, 2048, 512, 512, 2048, 2048, 0, 0, 0, 0, 0);
    // tmp = h2 + fbuf @ f2w + f2b
    k_gemm<bf16, float, 0><<<dim3(8, 32, 1), 256, 0, stream>>>(
        fbuf, f2w + (size_t)i * 2048 * 512, f2b + i * 512, h2, tmp,
        NN, 512, 2048, 2048, 512, 512, 512, 0, 0, 0, 0);
    k_ln<<<NN / 4, 256, 0, stream>>>(tmp, ln2g + i * 512, ln2b + i * 512, h2);
  }

  k_pool<<<64, 512, 0, stream>>>(h2, out_pool);
}

// Round 3
// 755.889 us; speedup vs baseline: 3.3758x; 3.3758x over previous
//
#include <hip/hip_runtime.h>
#include <hip/hip_bf16.h>

#define NN 4096
#define EE 16384
#define ET 20480   // EE + NN

typedef __hip_bfloat16 bf16;
typedef __bf16 bfv8 __attribute__((ext_vector_type(8)));
typedef float fv4 __attribute__((ext_vector_type(4)));

__device__ __forceinline__ float warp_max(float v){
#pragma unroll
  for (int o = 32; o; o >>= 1) v = fmaxf(v, __shfl_xor(v, o));
  return v;
}
__device__ __forceinline__ float warp_sum(float v){
#pragma unroll
  for (int o = 32; o; o >>= 1) v += __shfl_xor(v, o);
  return v;
}

// async global->LDS, 16B per lane. lbase = wave-uniform LDS base (lane*16 added by HW).
__device__ __forceinline__ void gl_lds16(const void* g, void* lbase, int lane){
#if __has_builtin(__builtin_amdgcn_global_load_lds)
  __builtin_amdgcn_global_load_lds(
      (const __attribute__((address_space(1))) unsigned int*)g,
      (__attribute__((address_space(3))) unsigned int*)lbase, 16, 0, 0);
#else
  *(uint4*)((char*)lbase + lane * 16) = *(const uint4*)g;
#endif
}

// ---------------- graph preprocessing ----------------

__global__ void k_deg_esum(const int* __restrict__ dst0, const float* __restrict__ eattr,
                           int* deg, float* esum){
  int e = blockIdx.x * 256 + threadIdx.x;
  if (e >= EE) return;
  int d = dst0[e];
  atomicAdd(&deg[d], 1);
  const float* ar = eattr + (size_t)e * 11;
  float* er = esum + (size_t)d * 11;
#pragma unroll
  for (int j = 0; j < 11; j++) atomicAdd(&er[j], ar[j]);
}

__global__ void k_loop_attr(const float* __restrict__ esum, const int* __restrict__ deg,
                            float* lattr){
  int n = blockIdx.x * 256 + threadIdx.x;
  if (n >= NN) return;
  float c = fmaxf((float)deg[n], 1.0f);
#pragma unroll
  for (int j = 0; j < 11; j++) lattr[n * 11 + j] = esum[n * 11 + j] / c;
}

__global__ void k_scan(const int* __restrict__ deg, int* offsets){
  __shared__ int sums[256];
  int t = threadIdx.x;
  int base = t * 16;
  int vals[16];
  int s = 0;
#pragma unroll
  for (int j = 0; j < 16; j++){ vals[j] = s; s += deg[base + j] + 1; }
  sums[t] = s;
  __syncthreads();
  for (int off = 1; off < 256; off <<= 1){
    int v = (t >= off) ? sums[t - off] : 0;
    __syncthreads();
    sums[t] += v;
    __syncthreads();
  }
  int pre = (t == 0) ? 0 : sums[t - 1];
#pragma unroll
  for (int j = 0; j < 16; j++) offsets[base + j] = pre + vals[j];
  if (t == 255) offsets[NN] = sums[255];
}

__global__ void k_scatter(const int* __restrict__ src0, const int* __restrict__ dst0,
                          const int* __restrict__ offsets, int* cursor,
                          int* csr_src, int* csr_eid){
  int t = blockIdx.x * 256 + threadIdx.x;
  if (t < EE){
    int d = dst0[t];
    int pos = offsets[d] + atomicAdd(&cursor[d], 1);
    csr_src[pos] = src0[t];
    csr_eid[pos] = t;
  } else if (t < EE + NN){
    int n = t - EE;
    int pos = offsets[n + 1] - 1;
    csr_src[pos] = n;
    csr_eid[pos] = EE + n;
  }
}

// ---------------- folded attention weight vectors ----------------

__global__ void k_fold1(const float* __restrict__ W1, const float* __restrict__ as1,
                        const float* __restrict__ ad1, const float* __restrict__ We1,
                        const float* __restrict__ ae1,
                        float* wse1, float* wsd1, float* wee1){
  int t = blockIdx.x * 256 + threadIdx.x;
  if (t < 930){
    int k = t / 10, h = t % 10;
    const float* wr = W1 + (size_t)k * 5120 + h * 512;
    const float* asr = as1 + h * 512;
    const float* adr = ad1 + h * 512;
    float ss = 0, sd = 0;
    for (int c = 0; c < 512; c++){ float w = wr[c]; ss += w * asr[c]; sd += w * adr[c]; }
    wse1[t] = ss; wsd1[t] = sd;
  } else if (t < 1040){
    int u = t - 930;
    int k = u / 10, h = u % 10;
    const float* wr = We1 + (size_t)k * 5120 + h * 512;
    const float* aer = ae1 + h * 512;
    float se = 0;
    for (int c = 0; c < 512; c++) se += wr[c] * aer[c];
    wee1[u] = se;
  }
}

__global__ void k_fold2(const float* __restrict__ W2, const float* __restrict__ as2,
                        const float* __restrict__ ad2, const float* __restrict__ We2,
                        const float* __restrict__ ae2,
                        float* w2s, float* w2d, float* we2e){
  int t = blockIdx.x * 256 + threadIdx.x;
  if (t < 5120){
    const float* wr = W2 + (size_t)t * 512;
    float ss = 0, sd = 0;
    for (int c = 0; c < 512; c++){ float w = wr[c]; ss += w * as2[c]; sd += w * ad2[c]; }
    w2s[t] = ss; w2d[t] = sd;
  } else if (t < 5131){
    int k = t - 5120;
    const float* wr = We2 + (size_t)k * 512;
    float se = 0;
    for (int c = 0; c < 512; c++) se += wr[c] * ae2[c];
    we2e[k] = se;
  }
}

__global__ void k_logits1(const float* __restrict__ x1, const float* __restrict__ wse1,
                          const float* __restrict__ wsd1, float* S1, float* D1){
  int t = blockIdx.x * 256 + threadIdx.x;
  int n = t / 10, h = t % 10;
  const float* xr = x1 + (size_t)n * 93;
  float s = 0, d = 0;
  for (int k = 0; k < 93; k++){ float x = xr[k]; s += x * wse1[k * 10 + h]; d += x * wsd1[k * 10 + h]; }
  S1[t] = s; D1[t] = d;
}

// ---------------- weight prep: f32 -> bf16 transposed (B^T [N][K]) ----------------

__global__ void k_t2b(const float* __restrict__ src, bf16* __restrict__ dst,
                      int K, int N, long sZ, long dZ){
  __shared__ float t[32][33];
  src += (size_t)blockIdx.z * sZ;
  dst += (size_t)blockIdx.z * dZ;
  int k0 = blockIdx.y * 32, n0 = blockIdx.x * 32;
  int x = threadIdx.x, y = threadIdx.y;   // 32 x 8
#pragma unroll
  for (int yy = y; yy < 32; yy += 8){
    int k = k0 + yy, n = n0 + x;
    t[yy][x] = (k < K && n < N) ? src[(size_t)k * N + n] : 0.f;
  }
  __syncthreads();
#pragma unroll
  for (int yy = y; yy < 32; yy += 8){
    int n = n0 + yy, k = k0 + x;
    if (n < N && k < K) dst[(size_t)n * K + k] = __float2bfloat16(t[x][yy]);
  }
}

// W1t[h][c][k<96] = W1[k][h*512+c] (k>=93 -> 0)
__global__ void k_prep_w1t(const float* __restrict__ W1, bf16* __restrict__ W1t){
  int t = blockIdx.x * 256 + threadIdx.x;
  if (t >= 10 * 512 * 96) return;
  int k = t % 96, c = (t / 96) & 511, h = t / (96 * 512);
  float v = (k < 93) ? W1[(size_t)k * 5120 + h * 512 + c] : 0.f;
  W1t[t] = __float2bfloat16(v);
}

// ---------------- GAT layer 1: softmax + 93-wide aggregate -> bf16 [wid][96] ----------------

__global__ __launch_bounds__(256) void k_gat1(
    const int* __restrict__ offsets, const int* __restrict__ csr_src,
    const int* __restrict__ csr_eid, const float* __restrict__ eattr,
    const float* __restrict__ lattr, const float* __restrict__ S1,
    const float* __restrict__ D1, const float* __restrict__ wee1,
    const float* __restrict__ x1, bf16* __restrict__ xaggp){
  int wid = (blockIdx.x * 256 + threadIdx.x) >> 6;   // n*10+h
  int lane = threadIdx.x & 63;
  int n = wid / 10, h = wid % 10;
  int start = offsets[n], end = offsets[n + 1];
  float dl = D1[wid];
  float wl[11];
#pragma unroll
  for (int j = 0; j < 11; j++) wl[j] = wee1[j * 10 + h];

  float m = -1e30f;
  for (int pos = start + lane; pos < end; pos += 64){
    int s = csr_src[pos]; int eid = csr_eid[pos];
    const float* ea = (eid < EE) ? eattr + (size_t)eid * 11 : lattr + (size_t)(eid - EE) * 11;
    float eel = 0;
#pragma unroll
    for (int j = 0; j < 11; j++) eel += ea[j] * wl[j];
    float lg = S1[s * 10 + h] + dl + eel;
    lg = lg > 0.f ? lg : 0.2f * lg;
    m = fmaxf(m, lg);
  }
  m = warp_max(m);

  float ps = 0;
  for (int pos = start + lane; pos < end; pos += 64){
    int s = csr_src[pos]; int eid = csr_eid[pos];
    const float* ea = (eid < EE) ? eattr + (size_t)eid * 11 : lattr + (size_t)(eid - EE) * 11;
    float eel = 0;
#pragma unroll
    for (int j = 0; j < 11; j++) eel += ea[j] * wl[j];
    float lg = S1[s * 10 + h] + dl + eel;
    lg = lg > 0.f ? lg : 0.2f * lg;
    ps += __expf(lg - m);
  }
  ps = warp_sum(ps);
  float inv = 1.0f / ps;

  float acc0 = 0, acc1 = 0;
  for (int pos = start; pos < end; pos++){
    int s = csr_src[pos]; int eid = csr_eid[pos];
    const float* ea = (eid < EE) ? eattr + (size_t)eid * 11 : lattr + (size_t)(eid - EE) * 11;
    float eel = 0;
#pragma unroll
    for (int j = 0; j < 11; j++) eel += ea[j] * wl[j];
    float lg = S1[s * 10 + h] + dl + eel;
    lg = lg > 0.f ? lg : 0.2f * lg;
    float alpha = __expf(lg - m) * inv;
    const float* xr = x1 + (size_t)s * 93;
    acc0 += alpha * xr[lane];
    if (lane < 29) acc1 += alpha * xr[64 + lane];
  }
  bf16* o = xaggp + (size_t)wid * 96;
  o[lane] = __float2bfloat16(acc0);
  if (lane < 29) o[64 + lane] = __float2bfloat16(acc1);
  else if (lane < 32) o[64 + lane] = __float2bfloat16(0.f);  // pad k=93..95
}

// ---------------- layer-2 node logits ----------------

__global__ __launch_bounds__(256) void k_logits2(const bf16* __restrict__ h1,
                                                 const float* __restrict__ w2s,
                                                 const float* __restrict__ w2d,
                                                 float* s2, float* d2){
  int wid = (blockIdx.x * 256 + threadIdx.x) >> 6;
  int lane = threadIdx.x & 63;
  const bf16* hr = h1 + (size_t)wid * 5120;
  float a = 0, b = 0;
  for (int k = lane; k < 5120; k += 64){
    float v = __bfloat162float(hr[k]);
    a += v * w2s[k]; b += v * w2d[k];
  }
  a = warp_sum(a); b = warp_sum(b);
  if (lane == 0){ s2[wid] = a; d2[wid] = b; }
}

// ---------------- GAT layer 2 ----------------

__global__ __launch_bounds__(256) void k_gat2(
    const int* __restrict__ offsets, const int* __restrict__ csr_src,
    const int* __restrict__ csr_eid, const float* __restrict__ eattr,
    const float* __restrict__ lattr, const float* __restrict__ s2,
    const float* __restrict__ d2, const float* __restrict__ we2e,
    const float* __restrict__ xs2, const float* __restrict__ b2,
    float* __restrict__ h2f, bf16* __restrict__ hbf, float* __restrict__ alpha_out){
  int n = (blockIdx.x * 256 + threadIdx.x) >> 6;
  int lane = threadIdx.x & 63;
  int start = offsets[n], end = offsets[n + 1];
  float dl = d2[n];
  float wl[11];
#pragma unroll
  for (int j = 0; j < 11; j++) wl[j] = we2e[j];

  float m = -1e30f;
  for (int pos = start + lane; pos < end; pos += 64){
    int s = csr_src[pos]; int eid = csr_eid[pos];
    const float* ea = (eid < EE) ? eattr + (size_t)eid * 11 : lattr + (size_t)(eid - EE) * 11;
    float eel = 0;
#pragma unroll
    for (int j = 0; j < 11; j++) eel += ea[j] * wl[j];
    float lg = s2[s] + dl + eel;
    lg = lg > 0.f ? lg : 0.2f * lg;
    m = fmaxf(m, lg);
  }
  m = warp_max(m);

  float ps = 0;
  for (int pos = start + lane; pos < end; pos += 64){
    int s = csr_src[pos]; int eid = csr_eid[pos];
    const float* ea = (eid < EE) ? eattr + (size_t)eid * 11 : lattr + (size_t)(eid - EE) * 11;
    float eel = 0;
#pragma unroll
    for (int j = 0; j < 11; j++) eel += ea[j] * wl[j];
    float lg = s2[s] + dl + eel;
    lg = lg > 0.f ? lg : 0.2f * lg;
    ps += __expf(lg - m);
  }
  ps = warp_sum(ps);
  float inv = 1.0f / ps;

  float acc[8] = {0, 0, 0, 0, 0, 0, 0, 0};
  for (int pos = start; pos < end; pos++){
    int s = csr_src[pos]; int eid = csr_eid[pos];
    const float* ea = (eid < EE) ? eattr + (size_t)eid * 11 : lattr + (size_t)(eid - EE) * 11;
    float eel = 0;
#pragma unroll
    for (int j = 0; j < 11; j++) eel += ea[j] * wl[j];
    float lg = s2[s] + dl + eel;
    lg = lg > 0.f ? lg : 0.2f * lg;
    float alpha = __expf(lg - m) * inv;
    if (lane == 0) alpha_out[eid] = alpha;
    const float* xr = xs2 + (size_t)s * 512;
#pragma unroll
    for (int j = 0; j < 8; j++) acc[j] += alpha * xr[lane + j * 64];
  }
#pragma unroll
  for (int j = 0; j < 8; j++){
    int c = lane + j * 64;
    float v = acc[j] + b2[c];
    v = v > 0.f ? v : (__expf(v) - 1.f);
    h2f[(size_t)n * 512 + c] = v;
    hbf[(size_t)n * 512 + c] = __float2bfloat16(v);
  }
}

// ---------------- MFMA bf16 GEMM: C = act(A @ Bt^T + bias + res) ----------------
// A [M,K] bf16 (lda), Bt [N,K] bf16 (ld = K), C [M,ldc]. K % 32 == 0,
// M % (BMF*32) == 0, N % (BNF*32) == 0. If RES, res has ld == ldc.
// m97 structure: linear LDS [rows][32] bf16, global_load_lds width 16,
// 2-barrier K-loop, per-wave (BMF*16)x(BNF*16) output via 16x16x32 MFMA.

__device__ __forceinline__ void stC_elem(float* p, float v){ *p = v; }
__device__ __forceinline__ void stC_elem(bf16* p, float v){ *p = __float2bfloat16(v); }

template <int BMF, int BNF, int ACT, bool BIAS, bool RES, typename TC>
__global__ __launch_bounds__(256) void k_mm(
    const bf16* __restrict__ A, const bf16* __restrict__ Bt,
    const float* __restrict__ bias, const float* __restrict__ res,
    TC* __restrict__ C, int M, int K, int lda, int ldc,
    long aZ, long bZ, long cZ, long biasZ){
  constexpr int BM = BMF * 32, BN = BNF * 32;
  __shared__ __align__(16) bf16 As[BM * 32];
  __shared__ __align__(16) bf16 Bs[BN * 32];
  const int tid = threadIdx.x, wave = tid >> 6, lane = tid & 63;
  const int bm = blockIdx.y * BM, bn = blockIdx.x * BN;
  const int z = blockIdx.z;
  A  += (size_t)z * aZ;
  Bt += (size_t)z * bZ;
  C  += (size_t)z * cZ;
  const float* bp = BIAS ? bias + (size_t)z * biasZ : nullptr;

  const int trow = tid >> 2, tk = (tid & 3) * 8;   // staging: 16B per thread
  const int wr = (wave >> 1) * (BMF * 16), wc = (wave & 1) * (BNF * 16);
  const int r = lane & 15, kq = lane >> 4;

  fv4 acc[BMF][BNF] = {};

  for (int k0 = 0; k0 < K; k0 += 32){
#pragma unroll
    for (int s = 0; s < BM / 64; s++)
      gl_lds16(A + (size_t)(bm + s * 64 + trow) * lda + k0 + tk,
               (char*)As + s * 4096 + wave * 1024, lane);
#pragma unroll
    for (int s = 0; s < BN / 64; s++)
      gl_lds16(Bt + (size_t)(bn + s * 64 + trow) * K + k0 + tk,
               (char*)Bs + s * 4096 + wave * 1024, lane);
    __syncthreads();   // drains vmcnt -> staged data visible

    bfv8 a[BMF], b[BNF];
#pragma unroll
    for (int i = 0; i < BMF; i++)
      a[i] = *(const bfv8*)&As[(wr + i * 16 + r) * 32 + kq * 8];
#pragma unroll
    for (int j = 0; j < BNF; j++)
      b[j] = *(const bfv8*)&Bs[(wc + j * 16 + r) * 32 + kq * 8];
#pragma unroll
    for (int i = 0; i < BMF; i++)
#pragma unroll
      for (int j = 0; j < BNF; j++)
        acc[i][j] = __builtin_amdgcn_mfma_f32_16x16x32_bf16(a[i], b[j], acc[i][j], 0, 0, 0);
    __syncthreads();
  }

  // C/D layout: col = lane&15, row = (lane>>4)*4 + q   [m89/m91 verified]
  const int rb = bm + wr + (lane >> 4) * 4;
  const int cb = bn + wc + (lane & 15);
#pragma unroll
  for (int i = 0; i < BMF; i++)
#pragma unroll
    for (int j = 0; j < BNF; j++){
      int gn = cb + j * 16;
      float bv = BIAS ? bp[gn] : 0.f;
#pragma unroll
      for (int q = 0; q < 4; q++){
        int gm = rb + i * 16 + q;
        float v = acc[i][j][q] + bv;
        if (RES) v += res[(size_t)gm * ldc + gn];
        if (ACT == 1) v = fmaxf(v, 0.f);
        if (ACT == 2) v = v > 0.f ? v : (__expf(v) - 1.f);
        stC_elem(&C[(size_t)gm * ldc + gn], v);
      }
    }
}

// ---------------- f32 tiled GEMM (kept only for tiny Wvo = Wv @ Wo) ----------------

template <int ACT>
__global__ __launch_bounds__(256) void k_gemm(
    const float* __restrict__ A, const float* __restrict__ B,
    float* __restrict__ C, int M, int Nn, int K,
    int lda, int ldb, int ldc,
    long aZ, long bZ, long cZ){
  __shared__ float As[16][128];
  __shared__ float Bs[16][64];
  int z = blockIdx.z;
  A += (size_t)z * aZ;
  B += (size_t)z * bZ;
  C += (size_t)z * cZ;

  int bm = blockIdx.y * 128, bn = blockIdx.x * 64;
  int tid = threadIdx.x;
  int tx = tid & 15, ty = tid >> 4;
  float acc[8][4] = {};

  for (int k0 = 0; k0 < K; k0 += 16){
    {
      int rr = tid >> 1;
      int cbk = (tid & 1) * 8;
      int gm = bm + rr;
#pragma unroll
      for (int j = 0; j < 8; j++){
        int gk = k0 + cbk + j;
        float v = 0.f;
        if (gm < M && gk < K) v = A[(size_t)gm * lda + gk];
        As[cbk + j][rr] = v;
      }
    }
    {
      int rr = tid >> 4;
      int cbn = (tid & 15) * 4;
      int gk = k0 + rr;
#pragma unroll
      for (int j = 0; j < 4; j++){
        int gn = bn + cbn + j;
        float v = 0.f;
        if (gk < K && gn < Nn) v = B[(size_t)gk * ldb + gn];
        Bs[rr][cbn + j] = v;
      }
    }
    __syncthreads();
#pragma unroll
    for (int kk = 0; kk < 16; kk++){
      float4 a0 = *(const float4*)&As[kk][ty * 8];
      float4 a1 = *(const float4*)&As[kk][ty * 8 + 4];
      float4 b0 = *(const float4*)&Bs[kk][tx * 4];
      float av[8] = {a0.x, a0.y, a0.z, a0.w, a1.x, a1.y, a1.z, a1.w};
      float bv[4] = {b0.x, b0.y, b0.z, b0.w};
#pragma unroll
      for (int i = 0; i < 8; i++)
#pragma unroll
        for (int j = 0; j < 4; j++) acc[i][j] += av[i] * bv[j];
    }
    __syncthreads();
  }

#pragma unroll
  for (int i = 0; i < 8; i++){
    int gm = bm + ty * 8 + i;
    if (gm >= M) continue;
#pragma unroll
    for (int j = 0; j < 4; j++){
      int gn = bn + tx * 4 + j;
      if (gn >= Nn) continue;
      C[(size_t)gm * ldc + gn] = acc[i][j];
    }
  }
}

// ---------------- misc: bvo fold, layernorm (dual out), pool ----------------

__global__ void k_bvo(const float* __restrict__ in_b, const float* __restrict__ out_w,
                      const float* __restrict__ out_b, float* bvo){
  int t = blockIdx.x * 256 + threadIdx.x;
  if (t >= 1024) return;
  int i = t >> 9, c = t & 511;
  const float* ib = in_b + i * 1536 + 1024;
  const float* ow = out_w + (size_t)i * 262144;
  float s = out_b[i * 512 + c];
  for (int k = 0; k < 512; k++) s += ib[k] * ow[(size_t)k * 512 + c];
  bvo[t] = s;
}

__global__ __launch_bounds__(256) void k_ln(const float* __restrict__ x,
                                            const float* __restrict__ g,
                                            const float* __restrict__ b,
                                            float* __restrict__ yf,
                                            bf16* __restrict__ ybf){
  int wid = (blockIdx.x * 256 + threadIdx.x) >> 6;
  int lane = threadIdx.x & 63;
  const float* xr = x + (size_t)wid * 512;
  float v[8];
  float s = 0;
#pragma unroll
  for (int j = 0; j < 8; j++){ v[j] = xr[lane + j * 64]; s += v[j]; }
  s = warp_sum(s);
  float mu = s * (1.0f / 512.0f);
  float var = 0;
#pragma unroll
  for (int j = 0; j < 8; j++){ float d = v[j] - mu; var += d * d; }
  var = warp_sum(var) * (1.0f / 512.0f);
  float inv = rsqrtf(var + 1e-5f);
#pragma unroll
  for (int j = 0; j < 8; j++){
    int c = lane + j * 64;
    float o = (v[j] - mu) * inv * g[c] + b[c];
    yf[(size_t)wid * 512 + c] = o;
    ybf[(size_t)wid * 512 + c] = __float2bfloat16(o);
  }
}

__global__ void k_pool(const float* __restrict__ h, float* __restrict__ out){
  int b = blockIdx.x;
  int c = threadIdx.x;   // 512 threads
  const float* hr = h + (size_t)b * 64 * 512;
  float m = -1e30f;
  for (int i = 0; i < 64; i++) m = fmaxf(m, hr[i * 512 + c]);
  out[(size_t)b * 512 + c] = m;
}

// ---------------- launcher ----------------

extern "C" void kernel_launch(void* const* d_in, const int* in_sizes, int n_in,
                              void* d_out, int out_size, void* d_ws, size_t ws_size,
                              hipStream_t stream){
  const float* x1    = (const float*)d_in[0];
  const int*   ei    = (const int*)d_in[1];
  const float* eattr = (const float*)d_in[2];
  const float* W1    = (const float*)d_in[4];
  const float* as1   = (const float*)d_in[5];
  const float* ad1   = (const float*)d_in[6];
  const float* We1   = (const float*)d_in[7];
  const float* ae1   = (const float*)d_in[8];
  const float* b1    = (const float*)d_in[9];
  const float* W2    = (const float*)d_in[10];
  const float* as2   = (const float*)d_in[11];
  const float* ad2   = (const float*)d_in[12];
  const float* We2   = (const float*)d_in[13];
  const float* ae2   = (const float*)d_in[14];
  const float* b2    = (const float*)d_in[15];
  const float* in_w  = (const float*)d_in[16];
  const float* in_b  = (const float*)d_in[17];
  const float* out_w = (const float*)d_in[18];
  const float* out_b = (const float*)d_in[19];
  const float* ln1g  = (const float*)d_in[20];
  const float* ln1b  = (const float*)d_in[21];
  const float* f1w   = (const float*)d_in[22];
  const float* f1b   = (const float*)d_in[23];
  const float* f2w   = (const float*)d_in[24];
  const float* f2b   = (const float*)d_in[25];
  const float* ln2g  = (const float*)d_in[26];
  const float* ln2b  = (const float*)d_in[27];

  const int* src0 = ei;
  const int* dst0 = ei + EE;

  char* p = (char*)d_ws;
  auto alloc = [&](size_t bytes) -> void* {
    void* r = p;
    p += (bytes + 255) & ~(size_t)255;
    return r;
  };
  float* esum    = (float*)alloc(NN * 11 * 4);
  float* lattr   = (float*)alloc(NN * 11 * 4);
  int*   deg     = (int*)alloc(NN * 4);
  int*   offsets = (int*)alloc((NN + 1) * 4);
  int*   cursor  = (int*)alloc(NN * 4);
  int*   csr_src = (int*)alloc(ET * 4);
  int*   csr_eid = (int*)alloc(ET * 4);
  float* wse1    = (float*)alloc(930 * 4);
  float* wsd1    = (float*)alloc(930 * 4);
  float* wee1    = (float*)alloc(110 * 4);
  float* S1      = (float*)alloc(NN * 10 * 4);
  float* D1b     = (float*)alloc(NN * 10 * 4);
  bf16*  xaggp   = (bf16*)alloc((size_t)NN * 10 * 96 * 2);
  bf16*  W1t     = (bf16*)alloc((size_t)10 * 512 * 96 * 2);
  bf16*  W2t     = (bf16*)alloc((size_t)512 * 5120 * 2);
  bf16*  f1wt    = (bf16*)alloc((size_t)2 * 2048 * 512 * 2);
  bf16*  f2wt    = (bf16*)alloc((size_t)2 * 512 * 2048 * 2);
  bf16*  Wvot    = (bf16*)alloc((size_t)2 * 512 * 512 * 2);
  bf16*  h1      = (bf16*)alloc((size_t)NN * 5120 * 2);
  float* w2s     = (float*)alloc(5120 * 4);
  float* w2d     = (float*)alloc(5120 * 4);
  float* we2e    = (float*)alloc(16 * 4);
  float* s2      = (float*)alloc(NN * 4);
  float* d2v     = (float*)alloc(NN * 4);
  float* xs2     = (float*)alloc((size_t)NN * 512 * 4);   // aliased as tmp after gat2
  float* h2f     = (float*)alloc((size_t)NN * 512 * 4);
  bf16*  hbf     = (bf16*)alloc((size_t)NN * 512 * 2);
  bf16*  fbuf    = (bf16*)alloc((size_t)NN * 2048 * 2);
  float* Wvo     = (float*)alloc((size_t)2 * 512 * 512 * 4);
  float* bvo     = (float*)alloc(2 * 512 * 4);
  float* tmp     = xs2;   // alias: xs2 dead after k_gat2

  float* out_pool = (float*)d_out;
  float* alpha2   = out_pool + 64 * 512;

  hipMemsetAsync(deg, 0, NN * 4, stream);
  hipMemsetAsync(esum, 0, NN * 11 * 4, stream);
  hipMemsetAsync(cursor, 0, NN * 4, stream);

  // graph prep + logit folds
  k_deg_esum<<<EE / 256, 256, 0, stream>>>(dst0, eattr, deg, esum);
  k_loop_attr<<<NN / 256, 256, 0, stream>>>(esum, deg, lattr);
  k_scan<<<1, 256, 0, stream>>>(deg, offsets);
  k_scatter<<<(EE + NN) / 256, 256, 0, stream>>>(src0, dst0, offsets, cursor, csr_src, csr_eid);
  k_fold1<<<5, 256, 0, stream>>>(W1, as1, ad1, We1, ae1, wse1, wsd1, wee1);
  k_fold2<<<21, 256, 0, stream>>>(W2, as2, ad2, We2, ae2, w2s, w2d, we2e);
  k_logits1<<<160, 256, 0, stream>>>(x1, wse1, wsd1, S1, D1b);

  // weight preps (independent of graph work)
  k_prep_w1t<<<1920, 256, 0, stream>>>(W1, W1t);
  k_t2b<<<dim3(16, 160, 1), dim3(32, 8), 0, stream>>>(W2, W2t, 5120, 512, 0, 0);
  k_t2b<<<dim3(64, 16, 2), dim3(32, 8), 0, stream>>>(f1w, f1wt, 512, 2048,
                                                     512L * 2048, 2048L * 512);
  k_t2b<<<dim3(16, 64, 2), dim3(32, 8), 0, stream>>>(f2w, f2wt, 2048, 512,
                                                     2048L * 512, 512L * 2048);

  // GAT-1: aggregate 93-wide, then project per-head with MFMA
  k_gat1<<<(NN * 10) / 4, 256, 0, stream>>>(offsets, csr_src, csr_eid, eattr, lattr,
                                            S1, D1b, wee1, x1, xaggp);
  // h1 = elu(xagg @ W1 + b1): z=10 heads, M=4096, N=512, K=96
  k_mm<4, 4, 2, true, false, bf16><<<dim3(4, 32, 10), 256, 0, stream>>>(
      xaggp, W1t, b1, nullptr, h1, NN, 96, 960, 5120, 96, 512L * 96, 512, 512);

  k_logits2<<<NN / 4, 256, 0, stream>>>(h1, w2s, w2d, s2, d2v);
  // xs2 = h1 @ W2: M=4096, N=512, K=5120
  k_mm<2, 4, 0, false, false, float><<<dim3(4, 64, 1), 256, 0, stream>>>(
      h1, W2t, nullptr, nullptr, xs2, NN, 5120, 5120, 512, 0, 0, 0, 0);
  k_gat2<<<NN / 4, 256, 0, stream>>>(offsets, csr_src, csr_eid, eattr, lattr,
                                     s2, d2v, we2e, xs2, b2, h2f, hbf, alpha2);

  // transformer weight folds: Wvo = Wv @ Wo (f32, tiny), bvo, then bf16^T
  k_gemm<0><<<dim3(8, 4, 2), 256, 0, stream>>>(
      in_w + 1024, out_w, Wvo, 512, 512, 512, 1536, 512, 512,
      786432, 262144, 262144);
  k_bvo<<<4, 256, 0, stream>>>(in_b, out_w, out_b, bvo);
  k_t2b<<<dim3(16, 16, 2), dim3(32, 8), 0, stream>>>(Wvo, Wvot, 512, 512,
                                                     262144, 262144);

  for (int i = 0; i < 2; i++){
    // tmp = h2 + h2 @ Wvo + bvo   (A = bf16 h, res = f32 h)
    k_mm<2, 4, 0, true, true, float><<<dim3(4, 64, 1), 256, 0, stream>>>(
        hbf, Wvot + (size_t)i * 262144, bvo + i * 512, h2f, tmp,
        NN, 512, 512, 512, 0, 0, 0, 0);
    k_ln<<<NN / 4, 256, 0, stream>>>(tmp, ln1g + i * 512, ln1b + i * 512, h2f, hbf);
    // fbuf = relu(h @ f1w + f1b): N=2048, K=512
    k_mm<4, 4, 1, true, false, bf16><<<dim3(16, 32, 1), 256, 0, stream>>>(
        hbf, f1wt + (size_t)i * 2048 * 512, f1b + i * 2048, nullptr, fbuf,
        NN, 512, 512, 2048, 0, 0, 0, 0);
    // tmp = h + fbuf @ f2w + f2b: N=512, K=2048
    k_mm<2, 4, 0, true, true, float><<<dim3(4, 64, 1), 256, 0, stream>>>(
        fbuf, f2wt + (size_t)i * 512 * 2048, f2b + i * 512, h2f, tmp,
        NN, 2048, 2048, 512, 0, 0, 0, 0);
    k_ln<<<NN / 4, 256, 0, stream>>>(tmp, ln2g + i * 512, ln2b + i * 512, h2f, hbf);
  }

  k_pool<<<64, 512, 0, stream>>>(h2f, out_pool);
}

// Round 4
// 665.765 us; speedup vs baseline: 3.8328x; 1.1354x over previous
//
#include <hip/hip_runtime.h>
#include <hip/hip_bf16.h>

#define NN 4096
#define EE 16384
#define ET 20480   // EE + NN

typedef __hip_bfloat16 bf16;
typedef __bf16 bfv8 __attribute__((ext_vector_type(8)));
typedef float fv4 __attribute__((ext_vector_type(4)));

__device__ __forceinline__ float warp_max(float v){
#pragma unroll
  for (int o = 32; o; o >>= 1) v = fmaxf(v, __shfl_xor(v, o));
  return v;
}
__device__ __forceinline__ float warp_sum(float v){
#pragma unroll
  for (int o = 32; o; o >>= 1) v += __shfl_xor(v, o);
  return v;
}
__device__ __forceinline__ float bf2f(unsigned short u){
  return __uint_as_float((unsigned)u << 16);
}

// async global->LDS, 16B per lane. lbase = wave-uniform LDS base (lane*16 added by HW).
__device__ __forceinline__ void gl_lds16(const void* g, void* lbase, int lane){
#if __has_builtin(__builtin_amdgcn_global_load_lds)
  __builtin_amdgcn_global_load_lds(
      (const __attribute__((address_space(1))) unsigned int*)g,
      (__attribute__((address_space(3))) unsigned int*)lbase, 16, 0, 0);
#else
  *(uint4*)((char*)lbase + lane * 16) = *(const uint4*)g;
#endif
}

// ---------------- graph preprocessing ----------------

__global__ void k_deg_esum(const int* __restrict__ dst0, const float* __restrict__ eattr,
                           int* deg, float* esum){
  int e = blockIdx.x * 256 + threadIdx.x;
  if (e >= EE) return;
  int d = dst0[e];
  atomicAdd(&deg[d], 1);
  const float* ar = eattr + (size_t)e * 11;
  float* er = esum + (size_t)d * 11;
#pragma unroll
  for (int j = 0; j < 11; j++) atomicAdd(&er[j], ar[j]);
}

__global__ void k_loop_attr(const float* __restrict__ esum, const int* __restrict__ deg,
                            float* lattr){
  int n = blockIdx.x * 256 + threadIdx.x;
  if (n >= NN) return;
  float c = fmaxf((float)deg[n], 1.0f);
#pragma unroll
  for (int j = 0; j < 11; j++) lattr[n * 11 + j] = esum[n * 11 + j] / c;
}

__global__ void k_scan(const int* __restrict__ deg, int* offsets){
  __shared__ int sums[256];
  int t = threadIdx.x;
  int base = t * 16;
  int vals[16];
  int s = 0;
#pragma unroll
  for (int j = 0; j < 16; j++){ vals[j] = s; s += deg[base + j] + 1; }
  sums[t] = s;
  __syncthreads();
  for (int off = 1; off < 256; off <<= 1){
    int v = (t >= off) ? sums[t - off] : 0;
    __syncthreads();
    sums[t] += v;
    __syncthreads();
  }
  int pre = (t == 0) ? 0 : sums[t - 1];
#pragma unroll
  for (int j = 0; j < 16; j++) offsets[base + j] = pre + vals[j];
  if (t == 255) offsets[NN] = sums[255];
}

__global__ void k_scatter(const int* __restrict__ src0, const int* __restrict__ dst0,
                          const int* __restrict__ offsets, int* cursor,
                          int* csr_src, int* csr_eid){
  int t = blockIdx.x * 256 + threadIdx.x;
  if (t < EE){
    int d = dst0[t];
    int pos = offsets[d] + atomicAdd(&cursor[d], 1);
    csr_src[pos] = src0[t];
    csr_eid[pos] = t;
  } else if (t < EE + NN){
    int n = t - EE;
    int pos = offsets[n + 1] - 1;
    csr_src[pos] = n;
    csr_eid[pos] = EE + n;
  }
}

// ---------------- folded attention weight vectors ----------------

__global__ void k_fold1(const float* __restrict__ W1, const float* __restrict__ as1,
                        const float* __restrict__ ad1, const float* __restrict__ We1,
                        const float* __restrict__ ae1,
                        float* wse1, float* wsd1, float* wee1){
  int t = blockIdx.x * 256 + threadIdx.x;
  if (t < 930){
    int k = t / 10, h = t % 10;
    const float* wr = W1 + (size_t)k * 5120 + h * 512;
    const float* asr = as1 + h * 512;
    const float* adr = ad1 + h * 512;
    float ss = 0, sd = 0;
    for (int c = 0; c < 512; c++){ float w = wr[c]; ss += w * asr[c]; sd += w * adr[c]; }
    wse1[t] = ss; wsd1[t] = sd;
  } else if (t < 1040){
    int u = t - 930;
    int k = u / 10, h = u % 10;
    const float* wr = We1 + (size_t)k * 5120 + h * 512;
    const float* aer = ae1 + h * 512;
    float se = 0;
    for (int c = 0; c < 512; c++) se += wr[c] * aer[c];
    wee1[u] = se;
  }
}

__global__ void k_fold2(const float* __restrict__ W2, const float* __restrict__ as2,
                        const float* __restrict__ ad2, const float* __restrict__ We2,
                        const float* __restrict__ ae2,
                        float* w2s, float* w2d, float* we2e){
  int t = blockIdx.x * 256 + threadIdx.x;
  if (t < 5120){
    const float* wr = W2 + (size_t)t * 512;
    float ss = 0, sd = 0;
    for (int c = 0; c < 512; c++){ float w = wr[c]; ss += w * as2[c]; sd += w * ad2[c]; }
    w2s[t] = ss; w2d[t] = sd;
  } else if (t < 5131){
    int k = t - 5120;
    const float* wr = We2 + (size_t)k * 512;
    float se = 0;
    for (int c = 0; c < 512; c++) se += wr[c] * ae2[c];
    we2e[k] = se;
  }
}

__global__ void k_logits1(const float* __restrict__ x1, const float* __restrict__ wse1,
                          const float* __restrict__ wsd1, float* S1, float* D1){
  int t = blockIdx.x * 256 + threadIdx.x;
  int n = t / 10, h = t % 10;
  const float* xr = x1 + (size_t)n * 93;
  float s = 0, d = 0;
  for (int k = 0; k < 93; k++){ float x = xr[k]; s += x * wse1[k * 10 + h]; d += x * wsd1[k * 10 + h]; }
  S1[t] = s; D1[t] = d;
}

// ---------------- weight prep ----------------

// dst[n][k(dK)] = bf16(src[k][n]) for k<K (0 for K<=k<dK); src [K][N] f32
__global__ void k_t2b(const float* __restrict__ src, bf16* __restrict__ dst,
                      int K, int N, int dK, long sZ, long dZ){
  __shared__ float t[32][33];
  src += (size_t)blockIdx.z * sZ;
  dst += (size_t)blockIdx.z * dZ;
  int k0 = blockIdx.y * 32, n0 = blockIdx.x * 32;
  int x = threadIdx.x, y = threadIdx.y;   // 32 x 8
#pragma unroll
  for (int yy = y; yy < 32; yy += 8){
    int k = k0 + yy, n = n0 + x;
    t[yy][x] = (k < K && n < N) ? src[(size_t)k * N + n] : 0.f;
  }
  __syncthreads();
#pragma unroll
  for (int yy = y; yy < 32; yy += 8){
    int n = n0 + yy, k = k0 + x;
    if (n < N && k < dK) dst[(size_t)n * dK + k] = __float2bfloat16(t[x][yy]);
  }
}

// Wvb[i][k][j] = bf16(in_w[i][k][1024+j])   (512x512 slice, row-major)
__global__ void k_prep_wv(const float* __restrict__ in_w, bf16* __restrict__ Wvb){
  int t = blockIdx.x * 256 + threadIdx.x;   // < 2*512*512
  int i = t >> 18, rem = t & 262143, k = rem >> 9, j = rem & 511;
  Wvb[t] = __float2bfloat16(in_w[(size_t)i * 786432 + (size_t)k * 1536 + 1024 + j]);
}

// ---------------- GAT layer 1: softmax + 93-wide aggregate -> bf16 [wid][96] ----------------

__global__ __launch_bounds__(256) void k_gat1(
    const int* __restrict__ offsets, const int* __restrict__ csr_src,
    const int* __restrict__ csr_eid, const float* __restrict__ eattr,
    const float* __restrict__ lattr, const float* __restrict__ S1,
    const float* __restrict__ D1, const float* __restrict__ wee1,
    const float* __restrict__ x1, bf16* __restrict__ xaggp){
  int wid = (blockIdx.x * 256 + threadIdx.x) >> 6;   // n*10+h
  int lane = threadIdx.x & 63;
  int n = wid / 10, h = wid % 10;
  int start = offsets[n], end = offsets[n + 1];
  float dl = D1[wid];
  float wl[11];
#pragma unroll
  for (int j = 0; j < 11; j++) wl[j] = wee1[j * 10 + h];

  float m = -1e30f;
  for (int pos = start + lane; pos < end; pos += 64){
    int s = csr_src[pos]; int eid = csr_eid[pos];
    const float* ea = (eid < EE) ? eattr + (size_t)eid * 11 : lattr + (size_t)(eid - EE) * 11;
    float eel = 0;
#pragma unroll
    for (int j = 0; j < 11; j++) eel += ea[j] * wl[j];
    float lg = S1[s * 10 + h] + dl + eel;
    lg = lg > 0.f ? lg : 0.2f * lg;
    m = fmaxf(m, lg);
  }
  m = warp_max(m);

  float ps = 0;
  for (int pos = start + lane; pos < end; pos += 64){
    int s = csr_src[pos]; int eid = csr_eid[pos];
    const float* ea = (eid < EE) ? eattr + (size_t)eid * 11 : lattr + (size_t)(eid - EE) * 11;
    float eel = 0;
#pragma unroll
    for (int j = 0; j < 11; j++) eel += ea[j] * wl[j];
    float lg = S1[s * 10 + h] + dl + eel;
    lg = lg > 0.f ? lg : 0.2f * lg;
    ps += __expf(lg - m);
  }
  ps = warp_sum(ps);
  float inv = 1.0f / ps;

  float acc0 = 0, acc1 = 0;
  for (int pos = start; pos < end; pos++){
    int s = csr_src[pos]; int eid = csr_eid[pos];
    const float* ea = (eid < EE) ? eattr + (size_t)eid * 11 : lattr + (size_t)(eid - EE) * 11;
    float eel = 0;
#pragma unroll
    for (int j = 0; j < 11; j++) eel += ea[j] * wl[j];
    float lg = S1[s * 10 + h] + dl + eel;
    lg = lg > 0.f ? lg : 0.2f * lg;
    float alpha = __expf(lg - m) * inv;
    const float* xr = x1 + (size_t)s * 93;
    acc0 += alpha * xr[lane];
    if (lane < 29) acc1 += alpha * xr[64 + lane];
  }
  bf16* o = xaggp + (size_t)wid * 96;
  o[lane] = __float2bfloat16(acc0);
  if (lane < 29) o[64 + lane] = __float2bfloat16(acc1);
  else if (lane < 32) o[64 + lane] = __float2bfloat16(0.f);  // pad k=93..95
}

// ---------------- layer-2 node logits (vectorized bf16x8 loads) ----------------

__global__ __launch_bounds__(256) void k_logits2(const bf16* __restrict__ h1,
                                                 const float* __restrict__ w2s,
                                                 const float* __restrict__ w2d,
                                                 float* s2, float* d2){
  int wid = (blockIdx.x * 256 + threadIdx.x) >> 6;
  int lane = threadIdx.x & 63;
  const bf16* hr = h1 + (size_t)wid * 5120;
  float a = 0, b = 0;
#pragma unroll
  for (int g = 0; g < 10; g++){
    int base = (g * 64 + lane) * 8;
    union { uint4 u; unsigned short s[8]; } hv;
    hv.u = *(const uint4*)&hr[base];
    float4 ws0 = *(const float4*)&w2s[base];
    float4 ws1 = *(const float4*)&w2s[base + 4];
    float4 wd0 = *(const float4*)&w2d[base];
    float4 wd1 = *(const float4*)&w2d[base + 4];
    float f0 = bf2f(hv.s[0]), f1 = bf2f(hv.s[1]), f2 = bf2f(hv.s[2]), f3 = bf2f(hv.s[3]);
    float f4 = bf2f(hv.s[4]), f5 = bf2f(hv.s[5]), f6 = bf2f(hv.s[6]), f7 = bf2f(hv.s[7]);
    a += f0 * ws0.x + f1 * ws0.y + f2 * ws0.z + f3 * ws0.w
       + f4 * ws1.x + f5 * ws1.y + f6 * ws1.z + f7 * ws1.w;
    b += f0 * wd0.x + f1 * wd0.y + f2 * wd0.z + f3 * wd0.w
       + f4 * wd1.x + f5 * wd1.y + f6 * wd1.z + f7 * wd1.w;
  }
  a = warp_sum(a); b = warp_sum(b);
  if (lane == 0){ s2[wid] = a; d2[wid] = b; }
}

// ---------------- GAT layer 2 (bf16 xs2, uint4 gathers, c = lane*8+jj) ----------------

__global__ __launch_bounds__(256) void k_gat2(
    const int* __restrict__ offsets, const int* __restrict__ csr_src,
    const int* __restrict__ csr_eid, const float* __restrict__ eattr,
    const float* __restrict__ lattr, const float* __restrict__ s2,
    const float* __restrict__ d2, const float* __restrict__ we2e,
    const bf16* __restrict__ xs2, const float* __restrict__ b2,
    float* __restrict__ h2f, bf16* __restrict__ hbf, float* __restrict__ alpha_out){
  int n = (blockIdx.x * 256 + threadIdx.x) >> 6;
  int lane = threadIdx.x & 63;
  int start = offsets[n], end = offsets[n + 1];
  float dl = d2[n];
  float wl[11];
#pragma unroll
  for (int j = 0; j < 11; j++) wl[j] = we2e[j];

  float m = -1e30f;
  for (int pos = start + lane; pos < end; pos += 64){
    int s = csr_src[pos]; int eid = csr_eid[pos];
    const float* ea = (eid < EE) ? eattr + (size_t)eid * 11 : lattr + (size_t)(eid - EE) * 11;
    float eel = 0;
#pragma unroll
    for (int j = 0; j < 11; j++) eel += ea[j] * wl[j];
    float lg = s2[s] + dl + eel;
    lg = lg > 0.f ? lg : 0.2f * lg;
    m = fmaxf(m, lg);
  }
  m = warp_max(m);

  float ps = 0;
  for (int pos = start + lane; pos < end; pos += 64){
    int s = csr_src[pos]; int eid = csr_eid[pos];
    const float* ea = (eid < EE) ? eattr + (size_t)eid * 11 : lattr + (size_t)(eid - EE) * 11;
    float eel = 0;
#pragma unroll
    for (int j = 0; j < 11; j++) eel += ea[j] * wl[j];
    float lg = s2[s] + dl + eel;
    lg = lg > 0.f ? lg : 0.2f * lg;
    ps += __expf(lg - m);
  }
  ps = warp_sum(ps);
  float inv = 1.0f / ps;

  float acc[8] = {0, 0, 0, 0, 0, 0, 0, 0};
  for (int pos = start; pos < end; pos++){
    int s = csr_src[pos]; int eid = csr_eid[pos];
    const float* ea = (eid < EE) ? eattr + (size_t)eid * 11 : lattr + (size_t)(eid - EE) * 11;
    float eel = 0;
#pragma unroll
    for (int j = 0; j < 11; j++) eel += ea[j] * wl[j];
    float lg = s2[s] + dl + eel;
    lg = lg > 0.f ? lg : 0.2f * lg;
    float alpha = __expf(lg - m) * inv;
    if (lane == 0) alpha_out[eid] = alpha;
    union { uint4 u; unsigned short sh[8]; } xv;
    xv.u = *(const uint4*)&xs2[(size_t)s * 512 + lane * 8];
#pragma unroll
    for (int jj = 0; jj < 8; jj++) acc[jj] += alpha * bf2f(xv.sh[jj]);
  }
#pragma unroll
  for (int jj = 0; jj < 8; jj++){
    int c = lane * 8 + jj;
    float v = acc[jj] + b2[c];
    v = v > 0.f ? v : (__expf(v) - 1.f);
    h2f[(size_t)n * 512 + c] = v;
    hbf[(size_t)n * 512 + c] = __float2bfloat16(v);
  }
}

// ---------------- MFMA bf16 GEMM: C = act(A @ Bt^T + bias + res) ----------------
// A [M,K] bf16 (lda), Bt [N,K] bf16 (ld = K), C [M,ldc]. K%32==0, M%BM==0, N%BN==0.
// m97 structure + bijective XCD block swizzle (grid.x*grid.y must be %8==0).

__device__ __forceinline__ void stC_elem(float* p, float v){ *p = v; }
__device__ __forceinline__ void stC_elem(bf16* p, float v){ *p = __float2bfloat16(v); }

template <int BMF, int BNF, int ACT, bool BIAS, bool RES, typename TC>
__global__ __launch_bounds__(256) void k_mm(
    const bf16* __restrict__ A, const bf16* __restrict__ Bt,
    const float* __restrict__ bias, const float* __restrict__ res,
    TC* __restrict__ C, int M, int K, int lda, int ldc,
    long aZ, long bZ, long cZ, long biasZ){
  constexpr int BM = BMF * 32, BN = BNF * 32;
  __shared__ __align__(16) bf16 As[BM * 32];
  __shared__ __align__(16) bf16 Bs[BN * 32];
  const int tid = threadIdx.x, wave = tid >> 6, lane = tid & 63;

  // XCD-aware bijective swizzle over the 2D grid
  const int nwg = gridDim.x * gridDim.y;
  const int id = blockIdx.y * gridDim.x + blockIdx.x;
  const int cpx = nwg >> 3;
  const int swz = (id & 7) * cpx + (id >> 3);
  const int bm = (swz / gridDim.x) * BM, bn = (swz % gridDim.x) * BN;

  const int z = blockIdx.z;
  A  += (size_t)z * aZ;
  Bt += (size_t)z * bZ;
  C  += (size_t)z * cZ;
  const float* bp = BIAS ? bias + (size_t)z * biasZ : nullptr;

  const int trow = tid >> 2, tk = (tid & 3) * 8;   // staging: 16B per thread
  const int wr = (wave >> 1) * (BMF * 16), wc = (wave & 1) * (BNF * 16);
  const int r = lane & 15, kq = lane >> 4;

  fv4 acc[BMF][BNF] = {};

  for (int k0 = 0; k0 < K; k0 += 32){
#pragma unroll
    for (int s = 0; s < BM / 64; s++)
      gl_lds16(A + (size_t)(bm + s * 64 + trow) * lda + k0 + tk,
               (char*)As + s * 4096 + wave * 1024, lane);
#pragma unroll
    for (int s = 0; s < BN / 64; s++)
      gl_lds16(Bt + (size_t)(bn + s * 64 + trow) * K + k0 + tk,
               (char*)Bs + s * 4096 + wave * 1024, lane);
    __syncthreads();

    bfv8 a[BMF], b[BNF];
#pragma unroll
    for (int i = 0; i < BMF; i++)
      a[i] = *(const bfv8*)&As[(wr + i * 16 + r) * 32 + kq * 8];
#pragma unroll
    for (int j = 0; j < BNF; j++)
      b[j] = *(const bfv8*)&Bs[(wc + j * 16 + r) * 32 + kq * 8];
#pragma unroll
    for (int i = 0; i < BMF; i++)
#pragma unroll
      for (int j = 0; j < BNF; j++)
        acc[i][j] = __builtin_amdgcn_mfma_f32_16x16x32_bf16(a[i], b[j], acc[i][j], 0, 0, 0);
    __syncthreads();
  }

  // C/D layout: col = lane&15, row = (lane>>4)*4 + q
  const int rb = bm + wr + (lane >> 4) * 4;
  const int cb = bn + wc + (lane & 15);
#pragma unroll
  for (int i = 0; i < BMF; i++)
#pragma unroll
    for (int j = 0; j < BNF; j++){
      int gn = cb + j * 16;
      float bv = BIAS ? bp[gn] : 0.f;
#pragma unroll
      for (int q = 0; q < 4; q++){
        int gm = rb + i * 16 + q;
        float v = acc[i][j][q] + bv;
        if (RES) v += res[(size_t)gm * ldc + gn];
        if (ACT == 1) v = fmaxf(v, 0.f);
        if (ACT == 2) v = v > 0.f ? v : (__expf(v) - 1.f);
        stC_elem(&C[(size_t)gm * ldc + gn], v);
      }
    }
}

// ---------------- misc: bvo fold, layernorm (dual out), pool ----------------

__global__ void k_bvo(const float* __restrict__ in_b, const float* __restrict__ out_w,
                      const float* __restrict__ out_b, float* bvo){
  int t = blockIdx.x * 256 + threadIdx.x;
  if (t >= 1024) return;
  int i = t >> 9, c = t & 511;
  const float* ib = in_b + i * 1536 + 1024;
  const float* ow = out_w + (size_t)i * 262144;
  float s = out_b[i * 512 + c];
  for (int k = 0; k < 512; k++) s += ib[k] * ow[(size_t)k * 512 + c];
  bvo[t] = s;
}

__global__ __launch_bounds__(256) void k_ln(const float* __restrict__ x,
                                            const float* __restrict__ g,
                                            const float* __restrict__ b,
                                            float* __restrict__ yf,
                                            bf16* __restrict__ ybf){
  int wid = (blockIdx.x * 256 + threadIdx.x) >> 6;
  int lane = threadIdx.x & 63;
  const float* xr = x + (size_t)wid * 512;
  float v[8];
  float s = 0;
#pragma unroll
  for (int j = 0; j < 8; j++){ v[j] = xr[lane + j * 64]; s += v[j]; }
  s = warp_sum(s);
  float mu = s * (1.0f / 512.0f);
  float var = 0;
#pragma unroll
  for (int j = 0; j < 8; j++){ float d = v[j] - mu; var += d * d; }
  var = warp_sum(var) * (1.0f / 512.0f);
  float inv = rsqrtf(var + 1e-5f);
#pragma unroll
  for (int j = 0; j < 8; j++){
    int c = lane + j * 64;
    float o = (v[j] - mu) * inv * g[c] + b[c];
    yf[(size_t)wid * 512 + c] = o;
    ybf[(size_t)wid * 512 + c] = __float2bfloat16(o);
  }
}

__global__ void k_pool(const float* __restrict__ h, float* __restrict__ out){
  int b = blockIdx.x;
  int c = threadIdx.x;   // 512 threads
  const float* hr = h + (size_t)b * 64 * 512;
  float m = -1e30f;
  for (int i = 0; i < 64; i++) m = fmaxf(m, hr[i * 512 + c]);
  out[(size_t)b * 512 + c] = m;
}

// ---------------- launcher ----------------

extern "C" void kernel_launch(void* const* d_in, const int* in_sizes, int n_in,
                              void* d_out, int out_size, void* d_ws, size_t ws_size,
                              hipStream_t stream){
  const float* x1    = (const float*)d_in[0];
  const int*   ei    = (const int*)d_in[1];
  const float* eattr = (const float*)d_in[2];
  const float* W1    = (const float*)d_in[4];
  const float* as1   = (const float*)d_in[5];
  const float* ad1   = (const float*)d_in[6];
  const float* We1   = (const float*)d_in[7];
  const float* ae1   = (const float*)d_in[8];
  const float* b1    = (const float*)d_in[9];
  const float* W2    = (const float*)d_in[10];
  const float* as2   = (const float*)d_in[11];
  const float* ad2   = (const float*)d_in[12];
  const float* We2   = (const float*)d_in[13];
  const float* ae2   = (const float*)d_in[14];
  const float* b2    = (const float*)d_in[15];
  const float* in_w  = (const float*)d_in[16];
  const float* in_b  = (const float*)d_in[17];
  const float* out_w = (const float*)d_in[18];
  const float* out_b = (const float*)d_in[19];
  const float* ln1g  = (const float*)d_in[20];
  const float* ln1b  = (const float*)d_in[21];
  const float* f1w   = (const float*)d_in[22];
  const float* f1b   = (const float*)d_in[23];
  const float* f2w   = (const float*)d_in[24];
  const float* f2b   = (const float*)d_in[25];
  const float* ln2g  = (const float*)d_in[26];
  const float* ln2b  = (const float*)d_in[27];

  const int* src0 = ei;
  const int* dst0 = ei + EE;

  char* p = (char*)d_ws;
  auto alloc = [&](size_t bytes) -> void* {
    void* r = p;
    p += (bytes + 255) & ~(size_t)255;
    return r;
  };
  float* esum    = (float*)alloc(NN * 11 * 4);
  float* lattr   = (float*)alloc(NN * 11 * 4);
  int*   deg     = (int*)alloc(NN * 4);
  int*   offsets = (int*)alloc((NN + 1) * 4);
  int*   cursor  = (int*)alloc(NN * 4);
  int*   csr_src = (int*)alloc(ET * 4);
  int*   csr_eid = (int*)alloc(ET * 4);
  float* wse1    = (float*)alloc(930 * 4);
  float* wsd1    = (float*)alloc(930 * 4);
  float* wee1    = (float*)alloc(110 * 4);
  float* S1      = (float*)alloc(NN * 10 * 4);
  float* D1b     = (float*)alloc(NN * 10 * 4);
  bf16*  xaggp   = (bf16*)alloc((size_t)NN * 10 * 96 * 2);
  bf16*  W1t     = (bf16*)alloc((size_t)5120 * 96 * 2);
  bf16*  W2t     = (bf16*)alloc((size_t)512 * 5120 * 2);
  bf16*  f1wt    = (bf16*)alloc((size_t)2 * 2048 * 512 * 2);
  bf16*  f2wt    = (bf16*)alloc((size_t)2 * 512 * 2048 * 2);
  bf16*  Wvb     = (bf16*)alloc((size_t)2 * 512 * 512 * 2);
  bf16*  WoT     = (bf16*)alloc((size_t)2 * 512 * 512 * 2);
  bf16*  Wvot    = (bf16*)alloc((size_t)2 * 512 * 512 * 2);
  bf16*  h1      = (bf16*)alloc((size_t)NN * 5120 * 2);   // dead after xs2+logits2; reused below
  float* w2s     = (float*)alloc(5120 * 4);
  float* w2d     = (float*)alloc(5120 * 4);
  float* we2e    = (float*)alloc(16 * 4);
  float* s2      = (float*)alloc(NN * 4);
  float* d2v     = (float*)alloc(NN * 4);
  bf16*  xs2     = (bf16*)alloc((size_t)NN * 512 * 2);
  float* h2f     = (float*)alloc((size_t)NN * 512 * 4);
  bf16*  hbf     = (bf16*)alloc((size_t)NN * 512 * 2);
  float* bvo     = (float*)alloc(2 * 512 * 4);
  // aliases into dead h1 region (40 MB): tmp (8 MB) + fbuf (16 MB)
  float* tmp  = (float*)h1;
  bf16*  fbuf = (bf16*)((char*)h1 + (size_t)NN * 512 * 4);

  float* out_pool = (float*)d_out;
  float* alpha2   = out_pool + 64 * 512;

  hipMemsetAsync(deg, 0, NN * 4, stream);
  hipMemsetAsync(esum, 0, NN * 11 * 4, stream);
  hipMemsetAsync(cursor, 0, NN * 4, stream);

  // graph prep + logit folds
  k_deg_esum<<<EE / 256, 256, 0, stream>>>(dst0, eattr, deg, esum);
  k_loop_attr<<<NN / 256, 256, 0, stream>>>(esum, deg, lattr);
  k_scan<<<1, 256, 0, stream>>>(deg, offsets);
  k_scatter<<<(EE + NN) / 256, 256, 0, stream>>>(src0, dst0, offsets, cursor, csr_src, csr_eid);
  k_fold1<<<5, 256, 0, stream>>>(W1, as1, ad1, We1, ae1, wse1, wsd1, wee1);
  k_fold2<<<21, 256, 0, stream>>>(W2, as2, ad2, We2, ae2, w2s, w2d, we2e);
  k_logits1<<<160, 256, 0, stream>>>(x1, wse1, wsd1, S1, D1b);

  // weight preps
  k_t2b<<<dim3(160, 3, 1), dim3(32, 8), 0, stream>>>(W1, W1t, 93, 5120, 96, 0, 0);
  k_t2b<<<dim3(16, 160, 1), dim3(32, 8), 0, stream>>>(W2, W2t, 5120, 512, 5120, 0, 0);
  k_t2b<<<dim3(64, 16, 2), dim3(32, 8), 0, stream>>>(f1w, f1wt, 512, 2048, 512,
                                                     512L * 2048, 2048L * 512);
  k_t2b<<<dim3(16, 64, 2), dim3(32, 8), 0, stream>>>(f2w, f2wt, 2048, 512, 2048,
                                                     2048L * 512, 512L * 2048);
  k_prep_wv<<<2048, 256, 0, stream>>>(in_w, Wvb);
  k_t2b<<<dim3(16, 16, 2), dim3(32, 8), 0, stream>>>(out_w, WoT, 512, 512, 512,
                                                     262144, 262144);
  // Wvot[n][k] = sum_j WoT[n][j] * Wvb[k][j]  (bf16 out, = (Wv@Wo)^T)
  k_mm<4, 4, 0, false, false, bf16><<<dim3(4, 4, 2), 256, 0, stream>>>(
      WoT, Wvb, nullptr, nullptr, Wvot, 512, 512, 512, 512,
      262144, 262144, 262144, 0);
  k_bvo<<<4, 256, 0, stream>>>(in_b, out_w, out_b, bvo);

  // GAT-1: aggregate 93-wide, then project per-head with MFMA
  k_gat1<<<(NN * 10) / 4, 256, 0, stream>>>(offsets, csr_src, csr_eid, eattr, lattr,
                                            S1, D1b, wee1, x1, xaggp);
  // h1 = elu(xagg @ W1 + b1): z=10 heads, M=4096, N=512, K=96
  k_mm<4, 4, 2, true, false, bf16><<<dim3(4, 32, 10), 256, 0, stream>>>(
      xaggp, W1t, b1, nullptr, h1, NN, 96, 960, 5120, 96, 512L * 96, 512, 512);

  k_logits2<<<NN / 4, 256, 0, stream>>>(h1, w2s, w2d, s2, d2v);
  // xs2 = h1 @ W2 (bf16 out): M=4096, N=512, K=5120
  k_mm<2, 4, 0, false, false, bf16><<<dim3(4, 64, 1), 256, 0, stream>>>(
      h1, W2t, nullptr, nullptr, xs2, NN, 5120, 5120, 512, 0, 0, 0, 0);
  k_gat2<<<NN / 4, 256, 0, stream>>>(offsets, csr_src, csr_eid, eattr, lattr,
                                     s2, d2v, we2e, xs2, b2, h2f, hbf, alpha2);

  for (int i = 0; i < 2; i++){
    // tmp = h2 + h2 @ Wvo + bvo   (A = bf16 h, res = f32 h)
    k_mm<2, 4, 0, true, true, float><<<dim3(4, 64, 1), 256, 0, stream>>>(
        hbf, Wvot + (size_t)i * 262144, bvo + i * 512, h2f, tmp,
        NN, 512, 512, 512, 0, 0, 0, 0);
    k_ln<<<NN / 4, 256, 0, stream>>>(tmp, ln1g + i * 512, ln1b + i * 512, h2f, hbf);
    // fbuf = relu(h @ f1w + f1b): N=2048, K=512
    k_mm<4, 4, 1, true, false, bf16><<<dim3(16, 32, 1), 256, 0, stream>>>(
        hbf, f1wt + (size_t)i * 2048 * 512, f1b + i * 2048, nullptr, fbuf,
        NN, 512, 512, 2048, 0, 0, 0, 0);
    // tmp = h + fbuf @ f2w + f2b: N=512, K=2048
    k_mm<2, 4, 0, true, true, float><<<dim3(4, 64, 1), 256, 0, stream>>>(
        fbuf, f2wt + (size_t)i * 512 * 2048, f2b + i * 512, h2f, tmp,
        NN, 2048, 2048, 512, 0, 0, 0, 0);
    k_ln<<<NN / 4, 256, 0, stream>>>(tmp, ln2g + i * 512, ln2b + i * 512, h2f, hbf);
  }

  k_pool<<<64, 512, 0, stream>>>(h2f, out_pool);
}

// Round 5
// 594.329 us; speedup vs baseline: 4.2935x; 1.1202x over previous
//
#include <hip/hip_runtime.h>
#include <hip/hip_bf16.h>

#define NN 4096
#define EE 16384
#define ET 20480   // EE + NN

typedef __hip_bfloat16 bf16;
typedef __bf16 bfv8 __attribute__((ext_vector_type(8)));
typedef float fv4 __attribute__((ext_vector_type(4)));

__device__ __forceinline__ float warp_max(float v){
#pragma unroll
  for (int o = 32; o; o >>= 1) v = fmaxf(v, __shfl_xor(v, o));
  return v;
}
__device__ __forceinline__ float warp_sum(float v){
#pragma unroll
  for (int o = 32; o; o >>= 1) v += __shfl_xor(v, o);
  return v;
}
__device__ __forceinline__ float bf2f(unsigned short u){
  return __uint_as_float((unsigned)u << 16);
}

// async global->LDS, 16B per lane. lbase = wave-uniform LDS base (lane*16 added by HW).
__device__ __forceinline__ void gl_lds16(const void* g, void* lbase, int lane){
#if __has_builtin(__builtin_amdgcn_global_load_lds)
  __builtin_amdgcn_global_load_lds(
      (const __attribute__((address_space(1))) unsigned int*)g,
      (__attribute__((address_space(3))) unsigned int*)lbase, 16, 0, 0);
#else
  *(uint4*)((char*)lbase + lane * 16) = *(const uint4*)g;
#endif
}

// ---------------- graph preprocessing ----------------

__global__ void k_deg_esum(const int* __restrict__ dst0, const float* __restrict__ eattr,
                           int* deg, float* esum){
  int e = blockIdx.x * 256 + threadIdx.x;
  if (e >= EE) return;
  int d = dst0[e];
  atomicAdd(&deg[d], 1);
  const float* ar = eattr + (size_t)e * 11;
  float* er = esum + (size_t)d * 11;
#pragma unroll
  for (int j = 0; j < 11; j++) atomicAdd(&er[j], ar[j]);
}

__global__ void k_loop_attr(const float* __restrict__ esum, const int* __restrict__ deg,
                            float* lattr){
  int n = blockIdx.x * 256 + threadIdx.x;
  if (n >= NN) return;
  float c = fmaxf((float)deg[n], 1.0f);
#pragma unroll
  for (int j = 0; j < 11; j++) lattr[n * 11 + j] = esum[n * 11 + j] / c;
}

__global__ void k_scan(const int* __restrict__ deg, int* offsets){
  __shared__ int sums[256];
  int t = threadIdx.x;
  int base = t * 16;
  int vals[16];
  int s = 0;
#pragma unroll
  for (int j = 0; j < 16; j++){ vals[j] = s; s += deg[base + j] + 1; }
  sums[t] = s;
  __syncthreads();
  for (int off = 1; off < 256; off <<= 1){
    int v = (t >= off) ? sums[t - off] : 0;
    __syncthreads();
    sums[t] += v;
    __syncthreads();
  }
  int pre = (t == 0) ? 0 : sums[t - 1];
#pragma unroll
  for (int j = 0; j < 16; j++) offsets[base + j] = pre + vals[j];
  if (t == 255) offsets[NN] = sums[255];
}

__global__ void k_scatter(const int* __restrict__ src0, const int* __restrict__ dst0,
                          const int* __restrict__ offsets, int* cursor,
                          int* csr_src, int* csr_eid){
  int t = blockIdx.x * 256 + threadIdx.x;
  if (t < EE){
    int d = dst0[t];
    int pos = offsets[d] + atomicAdd(&cursor[d], 1);
    csr_src[pos] = src0[t];
    csr_eid[pos] = t;
  } else if (t < EE + NN){
    int n = t - EE;
    int pos = offsets[n + 1] - 1;
    csr_src[pos] = n;
    csr_eid[pos] = EE + n;
  }
}

// ---------------- folded attention weight vectors ----------------

__global__ void k_fold1(const float* __restrict__ W1, const float* __restrict__ as1,
                        const float* __restrict__ ad1, const float* __restrict__ We1,
                        const float* __restrict__ ae1,
                        float* wse1, float* wsd1, float* wee1){
  int t = blockIdx.x * 256 + threadIdx.x;
  if (t < 930){
    int k = t / 10, h = t % 10;
    const float* wr = W1 + (size_t)k * 5120 + h * 512;
    const float* asr = as1 + h * 512;
    const float* adr = ad1 + h * 512;
    float ss = 0, sd = 0;
    for (int c = 0; c < 512; c++){ float w = wr[c]; ss += w * asr[c]; sd += w * adr[c]; }
    wse1[t] = ss; wsd1[t] = sd;
  } else if (t < 1040){
    int u = t - 930;
    int k = u / 10, h = u % 10;
    const float* wr = We1 + (size_t)k * 5120 + h * 512;
    const float* aer = ae1 + h * 512;
    float se = 0;
    for (int c = 0; c < 512; c++) se += wr[c] * aer[c];
    wee1[u] = se;
  }
}

__global__ void k_fold2(const float* __restrict__ W2, const float* __restrict__ as2,
                        const float* __restrict__ ad2, const float* __restrict__ We2,
                        const float* __restrict__ ae2,
                        float* w2s, float* w2d, float* we2e){
  int t = blockIdx.x * 256 + threadIdx.x;
  if (t < 5120){
    const float* wr = W2 + (size_t)t * 512;
    float ss = 0, sd = 0;
    for (int c = 0; c < 512; c++){ float w = wr[c]; ss += w * as2[c]; sd += w * ad2[c]; }
    w2s[t] = ss; w2d[t] = sd;
  } else if (t < 5131){
    int k = t - 5120;
    const float* wr = We2 + (size_t)k * 512;
    float se = 0;
    for (int c = 0; c < 512; c++) se += wr[c] * ae2[c];
    we2e[k] = se;
  }
}

__global__ void k_logits1(const float* __restrict__ x1, const float* __restrict__ wse1,
                          const float* __restrict__ wsd1, float* S1, float* D1){
  int t = blockIdx.x * 256 + threadIdx.x;
  int n = t / 10, h = t % 10;
  const float* xr = x1 + (size_t)n * 93;
  float s = 0, d = 0;
  for (int k = 0; k < 93; k++){ float x = xr[k]; s += x * wse1[k * 10 + h]; d += x * wsd1[k * 10 + h]; }
  S1[t] = s; D1[t] = d;
}

// ---------------- weight prep ----------------

// dst[n][k(dK)] = bf16(src[k][n]) for k<K (0 for K<=k<dK); src [K][N] f32
__global__ void k_t2b(const float* __restrict__ src, bf16* __restrict__ dst,
                      int K, int N, int dK, long sZ, long dZ){
  __shared__ float t[32][33];
  src += (size_t)blockIdx.z * sZ;
  dst += (size_t)blockIdx.z * dZ;
  int k0 = blockIdx.y * 32, n0 = blockIdx.x * 32;
  int x = threadIdx.x, y = threadIdx.y;   // 32 x 8
#pragma unroll
  for (int yy = y; yy < 32; yy += 8){
    int k = k0 + yy, n = n0 + x;
    t[yy][x] = (k < K && n < N) ? src[(size_t)k * N + n] : 0.f;
  }
  __syncthreads();
#pragma unroll
  for (int yy = y; yy < 32; yy += 8){
    int n = n0 + yy, k = k0 + x;
    if (n < N && k < dK) dst[(size_t)n * dK + k] = __float2bfloat16(t[x][yy]);
  }
}

// Wvb[i][k][j] = bf16(in_w[i][k][1024+j])   (512x512 slice, row-major)
__global__ void k_prep_wv(const float* __restrict__ in_w, bf16* __restrict__ Wvb){
  int t = blockIdx.x * 256 + threadIdx.x;   // < 2*512*512
  int i = t >> 18, rem = t & 262143, k = rem >> 9, j = rem & 511;
  Wvb[t] = __float2bfloat16(in_w[(size_t)i * 786432 + (size_t)k * 1536 + 1024 + j]);
}

// ---------------- GAT layer 1: softmax + 93-wide aggregate -> bf16 [wid][96] ----------------

__global__ __launch_bounds__(256) void k_gat1(
    const int* __restrict__ offsets, const int* __restrict__ csr_src,
    const int* __restrict__ csr_eid, const float* __restrict__ eattr,
    const float* __restrict__ lattr, const float* __restrict__ S1,
    const float* __restrict__ D1, const float* __restrict__ wee1,
    const float* __restrict__ x1, bf16* __restrict__ xaggp){
  int wid = (blockIdx.x * 256 + threadIdx.x) >> 6;   // n*10+h
  int lane = threadIdx.x & 63;
  int n = wid / 10, h = wid % 10;
  int start = offsets[n], end = offsets[n + 1];
  float dl = D1[wid];
  float wl[11];
#pragma unroll
  for (int j = 0; j < 11; j++) wl[j] = wee1[j * 10 + h];

  float m = -1e30f;
  for (int pos = start + lane; pos < end; pos += 64){
    int s = csr_src[pos]; int eid = csr_eid[pos];
    const float* ea = (eid < EE) ? eattr + (size_t)eid * 11 : lattr + (size_t)(eid - EE) * 11;
    float eel = 0;
#pragma unroll
    for (int j = 0; j < 11; j++) eel += ea[j] * wl[j];
    float lg = S1[s * 10 + h] + dl + eel;
    lg = lg > 0.f ? lg : 0.2f * lg;
    m = fmaxf(m, lg);
  }
  m = warp_max(m);

  float ps = 0;
  for (int pos = start + lane; pos < end; pos += 64){
    int s = csr_src[pos]; int eid = csr_eid[pos];
    const float* ea = (eid < EE) ? eattr + (size_t)eid * 11 : lattr + (size_t)(eid - EE) * 11;
    float eel = 0;
#pragma unroll
    for (int j = 0; j < 11; j++) eel += ea[j] * wl[j];
    float lg = S1[s * 10 + h] + dl + eel;
    lg = lg > 0.f ? lg : 0.2f * lg;
    ps += __expf(lg - m);
  }
  ps = warp_sum(ps);
  float inv = 1.0f / ps;

  float acc0 = 0, acc1 = 0;
  for (int pos = start; pos < end; pos++){
    int s = csr_src[pos]; int eid = csr_eid[pos];
    const float* ea = (eid < EE) ? eattr + (size_t)eid * 11 : lattr + (size_t)(eid - EE) * 11;
    float eel = 0;
#pragma unroll
    for (int j = 0; j < 11; j++) eel += ea[j] * wl[j];
    float lg = S1[s * 10 + h] + dl + eel;
    lg = lg > 0.f ? lg : 0.2f * lg;
    float alpha = __expf(lg - m) * inv;
    const float* xr = x1 + (size_t)s * 93;
    acc0 += alpha * xr[lane];
    if (lane < 29) acc1 += alpha * xr[64 + lane];
  }
  bf16* o = xaggp + (size_t)wid * 96;
  o[lane] = __float2bfloat16(acc0);
  if (lane < 29) o[64 + lane] = __float2bfloat16(acc1);
  else if (lane < 32) o[64 + lane] = __float2bfloat16(0.f);  // pad k=93..95
}

// ---------------- layer-2 node logits (vectorized bf16x8 loads) ----------------

__global__ __launch_bounds__(256) void k_logits2(const bf16* __restrict__ h1,
                                                 const float* __restrict__ w2s,
                                                 const float* __restrict__ w2d,
                                                 float* s2, float* d2){
  int wid = (blockIdx.x * 256 + threadIdx.x) >> 6;
  int lane = threadIdx.x & 63;
  const bf16* hr = h1 + (size_t)wid * 5120;
  float a = 0, b = 0;
#pragma unroll
  for (int g = 0; g < 10; g++){
    int base = (g * 64 + lane) * 8;
    union { uint4 u; unsigned short s[8]; } hv;
    hv.u = *(const uint4*)&hr[base];
    float4 ws0 = *(const float4*)&w2s[base];
    float4 ws1 = *(const float4*)&w2s[base + 4];
    float4 wd0 = *(const float4*)&w2d[base];
    float4 wd1 = *(const float4*)&w2d[base + 4];
    float f0 = bf2f(hv.s[0]), f1 = bf2f(hv.s[1]), f2 = bf2f(hv.s[2]), f3 = bf2f(hv.s[3]);
    float f4 = bf2f(hv.s[4]), f5 = bf2f(hv.s[5]), f6 = bf2f(hv.s[6]), f7 = bf2f(hv.s[7]);
    a += f0 * ws0.x + f1 * ws0.y + f2 * ws0.z + f3 * ws0.w
       + f4 * ws1.x + f5 * ws1.y + f6 * ws1.z + f7 * ws1.w;
    b += f0 * wd0.x + f1 * wd0.y + f2 * wd0.z + f3 * wd0.w
       + f4 * wd1.x + f5 * wd1.y + f6 * wd1.z + f7 * wd1.w;
  }
  a = warp_sum(a); b = warp_sum(b);
  if (lane == 0){ s2[wid] = a; d2[wid] = b; }
}

// ---------------- GAT layer 2 (bf16 xs2, uint4 gathers) ----------------

__global__ __launch_bounds__(256) void k_gat2(
    const int* __restrict__ offsets, const int* __restrict__ csr_src,
    const int* __restrict__ csr_eid, const float* __restrict__ eattr,
    const float* __restrict__ lattr, const float* __restrict__ s2,
    const float* __restrict__ d2, const float* __restrict__ we2e,
    const bf16* __restrict__ xs2, const float* __restrict__ b2,
    float* __restrict__ h2f, bf16* __restrict__ hbf, float* __restrict__ alpha_out){
  int n = (blockIdx.x * 256 + threadIdx.x) >> 6;
  int lane = threadIdx.x & 63;
  int start = offsets[n], end = offsets[n + 1];
  float dl = d2[n];
  float wl[11];
#pragma unroll
  for (int j = 0; j < 11; j++) wl[j] = we2e[j];

  float m = -1e30f;
  for (int pos = start + lane; pos < end; pos += 64){
    int s = csr_src[pos]; int eid = csr_eid[pos];
    const float* ea = (eid < EE) ? eattr + (size_t)eid * 11 : lattr + (size_t)(eid - EE) * 11;
    float eel = 0;
#pragma unroll
    for (int j = 0; j < 11; j++) eel += ea[j] * wl[j];
    float lg = s2[s] + dl + eel;
    lg = lg > 0.f ? lg : 0.2f * lg;
    m = fmaxf(m, lg);
  }
  m = warp_max(m);

  float ps = 0;
  for (int pos = start + lane; pos < end; pos += 64){
    int s = csr_src[pos]; int eid = csr_eid[pos];
    const float* ea = (eid < EE) ? eattr + (size_t)eid * 11 : lattr + (size_t)(eid - EE) * 11;
    float eel = 0;
#pragma unroll
    for (int j = 0; j < 11; j++) eel += ea[j] * wl[j];
    float lg = s2[s] + dl + eel;
    lg = lg > 0.f ? lg : 0.2f * lg;
    ps += __expf(lg - m);
  }
  ps = warp_sum(ps);
  float inv = 1.0f / ps;

  float acc[8] = {0, 0, 0, 0, 0, 0, 0, 0};
  for (int pos = start; pos < end; pos++){
    int s = csr_src[pos]; int eid = csr_eid[pos];
    const float* ea = (eid < EE) ? eattr + (size_t)eid * 11 : lattr + (size_t)(eid - EE) * 11;
    float eel = 0;
#pragma unroll
    for (int j = 0; j < 11; j++) eel += ea[j] * wl[j];
    float lg = s2[s] + dl + eel;
    lg = lg > 0.f ? lg : 0.2f * lg;
    float alpha = __expf(lg - m) * inv;
    if (lane == 0) alpha_out[eid] = alpha;
    union { uint4 u; unsigned short sh[8]; } xv;
    xv.u = *(const uint4*)&xs2[(size_t)s * 512 + lane * 8];
#pragma unroll
    for (int jj = 0; jj < 8; jj++) acc[jj] += alpha * bf2f(xv.sh[jj]);
  }
#pragma unroll
  for (int jj = 0; jj < 8; jj++){
    int c = lane * 8 + jj;
    float v = acc[jj] + b2[c];
    v = v > 0.f ? v : (__expf(v) - 1.f);
    h2f[(size_t)n * 512 + c] = v;
    hbf[(size_t)n * 512 + c] = __float2bfloat16(v);
  }
}

// ---------------- MFMA bf16 GEMM: C = act(A @ Bt^T + bias + res) ----------------
// A [M,K+] bf16 (row stride lda), Bt [N,K+] bf16 (row stride ldb), C [M,ldc].
// K%32==0. z-dim: offsets aZ/bZ (elements) shift A/Bt (used for batching AND
// split-K: aZ=bZ=Kc gives k-window [z*Kc,(z+1)*Kc)), cZ shifts C.
// Double-buffered LDS, one barrier per K-step (prefetch next tile after barrier).
// Bijective XCD swizzle over 2D grid (gridDim.x*gridDim.y % 8 == 0).

__device__ __forceinline__ void stC_elem(float* p, float v){ *p = v; }
__device__ __forceinline__ void stC_elem(bf16* p, float v){ *p = __float2bfloat16(v); }

template <int BMF, int BNF, int ACT, bool BIAS, bool RES, typename TC>
__global__ __launch_bounds__(256) void k_mm(
    const bf16* __restrict__ A, const bf16* __restrict__ Bt,
    const float* __restrict__ bias, const float* __restrict__ res,
    TC* __restrict__ C, int M, int K, int lda, int ldb, int ldc,
    long aZ, long bZ, long cZ, long biasZ){
  constexpr int BM = BMF * 32, BN = BNF * 32;
  __shared__ __align__(16) bf16 As[2][BM * 32];
  __shared__ __align__(16) bf16 Bs[2][BN * 32];
  const int tid = threadIdx.x, wave = tid >> 6, lane = tid & 63;

  // XCD-aware bijective swizzle over the 2D grid
  const int nwg = gridDim.x * gridDim.y;
  const int id = blockIdx.y * gridDim.x + blockIdx.x;
  const int cpx = nwg >> 3;
  const int swz = (id & 7) * cpx + (id >> 3);
  const int bm = (swz / gridDim.x) * BM, bn = (swz % gridDim.x) * BN;

  const int z = blockIdx.z;
  A  += (size_t)z * aZ;
  Bt += (size_t)z * bZ;
  C  += (size_t)z * cZ;
  const float* bp = BIAS ? bias + (size_t)z * biasZ : nullptr;

  const int trow = tid >> 2, tk = (tid & 3) * 8;   // staging: 16B per thread
  const int wr = (wave >> 1) * (BMF * 16), wc = (wave & 1) * (BNF * 16);
  const int r = lane & 15, kq = lane >> 4;

  fv4 acc[BMF][BNF] = {};

  auto STAGE = [&](int buf, int k0){
#pragma unroll
    for (int s = 0; s < BM / 64; s++)
      gl_lds16(A + (size_t)(bm + s * 64 + trow) * lda + k0 + tk,
               (char*)&As[buf][0] + s * 4096 + wave * 1024, lane);
#pragma unroll
    for (int s = 0; s < BN / 64; s++)
      gl_lds16(Bt + (size_t)(bn + s * 64 + trow) * ldb + k0 + tk,
               (char*)&Bs[buf][0] + s * 4096 + wave * 1024, lane);
  };

  STAGE(0, 0);
  int cur = 0;
  for (int k0 = 0; k0 < K; k0 += 32){
    __syncthreads();           // vmcnt(0)+lgkmcnt(0)+barrier: buf[cur] staged, prev reads done
    if (k0 + 32 < K) STAGE(cur ^ 1, k0 + 32);   // async prefetch flies under compute

    bfv8 a[BMF], b[BNF];
#pragma unroll
    for (int i = 0; i < BMF; i++)
      a[i] = *(const bfv8*)&As[cur][(wr + i * 16 + r) * 32 + kq * 8];
#pragma unroll
    for (int j = 0; j < BNF; j++)
      b[j] = *(const bfv8*)&Bs[cur][(wc + j * 16 + r) * 32 + kq * 8];
#pragma unroll
    for (int i = 0; i < BMF; i++)
#pragma unroll
      for (int j = 0; j < BNF; j++)
        acc[i][j] = __builtin_amdgcn_mfma_f32_16x16x32_bf16(a[i], b[j], acc[i][j], 0, 0, 0);
    cur ^= 1;
  }

  // C/D layout: col = lane&15, row = (lane>>4)*4 + q
  const int rb = bm + wr + (lane >> 4) * 4;
  const int cb = bn + wc + (lane & 15);
#pragma unroll
  for (int i = 0; i < BMF; i++)
#pragma unroll
    for (int j = 0; j < BNF; j++){
      int gn = cb + j * 16;
      float bv = BIAS ? bp[gn] : 0.f;
#pragma unroll
      for (int q = 0; q < 4; q++){
        int gm = rb + i * 16 + q;
        float v = acc[i][j][q] + bv;
        if (RES) v += res[(size_t)gm * ldc + gn];
        if (ACT == 1) v = fmaxf(v, 0.f);
        if (ACT == 2) v = v > 0.f ? v : (__expf(v) - 1.f);
        stC_elem(&C[(size_t)gm * ldc + gn], v);
      }
    }
}

// ---------------- split-K reduce: out = bf16(pA + pB) ----------------

__global__ void k_red2bf(const float* __restrict__ pA, const float* __restrict__ pB,
                         bf16* __restrict__ out){
  int t = (blockIdx.x * 256 + threadIdx.x) * 4;
  float4 a = *(const float4*)&pA[t];
  float4 b = *(const float4*)&pB[t];
  out[t]     = __float2bfloat16(a.x + b.x);
  out[t + 1] = __float2bfloat16(a.y + b.y);
  out[t + 2] = __float2bfloat16(a.z + b.z);
  out[t + 3] = __float2bfloat16(a.w + b.w);
}

// ---------------- misc: bvo fold, layernorm variants, pool ----------------

__global__ void k_bvo(const float* __restrict__ in_b, const float* __restrict__ out_w,
                      const float* __restrict__ out_b, float* bvo){
  int t = blockIdx.x * 256 + threadIdx.x;
  if (t >= 1024) return;
  int i = t >> 9, c = t & 511;
  const float* ib = in_b + i * 1536 + 1024;
  const float* ow = out_w + (size_t)i * 262144;
  float s = out_b[i * 512 + c];
  for (int k = 0; k < 512; k++) s += ib[k] * ow[(size_t)k * 512 + c];
  bvo[t] = s;
}

__device__ __forceinline__ void ln_body(float v[8], int lane,
                                        const float* g, const float* b,
                                        float* yf, bf16* ybf, size_t row){
  float s = 0;
#pragma unroll
  for (int j = 0; j < 8; j++) s += v[j];
  s = warp_sum(s);
  float mu = s * (1.0f / 512.0f);
  float var = 0;
#pragma unroll
  for (int j = 0; j < 8; j++){ float d = v[j] - mu; var += d * d; }
  var = warp_sum(var) * (1.0f / 512.0f);
  float inv = rsqrtf(var + 1e-5f);
#pragma unroll
  for (int j = 0; j < 8; j++){
    int c = lane + j * 64;
    float o = (v[j] - mu) * inv * g[c] + b[c];
    yf[row * 512 + c] = o;
    ybf[row * 512 + c] = __float2bfloat16(o);
  }
}

__global__ __launch_bounds__(256) void k_ln(const float* __restrict__ x,
                                            const float* __restrict__ g,
                                            const float* __restrict__ b,
                                            float* __restrict__ yf,
                                            bf16* __restrict__ ybf){
  int wid = (blockIdx.x * 256 + threadIdx.x) >> 6;
  int lane = threadIdx.x & 63;
  const float* xr = x + (size_t)wid * 512;
  float v[8];
#pragma unroll
  for (int j = 0; j < 8; j++) v[j] = xr[lane + j * 64];
  ln_body(v, lane, g, b, yf, ybf, (size_t)wid);
}

// fused split-K reduce + bias + residual + LN
__global__ __launch_bounds__(256) void k_ln_fr(const float* __restrict__ pA,
                                               const float* __restrict__ pB,
                                               const float* __restrict__ bias,
                                               const float* __restrict__ res,
                                               const float* __restrict__ g,
                                               const float* __restrict__ b,
                                               float* __restrict__ yf,
                                               bf16* __restrict__ ybf){
  int wid = (blockIdx.x * 256 + threadIdx.x) >> 6;
  int lane = threadIdx.x & 63;
  size_t base = (size_t)wid * 512;
  float v[8];
#pragma unroll
  for (int j = 0; j < 8; j++){
    int c = lane + j * 64;
    v[j] = pA[base + c] + pB[base + c] + bias[c] + res[base + c];
  }
  ln_body(v, lane, g, b, yf, ybf, (size_t)wid);
}

__global__ void k_pool(const float* __restrict__ h, float* __restrict__ out){
  int b = blockIdx.x;
  int c = threadIdx.x;   // 512 threads
  const float* hr = h + (size_t)b * 64 * 512;
  float m = -1e30f;
  for (int i = 0; i < 64; i++) m = fmaxf(m, hr[i * 512 + c]);
  out[(size_t)b * 512 + c] = m;
}

// ---------------- launcher ----------------

extern "C" void kernel_launch(void* const* d_in, const int* in_sizes, int n_in,
                              void* d_out, int out_size, void* d_ws, size_t ws_size,
                              hipStream_t stream){
  const float* x1    = (const float*)d_in[0];
  const int*   ei    = (const int*)d_in[1];
  const float* eattr = (const float*)d_in[2];
  const float* W1    = (const float*)d_in[4];
  const float* as1   = (const float*)d_in[5];
  const float* ad1   = (const float*)d_in[6];
  const float* We1   = (const float*)d_in[7];
  const float* ae1   = (const float*)d_in[8];
  const float* b1    = (const float*)d_in[9];
  const float* W2    = (const float*)d_in[10];
  const float* as2   = (const float*)d_in[11];
  const float* ad2   = (const float*)d_in[12];
  const float* We2   = (const float*)d_in[13];
  const float* ae2   = (const float*)d_in[14];
  const float* b2    = (const float*)d_in[15];
  const float* in_w  = (const float*)d_in[16];
  const float* in_b  = (const float*)d_in[17];
  const float* out_w = (const float*)d_in[18];
  const float* out_b = (const float*)d_in[19];
  const float* ln1g  = (const float*)d_in[20];
  const float* ln1b  = (const float*)d_in[21];
  const float* f1w   = (const float*)d_in[22];
  const float* f1b   = (const float*)d_in[23];
  const float* f2w   = (const float*)d_in[24];
  const float* f2b   = (const float*)d_in[25];
  const float* ln2g  = (const float*)d_in[26];
  const float* ln2b  = (const float*)d_in[27];

  const int* src0 = ei;
  const int* dst0 = ei + EE;

  char* p = (char*)d_ws;
  auto alloc = [&](size_t bytes) -> void* {
    void* r = p;
    p += (bytes + 255) & ~(size_t)255;
    return r;
  };
  float* esum    = (float*)alloc(NN * 11 * 4);
  float* lattr   = (float*)alloc(NN * 11 * 4);
  int*   deg     = (int*)alloc(NN * 4);
  int*   offsets = (int*)alloc((NN + 1) * 4);
  int*   cursor  = (int*)alloc(NN * 4);
  int*   csr_src = (int*)alloc(ET * 4);
  int*   csr_eid = (int*)alloc(ET * 4);
  float* wse1    = (float*)alloc(930 * 4);
  float* wsd1    = (float*)alloc(930 * 4);
  float* wee1    = (float*)alloc(110 * 4);
  float* S1      = (float*)alloc(NN * 10 * 4);
  float* D1b     = (float*)alloc(NN * 10 * 4);
  bf16*  xaggp   = (bf16*)alloc((size_t)NN * 10 * 96 * 2);
  bf16*  W1t     = (bf16*)alloc((size_t)5120 * 96 * 2);
  bf16*  W2t     = (bf16*)alloc((size_t)512 * 5120 * 2);
  bf16*  f1wt    = (bf16*)alloc((size_t)2 * 2048 * 512 * 2);
  bf16*  f2wt    = (bf16*)alloc((size_t)2 * 512 * 2048 * 2);
  bf16*  Wvb     = (bf16*)alloc((size_t)2 * 512 * 512 * 2);
  bf16*  WoT     = (bf16*)alloc((size_t)2 * 512 * 512 * 2);
  bf16*  Wvot    = (bf16*)alloc((size_t)2 * 512 * 512 * 2);
  bf16*  h1      = (bf16*)alloc((size_t)NN * 5120 * 2);   // dead after xs2+logits2; reused below
  float* w2s     = (float*)alloc(5120 * 4);
  float* w2d     = (float*)alloc(5120 * 4);
  float* we2e    = (float*)alloc(16 * 4);
  float* s2      = (float*)alloc(NN * 4);
  float* d2v     = (float*)alloc(NN * 4);
  bf16*  xs2     = (bf16*)alloc((size_t)NN * 512 * 2);
  float* h2f     = (float*)alloc((size_t)NN * 512 * 4);
  bf16*  hbf     = (bf16*)alloc((size_t)NN * 512 * 2);
  float* bvo     = (float*)alloc(2 * 512 * 4);
  float* pbufA   = (float*)alloc((size_t)NN * 512 * 4);   // split-K partials
  float* pbufB   = (float*)alloc((size_t)NN * 512 * 4);
  long   pdz     = pbufB - pbufA;   // element stride between partials
  // aliases into dead h1 region (40 MB): tmp (8 MB) + fbuf (16 MB)
  float* tmp  = (float*)h1;
  bf16*  fbuf = (bf16*)((char*)h1 + (size_t)NN * 512 * 4);

  float* out_pool = (float*)d_out;
  float* alpha2   = out_pool + 64 * 512;

  hipMemsetAsync(deg, 0, NN * 4, stream);
  hipMemsetAsync(esum, 0, NN * 11 * 4, stream);
  hipMemsetAsync(cursor, 0, NN * 4, stream);

  // graph prep + logit folds
  k_deg_esum<<<EE / 256, 256, 0, stream>>>(dst0, eattr, deg, esum);
  k_loop_attr<<<NN / 256, 256, 0, stream>>>(esum, deg, lattr);
  k_scan<<<1, 256, 0, stream>>>(deg, offsets);
  k_scatter<<<(EE + NN) / 256, 256, 0, stream>>>(src0, dst0, offsets, cursor, csr_src, csr_eid);
  k_fold1<<<5, 256, 0, stream>>>(W1, as1, ad1, We1, ae1, wse1, wsd1, wee1);
  k_fold2<<<21, 256, 0, stream>>>(W2, as2, ad2, We2, ae2, w2s, w2d, we2e);
  k_logits1<<<160, 256, 0, stream>>>(x1, wse1, wsd1, S1, D1b);

  // weight preps
  k_t2b<<<dim3(160, 3, 1), dim3(32, 8), 0, stream>>>(W1, W1t, 93, 5120, 96, 0, 0);
  k_t2b<<<dim3(16, 160, 1), dim3(32, 8), 0, stream>>>(W2, W2t, 5120, 512, 5120, 0, 0);
  k_t2b<<<dim3(64, 16, 2), dim3(32, 8), 0, stream>>>(f1w, f1wt, 512, 2048, 512,
                                                     512L * 2048, 2048L * 512);
  k_t2b<<<dim3(16, 64, 2), dim3(32, 8), 0, stream>>>(f2w, f2wt, 2048, 512, 2048,
                                                     2048L * 512, 512L * 2048);
  k_prep_wv<<<2048, 256, 0, stream>>>(in_w, Wvb);
  k_t2b<<<dim3(16, 16, 2), dim3(32, 8), 0, stream>>>(out_w, WoT, 512, 512, 512,
                                                     262144, 262144);
  // Wvot[n][k] = sum_j WoT[n][j] * Wvb[k][j]  (bf16 out, = (Wv@Wo)^T)
  k_mm<4, 4, 0, false, false, bf16><<<dim3(4, 4, 2), 256, 0, stream>>>(
      WoT, Wvb, nullptr, nullptr, Wvot, 512, 512, 512, 512, 512,
      262144, 262144, 262144, 0);
  k_bvo<<<4, 256, 0, stream>>>(in_b, out_w, out_b, bvo);

  // GAT-1: aggregate 93-wide, then project per-head with MFMA
  k_gat1<<<(NN * 10) / 4, 256, 0, stream>>>(offsets, csr_src, csr_eid, eattr, lattr,
                                            S1, D1b, wee1, x1, xaggp);
  // h1 = elu(xagg @ W1 + b1): z=10 heads, M=4096, N=512, K=96
  k_mm<4, 4, 2, true, false, bf16><<<dim3(4, 32, 10), 256, 0, stream>>>(
      xaggp, W1t, b1, nullptr, h1, NN, 96, 960, 96, 5120, 96, 512L * 96, 512, 512);

  k_logits2<<<NN / 4, 256, 0, stream>>>(h1, w2s, w2d, s2, d2v);
  // xs2 = h1 @ W2 via split-K=2 (z in {0,1}, K-window 2560 each) -> f32 partials
  k_mm<2, 4, 0, false, false, float><<<dim3(4, 64, 2), 256, 0, stream>>>(
      h1, W2t, nullptr, nullptr, pbufA, NN, 2560, 5120, 5120, 512,
      2560, 2560, pdz, 0);
  k_red2bf<<<2048, 256, 0, stream>>>(pbufA, pbufB, xs2);
  k_gat2<<<NN / 4, 256, 0, stream>>>(offsets, csr_src, csr_eid, eattr, lattr,
                                     s2, d2v, we2e, xs2, b2, h2f, hbf, alpha2);

  for (int i = 0; i < 2; i++){
    // tmp = h2 + h2 @ Wvo + bvo   (BN=64 tiles: 512 blocks = 2/CU)
    k_mm<2, 2, 0, true, true, float><<<dim3(8, 64, 1), 256, 0, stream>>>(
        hbf, Wvot + (size_t)i * 262144, bvo + i * 512, h2f, tmp,
        NN, 512, 512, 512, 512, 0, 0, 0, 0);
    k_ln<<<NN / 4, 256, 0, stream>>>(tmp, ln1g + i * 512, ln1b + i * 512, h2f, hbf);
    // fbuf = relu(h @ f1w + f1b): N=2048, K=512
    k_mm<4, 4, 1, true, false, bf16><<<dim3(16, 32, 1), 256, 0, stream>>>(
        hbf, f1wt + (size_t)i * 2048 * 512, f1b + i * 2048, nullptr, fbuf,
        NN, 512, 512, 512, 2048, 0, 0, 0, 0);
    // FFN2 split-K=2: partials (K-window 1024 each), reduce fused into LN
    k_mm<2, 4, 0, false, false, float><<<dim3(4, 64, 2), 256, 0, stream>>>(
        fbuf, f2wt + (size_t)i * 512 * 2048, nullptr, nullptr, pbufA,
        NN, 1024, 2048, 2048, 512, 1024, 1024, pdz, 0);
    k_ln_fr<<<NN / 4, 256, 0, stream>>>(pbufA, pbufB, f2b + i * 512, h2f,
                                        ln2g + i * 512, ln2b + i * 512, h2f, hbf);
  }

  k_pool<<<64, 512, 0, stream>>>(h2f, out_pool);
}

// Round 7
// 542.406 us; speedup vs baseline: 4.7045x; 1.0957x over previous
//
#include <hip/hip_runtime.h>
#include <hip/hip_bf16.h>

#define NN 4096
#define EE 16384
#define ET 20480   // EE + NN

typedef __hip_bfloat16 bf16;
typedef __bf16 bfv8 __attribute__((ext_vector_type(8)));
typedef float fv4 __attribute__((ext_vector_type(4)));

__device__ __forceinline__ float warp_max(float v){
#pragma unroll
  for (int o = 32; o; o >>= 1) v = fmaxf(v, __shfl_xor(v, o));
  return v;
}
__device__ __forceinline__ float warp_sum(float v){
#pragma unroll
  for (int o = 32; o; o >>= 1) v += __shfl_xor(v, o);
  return v;
}
__device__ __forceinline__ float bf2f(unsigned short u){
  return __uint_as_float((unsigned)u << 16);
}

// async global->LDS, 16B per lane. lbase = wave-uniform LDS base (lane*16 added by HW).
__device__ __forceinline__ void gl_lds16(const void* g, void* lbase, int lane){
#if __has_builtin(__builtin_amdgcn_global_load_lds)
  __builtin_amdgcn_global_load_lds(
      (const __attribute__((address_space(1))) unsigned int*)g,
      (__attribute__((address_space(3))) unsigned int*)lbase, 16, 0, 0);
#else
  *(uint4*)((char*)lbase + lane * 16) = *(const uint4*)g;
#endif
}

// ---------------- graph preprocessing ----------------

__global__ void k_deg_esum(const int* __restrict__ dst0, const float* __restrict__ eattr,
                           int* deg, float* esum){
  int e = blockIdx.x * 256 + threadIdx.x;
  if (e >= EE) return;
  int d = dst0[e];
  atomicAdd(&deg[d], 1);
  const float* ar = eattr + (size_t)e * 11;
  float* er = esum + (size_t)d * 11;
#pragma unroll
  for (int j = 0; j < 11; j++) atomicAdd(&er[j], ar[j]);
}

__global__ void k_loop_attr(const float* __restrict__ esum, const int* __restrict__ deg,
                            float* lattr){
  int n = blockIdx.x * 256 + threadIdx.x;
  if (n >= NN) return;
  float c = fmaxf((float)deg[n], 1.0f);
#pragma unroll
  for (int j = 0; j < 11; j++) lattr[n * 11 + j] = esum[n * 11 + j] / c;
}

__global__ void k_scan(const int* __restrict__ deg, int* offsets){
  __shared__ int sums[256];
  int t = threadIdx.x;
  int base = t * 16;
  int vals[16];
  int s = 0;
#pragma unroll
  for (int j = 0; j < 16; j++){ vals[j] = s; s += deg[base + j] + 1; }
  sums[t] = s;
  __syncthreads();
  for (int off = 1; off < 256; off <<= 1){
    int v = (t >= off) ? sums[t - off] : 0;
    __syncthreads();
    sums[t] += v;
    __syncthreads();
  }
  int pre = (t == 0) ? 0 : sums[t - 1];
#pragma unroll
  for (int j = 0; j < 16; j++) offsets[base + j] = pre + vals[j];
  if (t == 255) offsets[NN] = sums[255];
}

__global__ void k_scatter(const int* __restrict__ src0, const int* __restrict__ dst0,
                          const int* __restrict__ offsets, int* cursor,
                          int* csr_src, int* csr_eid){
  int t = blockIdx.x * 256 + threadIdx.x;
  if (t < EE){
    int d = dst0[t];
    int pos = offsets[d] + atomicAdd(&cursor[d], 1);
    csr_src[pos] = src0[t];
    csr_eid[pos] = t;
  } else if (t < EE + NN){
    int n = t - EE;
    int pos = offsets[n + 1] - 1;
    csr_src[pos] = n;
    csr_eid[pos] = EE + n;
  }
}

// ---------------- folded attention weight vectors ----------------

__global__ void k_fold1(const float* __restrict__ W1, const float* __restrict__ as1,
                        const float* __restrict__ ad1, const float* __restrict__ We1,
                        const float* __restrict__ ae1,
                        float* wse1, float* wsd1, float* wee1){
  int t = blockIdx.x * 256 + threadIdx.x;
  if (t < 930){
    int k = t / 10, h = t % 10;
    const float* wr = W1 + (size_t)k * 5120 + h * 512;
    const float* asr = as1 + h * 512;
    const float* adr = ad1 + h * 512;
    float ss = 0, sd = 0;
    for (int c = 0; c < 512; c++){ float w = wr[c]; ss += w * asr[c]; sd += w * adr[c]; }
    wse1[t] = ss; wsd1[t] = sd;
  } else if (t < 1040){
    int u = t - 930;
    int k = u / 10, h = u % 10;
    const float* wr = We1 + (size_t)k * 5120 + h * 512;
    const float* aer = ae1 + h * 512;
    float se = 0;
    for (int c = 0; c < 512; c++) se += wr[c] * aer[c];
    wee1[u] = se;
  }
}

__global__ void k_fold2(const float* __restrict__ W2, const float* __restrict__ as2,
                        const float* __restrict__ ad2, const float* __restrict__ We2,
                        const float* __restrict__ ae2,
                        float* w2s, float* w2d, float* we2e){
  int t = blockIdx.x * 256 + threadIdx.x;
  if (t < 5120){
    const float* wr = W2 + (size_t)t * 512;
    float ss = 0, sd = 0;
    for (int c = 0; c < 512; c++){ float w = wr[c]; ss += w * as2[c]; sd += w * ad2[c]; }
    w2s[t] = ss; w2d[t] = sd;
  } else if (t < 5131){
    int k = t - 5120;
    const float* wr = We2 + (size_t)k * 512;
    float se = 0;
    for (int c = 0; c < 512; c++) se += wr[c] * ae2[c];
    we2e[k] = se;
  }
}

__global__ void k_logits1(const float* __restrict__ x1, const float* __restrict__ wse1,
                          const float* __restrict__ wsd1, float* S1, float* D1){
  int t = blockIdx.x * 256 + threadIdx.x;
  int n = t / 10, h = t % 10;
  const float* xr = x1 + (size_t)n * 93;
  float s = 0, d = 0;
  for (int k = 0; k < 93; k++){ float x = xr[k]; s += x * wse1[k * 10 + h]; d += x * wsd1[k * 10 + h]; }
  S1[t] = s; D1[t] = d;
}

// ---------------- weight prep ----------------

// dst[n][k(dK)] = bf16(src[k][n]) for k<K (0 for K<=k<dK); src [K][N] f32
__global__ void k_t2b(const float* __restrict__ src, bf16* __restrict__ dst,
                      int K, int N, int dK, long sZ, long dZ){
  __shared__ float t[32][33];
  src += (size_t)blockIdx.z * sZ;
  dst += (size_t)blockIdx.z * dZ;
  int k0 = blockIdx.y * 32, n0 = blockIdx.x * 32;
  int x = threadIdx.x, y = threadIdx.y;   // 32 x 8
#pragma unroll
  for (int yy = y; yy < 32; yy += 8){
    int k = k0 + yy, n = n0 + x;
    t[yy][x] = (k < K && n < N) ? src[(size_t)k * N + n] : 0.f;
  }
  __syncthreads();
#pragma unroll
  for (int yy = y; yy < 32; yy += 8){
    int n = n0 + yy, k = k0 + x;
    if (n < N && k < dK) dst[(size_t)n * dK + k] = __float2bfloat16(t[x][yy]);
  }
}

// Wvb[i][k][j] = bf16(in_w[i][k][1024+j])   (512x512 slice, row-major)
__global__ void k_prep_wv(const float* __restrict__ in_w, bf16* __restrict__ Wvb){
  int t = blockIdx.x * 256 + threadIdx.x;   // < 2*512*512
  int i = t >> 18, rem = t & 262143, k = rem >> 9, j = rem & 511;
  Wvb[t] = __float2bfloat16(in_w[(size_t)i * 786432 + (size_t)k * 1536 + 1024 + j]);
}

// ---------------- GAT layer 1: one wave per node, all 10 heads ----------------
// Lane-parallel logits (lane = edge), single-pass softmax via shuffles,
// shfl-broadcast aggregate. Fallback 3-pass path for deg > 64 (never hit here).

__global__ __launch_bounds__(256) void k_gat1(
    const int* __restrict__ offsets, const int* __restrict__ csr_src,
    const int* __restrict__ csr_eid, const float* __restrict__ eattr,
    const float* __restrict__ lattr, const float* __restrict__ S1,
    const float* __restrict__ D1, const float* __restrict__ wee1,
    const float* __restrict__ x1, bf16* __restrict__ xaggp){
  int n = (blockIdx.x * 256 + threadIdx.x) >> 6;
  int lane = threadIdx.x & 63;
  int start = offsets[n], end = offsets[n + 1];
  int deg = end - start;

  if (deg <= 64){
    bool act = lane < deg;
    int s = 0, eid = 0;
    float ea[11];
#pragma unroll
    for (int j = 0; j < 11; j++) ea[j] = 0.f;
    if (act){
      s = csr_src[start + lane];
      eid = csr_eid[start + lane];
      const float* eap = (eid < EE) ? eattr + (size_t)eid * 11
                                    : lattr + (size_t)(eid - EE) * 11;
#pragma unroll
      for (int j = 0; j < 11; j++) ea[j] = eap[j];
    }
    float alpha[10];
#pragma unroll
    for (int h = 0; h < 10; h++){
      float eel = 0;
#pragma unroll
      for (int j = 0; j < 11; j++) eel += ea[j] * wee1[j * 10 + h];
      float lg = -1e30f;
      if (act){
        lg = S1[s * 10 + h] + D1[n * 10 + h] + eel;
        lg = lg > 0.f ? lg : 0.2f * lg;
      }
      float m = warp_max(lg);
      float pv = act ? __expf(lg - m) : 0.f;
      float sum = warp_sum(pv);
      alpha[h] = pv / sum;
    }
    // aggregate: acc[h] over 93 dims (lane covers 0..63 and 64..92)
    float acc0[10], acc1[10];
#pragma unroll
    for (int h = 0; h < 10; h++){ acc0[h] = 0.f; acc1[h] = 0.f; }
    for (int e = 0; e < deg; e++){
      int se = __shfl(s, e);
      const float* xr = x1 + (size_t)se * 93;
      float xv0 = xr[lane];
      float xv1 = (lane < 29) ? xr[64 + lane] : 0.f;
#pragma unroll
      for (int h = 0; h < 10; h++){
        float al = __shfl(alpha[h], e);
        acc0[h] += al * xv0;
        acc1[h] += al * xv1;
      }
    }
#pragma unroll
    for (int h = 0; h < 10; h++){
      bf16* o = xaggp + (size_t)(n * 10 + h) * 96;
      o[lane] = __float2bfloat16(acc0[h]);
      if (lane < 29) o[64 + lane] = __float2bfloat16(acc1[h]);
      else if (lane < 32) o[64 + lane] = __float2bfloat16(0.f);
    }
  } else {
    // general fallback (3-pass per head) — correctness safety net
    for (int h = 0; h < 10; h++){
      float dl = D1[n * 10 + h];
      float wl[11];
#pragma unroll
      for (int j = 0; j < 11; j++) wl[j] = wee1[j * 10 + h];
      float m = -1e30f;
      for (int pos = start + lane; pos < end; pos += 64){
        int s = csr_src[pos]; int eid = csr_eid[pos];
        const float* ea = (eid < EE) ? eattr + (size_t)eid * 11 : lattr + (size_t)(eid - EE) * 11;
        float eel = 0;
#pragma unroll
        for (int j = 0; j < 11; j++) eel += ea[j] * wl[j];
        float lg = S1[s * 10 + h] + dl + eel;
        lg = lg > 0.f ? lg : 0.2f * lg;
        m = fmaxf(m, lg);
      }
      m = warp_max(m);
      float ps = 0;
      for (int pos = start + lane; pos < end; pos += 64){
        int s = csr_src[pos]; int eid = csr_eid[pos];
        const float* ea = (eid < EE) ? eattr + (size_t)eid * 11 : lattr + (size_t)(eid - EE) * 11;
        float eel = 0;
#pragma unroll
        for (int j = 0; j < 11; j++) eel += ea[j] * wl[j];
        float lg = S1[s * 10 + h] + dl + eel;
        lg = lg > 0.f ? lg : 0.2f * lg;
        ps += __expf(lg - m);
      }
      ps = warp_sum(ps);
      float inv = 1.0f / ps;
      float acc0 = 0, acc1 = 0;
      for (int pos = start; pos < end; pos++){
        int s = csr_src[pos]; int eid = csr_eid[pos];
        const float* ea = (eid < EE) ? eattr + (size_t)eid * 11 : lattr + (size_t)(eid - EE) * 11;
        float eel = 0;
#pragma unroll
        for (int j = 0; j < 11; j++) eel += ea[j] * wl[j];
        float lg = S1[s * 10 + h] + dl + eel;
        lg = lg > 0.f ? lg : 0.2f * lg;
        float alpha = __expf(lg - m) * inv;
        const float* xr = x1 + (size_t)s * 93;
        acc0 += alpha * xr[lane];
        if (lane < 29) acc1 += alpha * xr[64 + lane];
      }
      bf16* o = xaggp + (size_t)(n * 10 + h) * 96;
      o[lane] = __float2bfloat16(acc0);
      if (lane < 29) o[64 + lane] = __float2bfloat16(acc1);
      else if (lane < 32) o[64 + lane] = __float2bfloat16(0.f);
    }
  }
}

// ---------------- layer-2 node logits (vectorized bf16x8 loads) ----------------

__global__ __launch_bounds__(256) void k_logits2(const bf16* __restrict__ h1,
                                                 const float* __restrict__ w2s,
                                                 const float* __restrict__ w2d,
                                                 float* s2, float* d2){
  int wid = (blockIdx.x * 256 + threadIdx.x) >> 6;
  int lane = threadIdx.x & 63;
  const bf16* hr = h1 + (size_t)wid * 5120;
  float a = 0, b = 0;
#pragma unroll
  for (int g = 0; g < 10; g++){
    int base = (g * 64 + lane) * 8;
    union { uint4 u; unsigned short s[8]; } hv;
    hv.u = *(const uint4*)&hr[base];
    float4 ws0 = *(const float4*)&w2s[base];
    float4 ws1 = *(const float4*)&w2s[base + 4];
    float4 wd0 = *(const float4*)&w2d[base];
    float4 wd1 = *(const float4*)&w2d[base + 4];
    float f0 = bf2f(hv.s[0]), f1 = bf2f(hv.s[1]), f2 = bf2f(hv.s[2]), f3 = bf2f(hv.s[3]);
    float f4 = bf2f(hv.s[4]), f5 = bf2f(hv.s[5]), f6 = bf2f(hv.s[6]), f7 = bf2f(hv.s[7]);
    a += f0 * ws0.x + f1 * ws0.y + f2 * ws0.z + f3 * ws0.w
       + f4 * ws1.x + f5 * ws1.y + f6 * ws1.z + f7 * ws1.w;
    b += f0 * wd0.x + f1 * wd0.y + f2 * wd0.z + f3 * wd0.w
       + f4 * wd1.x + f5 * wd1.y + f6 * wd1.z + f7 * wd1.w;
  }
  a = warp_sum(a); b = warp_sum(b);
  if (lane == 0){ s2[wid] = a; d2[wid] = b; }
}

// ---------------- GAT layer 2: one wave per node, lane-parallel softmax ----------------

__global__ __launch_bounds__(256) void k_gat2(
    const int* __restrict__ offsets, const int* __restrict__ csr_src,
    const int* __restrict__ csr_eid, const float* __restrict__ eattr,
    const float* __restrict__ lattr, const float* __restrict__ s2,
    const float* __restrict__ d2, const float* __restrict__ we2e,
    const bf16* __restrict__ xs2, const float* __restrict__ b2,
    float* __restrict__ h2f, bf16* __restrict__ hbf, float* __restrict__ alpha_out){
  int n = (blockIdx.x * 256 + threadIdx.x) >> 6;
  int lane = threadIdx.x & 63;
  int start = offsets[n], end = offsets[n + 1];
  int deg = end - start;
  float dl = d2[n];

  float acc[8] = {0, 0, 0, 0, 0, 0, 0, 0};

  if (deg <= 64){
    bool act = lane < deg;
    int s = 0, eid = 0;
    float eel = 0.f;
    if (act){
      s = csr_src[start + lane];
      eid = csr_eid[start + lane];
      const float* eap = (eid < EE) ? eattr + (size_t)eid * 11
                                    : lattr + (size_t)(eid - EE) * 11;
#pragma unroll
      for (int j = 0; j < 11; j++) eel += eap[j] * we2e[j];
    }
    float lg = -1e30f;
    if (act){
      lg = s2[s] + dl + eel;
      lg = lg > 0.f ? lg : 0.2f * lg;
    }
    float m = warp_max(lg);
    float pv = act ? __expf(lg - m) : 0.f;
    float sum = warp_sum(pv);
    float alpha = pv / sum;
    if (act) alpha_out[eid] = alpha;

    for (int e = 0; e < deg; e++){
      int se = __shfl(s, e);
      float al = __shfl(alpha, e);
      union { uint4 u; unsigned short sh[8]; } xv;
      xv.u = *(const uint4*)&xs2[(size_t)se * 512 + lane * 8];
#pragma unroll
      for (int jj = 0; jj < 8; jj++) acc[jj] += al * bf2f(xv.sh[jj]);
    }
  } else {
    // general fallback (3-pass)
    float wl[11];
#pragma unroll
    for (int j = 0; j < 11; j++) wl[j] = we2e[j];
    float m = -1e30f;
    for (int pos = start + lane; pos < end; pos += 64){
      int s = csr_src[pos]; int eid = csr_eid[pos];
      const float* ea = (eid < EE) ? eattr + (size_t)eid * 11 : lattr + (size_t)(eid - EE) * 11;
      float eel = 0;
#pragma unroll
      for (int j = 0; j < 11; j++) eel += ea[j] * wl[j];
      float lg = s2[s] + dl + eel;
      lg = lg > 0.f ? lg : 0.2f * lg;
      m = fmaxf(m, lg);
    }
    m = warp_max(m);
    float ps = 0;
    for (int pos = start + lane; pos < end; pos += 64){
      int s = csr_src[pos]; int eid = csr_eid[pos];
      const float* ea = (eid < EE) ? eattr + (size_t)eid * 11 : lattr + (size_t)(eid - EE) * 11;
      float eel = 0;
#pragma unroll
      for (int j = 0; j < 11; j++) eel += ea[j] * wl[j];
      float lg = s2[s] + dl + eel;
      lg = lg > 0.f ? lg : 0.2f * lg;
      ps += __expf(lg - m);
    }
    ps = warp_sum(ps);
    float inv = 1.0f / ps;
    for (int pos = start; pos < end; pos++){
      int s = csr_src[pos]; int eid = csr_eid[pos];
      const float* ea = (eid < EE) ? eattr + (size_t)eid * 11 : lattr + (size_t)(eid - EE) * 11;
      float eel = 0;
#pragma unroll
      for (int j = 0; j < 11; j++) eel += ea[j] * wl[j];
      float lg = s2[s] + dl + eel;
      lg = lg > 0.f ? lg : 0.2f * lg;
      float alpha = __expf(lg - m) * inv;
      if (lane == 0) alpha_out[eid] = alpha;
      union { uint4 u; unsigned short sh[8]; } xv;
      xv.u = *(const uint4*)&xs2[(size_t)s * 512 + lane * 8];
#pragma unroll
      for (int jj = 0; jj < 8; jj++) acc[jj] += alpha * bf2f(xv.sh[jj]);
    }
  }

#pragma unroll
  for (int jj = 0; jj < 8; jj++){
    int c = lane * 8 + jj;
    float v = acc[jj] + b2[c];
    v = v > 0.f ? v : (__expf(v) - 1.f);
    h2f[(size_t)n * 512 + c] = v;
    hbf[(size_t)n * 512 + c] = __float2bfloat16(v);
  }
}

// ---------------- MFMA bf16 GEMM: C = act(A @ Bt^T + bias + res) ----------------
// A [M,K+] bf16 (row stride lda), Bt [N,K+] bf16 (row stride ldb), C [M,ldc].
// K%32==0. z-dim: offsets aZ/bZ (elements) shift A/Bt (batching AND split-K),
// cZ shifts C. Double-buffered LDS, one barrier per K-step.
// Bijective XCD swizzle over 2D grid (gridDim.x*gridDim.y % 8 == 0).

__device__ __forceinline__ void stC_elem(float* p, float v){ *p = v; }
__device__ __forceinline__ void stC_elem(bf16* p, float v){ *p = __float2bfloat16(v); }

template <int BMF, int BNF, int ACT, bool BIAS, bool RES, typename TC>
__global__ __launch_bounds__(256) void k_mm(
    const bf16* __restrict__ A, const bf16* __restrict__ Bt,
    const float* __restrict__ bias, const float* __restrict__ res,
    TC* __restrict__ C, int M, int K, int lda, int ldb, int ldc,
    long aZ, long bZ, long cZ, long biasZ){
  constexpr int BM = BMF * 32, BN = BNF * 32;
  __shared__ __align__(16) bf16 As[2][BM * 32];
  __shared__ __align__(16) bf16 Bs[2][BN * 32];
  const int tid = threadIdx.x, wave = tid >> 6, lane = tid & 63;

  const int nwg = gridDim.x * gridDim.y;
  const int id = blockIdx.y * gridDim.x + blockIdx.x;
  const int cpx = nwg >> 3;
  const int swz = (id & 7) * cpx + (id >> 3);
  const int bm = (swz / gridDim.x) * BM, bn = (swz % gridDim.x) * BN;

  const int z = blockIdx.z;
  A  += (size_t)z * aZ;
  Bt += (size_t)z * bZ;
  C  += (size_t)z * cZ;
  const float* bp = BIAS ? bias + (size_t)z * biasZ : nullptr;

  const int trow = tid >> 2, tk = (tid & 3) * 8;   // staging: 16B per thread
  const int wr = (wave >> 1) * (BMF * 16), wc = (wave & 1) * (BNF * 16);
  const int r = lane & 15, kq = lane >> 4;

  fv4 acc[BMF][BNF] = {};

  auto STAGE = [&](int buf, int k0){
#pragma unroll
    for (int s = 0; s < BM / 64; s++)
      gl_lds16(A + (size_t)(bm + s * 64 + trow) * lda + k0 + tk,
               (char*)&As[buf][0] + s * 4096 + wave * 1024, lane);
#pragma unroll
    for (int s = 0; s < BN / 64; s++)
      gl_lds16(Bt + (size_t)(bn + s * 64 + trow) * ldb + k0 + tk,
               (char*)&Bs[buf][0] + s * 4096 + wave * 1024, lane);
  };

  STAGE(0, 0);
  int cur = 0;
  for (int k0 = 0; k0 < K; k0 += 32){
    __syncthreads();
    if (k0 + 32 < K) STAGE(cur ^ 1, k0 + 32);

    bfv8 a[BMF], b[BNF];
#pragma unroll
    for (int i = 0; i < BMF; i++)
      a[i] = *(const bfv8*)&As[cur][(wr + i * 16 + r) * 32 + kq * 8];
#pragma unroll
    for (int j = 0; j < BNF; j++)
      b[j] = *(const bfv8*)&Bs[cur][(wc + j * 16 + r) * 32 + kq * 8];
#pragma unroll
    for (int i = 0; i < BMF; i++)
#pragma unroll
      for (int j = 0; j < BNF; j++)
        acc[i][j] = __builtin_amdgcn_mfma_f32_16x16x32_bf16(a[i], b[j], acc[i][j], 0, 0, 0);
    cur ^= 1;
  }

  const int rb = bm + wr + (lane >> 4) * 4;
  const int cb = bn + wc + (lane & 15);
#pragma unroll
  for (int i = 0; i < BMF; i++)
#pragma unroll
    for (int j = 0; j < BNF; j++){
      int gn = cb + j * 16;
      float bv = BIAS ? bp[gn] : 0.f;
#pragma unroll
      for (int q = 0; q < 4; q++){
        int gm = rb + i * 16 + q;
        float v = acc[i][j][q] + bv;
        if (RES) v += res[(size_t)gm * ldc + gn];
        if (ACT == 1) v = fmaxf(v, 0.f);
        if (ACT == 2) v = v > 0.f ? v : (__expf(v) - 1.f);
        stC_elem(&C[(size_t)gm * ldc + gn], v);
      }
    }
}

// ---------------- split-K reduce: out = bf16(pA + pB) ----------------

__global__ void k_red2bf(const float* __restrict__ pA, const float* __restrict__ pB,
                         bf16* __restrict__ out){
  int t = (blockIdx.x * 256 + threadIdx.x) * 4;
  float4 a = *(const float4*)&pA[t];
  float4 b = *(const float4*)&pB[t];
  out[t]     = __float2bfloat16(a.x + b.x);
  out[t + 1] = __float2bfloat16(a.y + b.y);
  out[t + 2] = __float2bfloat16(a.z + b.z);
  out[t + 3] = __float2bfloat16(a.w + b.w);
}

// ---------------- misc: bvo fold, layernorm variants, pool ----------------

__global__ void k_bvo(const float* __restrict__ in_b, const float* __restrict__ out_w,
                      const float* __restrict__ out_b, float* bvo){
  int t = blockIdx.x * 256 + threadIdx.x;
  if (t >= 1024) return;
  int i = t >> 9, c = t & 511;
  const float* ib = in_b + i * 1536 + 1024;
  const float* ow = out_w + (size_t)i * 262144;
  float s = out_b[i * 512 + c];
  for (int k = 0; k < 512; k++) s += ib[k] * ow[(size_t)k * 512 + c];
  bvo[t] = s;
}

__device__ __forceinline__ void ln_body(float v[8], int lane,
                                        const float* g, const float* b,
                                        float* yf, bf16* ybf, size_t row){
  float s = 0;
#pragma unroll
  for (int j = 0; j < 8; j++) s += v[j];
  s = warp_sum(s);
  float mu = s * (1.0f / 512.0f);
  float var = 0;
#pragma unroll
  for (int j = 0; j < 8; j++){ float d = v[j] - mu; var += d * d; }
  var = warp_sum(var) * (1.0f / 512.0f);
  float inv = rsqrtf(var + 1e-5f);
#pragma unroll
  for (int j = 0; j < 8; j++){
    int c = lane + j * 64;
    float o = (v[j] - mu) * inv * g[c] + b[c];
    yf[row * 512 + c] = o;
    ybf[row * 512 + c] = __float2bfloat16(o);
  }
}

__global__ __launch_bounds__(256) void k_ln(const float* __restrict__ x,
                                            const float* __restrict__ g,
                                            const float* __restrict__ b,
                                            float* __restrict__ yf,
                                            bf16* __restrict__ ybf){
  int wid = (blockIdx.x * 256 + threadIdx.x) >> 6;
  int lane = threadIdx.x & 63;
  const float* xr = x + (size_t)wid * 512;
  float v[8];
#pragma unroll
  for (int j = 0; j < 8; j++) v[j] = xr[lane + j * 64];
  ln_body(v, lane, g, b, yf, ybf, (size_t)wid);
}

// fused split-K reduce + bias + residual + LN
__global__ __launch_bounds__(256) void k_ln_fr(const float* __restrict__ pA,
                                               const float* __restrict__ pB,
                                               const float* __restrict__ bias,
                                               const float* __restrict__ res,
                                               const float* __restrict__ g,
                                               const float* __restrict__ b,
                                               float* __restrict__ yf,
                                               bf16* __restrict__ ybf){
  int wid = (blockIdx.x * 256 + threadIdx.x) >> 6;
  int lane = threadIdx.x & 63;
  size_t base = (size_t)wid * 512;
  float v[8];
#pragma unroll
  for (int j = 0; j < 8; j++){
    int c = lane + j * 64;
    v[j] = pA[base + c] + pB[base + c] + bias[c] + res[base + c];
  }
  ln_body(v, lane, g, b, yf, ybf, (size_t)wid);
}

__global__ void k_pool(const float* __restrict__ h, float* __restrict__ out){
  int b = blockIdx.x;
  int c = threadIdx.x;   // 512 threads
  const float* hr = h + (size_t)b * 64 * 512;
  float m = -1e30f;
  for (int i = 0; i < 64; i++) m = fmaxf(m, hr[i * 512 + c]);
  out[(size_t)b * 512 + c] = m;
}

// ---------------- launcher ----------------

extern "C" void kernel_launch(void* const* d_in, const int* in_sizes, int n_in,
                              void* d_out, int out_size, void* d_ws, size_t ws_size,
                              hipStream_t stream){
  const float* x1    = (const float*)d_in[0];
  const int*   ei    = (const int*)d_in[1];
  const float* eattr = (const float*)d_in[2];
  const float* W1    = (const float*)d_in[4];
  const float* as1   = (const float*)d_in[5];
  const float* ad1   = (const float*)d_in[6];
  const float* We1   = (const float*)d_in[7];
  const float* ae1   = (const float*)d_in[8];
  const float* b1    = (const float*)d_in[9];
  const float* W2    = (const float*)d_in[10];
  const float* as2   = (const float*)d_in[11];
  const float* ad2   = (const float*)d_in[12];
  const float* We2   = (const float*)d_in[13];
  const float* ae2   = (const float*)d_in[14];
  const float* b2    = (const float*)d_in[15];
  const float* in_w  = (const float*)d_in[16];
  const float* in_b  = (const float*)d_in[17];
  const float* out_w = (const float*)d_in[18];
  const float* out_b = (const float*)d_in[19];
  const float* ln1g  = (const float*)d_in[20];
  const float* ln1b  = (const float*)d_in[21];
  const float* f1w   = (const float*)d_in[22];
  const float* f1b   = (const float*)d_in[23];
  const float* f2w   = (const float*)d_in[24];
  const float* f2b   = (const float*)d_in[25];
  const float* ln2g  = (const float*)d_in[26];
  const float* ln2b  = (const float*)d_in[27];

  const int* src0 = ei;
  const int* dst0 = ei + EE;

  char* p = (char*)d_ws;
  auto alloc = [&](size_t bytes) -> void* {
    void* r = p;
    p += (bytes + 255) & ~(size_t)255;
    return r;
  };
  float* esum    = (float*)alloc(NN * 11 * 4);
  float* lattr   = (float*)alloc(NN * 11 * 4);
  int*   deg     = (int*)alloc(NN * 4);
  int*   offsets = (int*)alloc((NN + 1) * 4);
  int*   cursor  = (int*)alloc(NN * 4);
  int*   csr_src = (int*)alloc(ET * 4);
  int*   csr_eid = (int*)alloc(ET * 4);
  float* wse1    = (float*)alloc(930 * 4);
  float* wsd1    = (float*)alloc(930 * 4);
  float* wee1    = (float*)alloc(110 * 4);
  float* S1      = (float*)alloc(NN * 10 * 4);
  float* D1b     = (float*)alloc(NN * 10 * 4);
  bf16*  xaggp   = (bf16*)alloc((size_t)NN * 10 * 96 * 2);
  bf16*  W1t     = (bf16*)alloc((size_t)5120 * 96 * 2);
  bf16*  W2t     = (bf16*)alloc((size_t)512 * 5120 * 2);
  bf16*  f1wt    = (bf16*)alloc((size_t)2 * 2048 * 512 * 2);
  bf16*  f2wt    = (bf16*)alloc((size_t)2 * 512 * 2048 * 2);
  bf16*  Wvb     = (bf16*)alloc((size_t)2 * 512 * 512 * 2);
  bf16*  WoT     = (bf16*)alloc((size_t)2 * 512 * 512 * 2);
  bf16*  Wvot    = (bf16*)alloc((size_t)2 * 512 * 512 * 2);
  bf16*  h1      = (bf16*)alloc((size_t)NN * 5120 * 2);   // dead after xs2+logits2; reused below
  float* w2s     = (float*)alloc(5120 * 4);
  float* w2d     = (float*)alloc(5120 * 4);
  float* we2e    = (float*)alloc(16 * 4);
  float* s2      = (float*)alloc(NN * 4);
  float* d2v     = (float*)alloc(NN * 4);
  bf16*  xs2     = (bf16*)alloc((size_t)NN * 512 * 2);
  float* h2f     = (float*)alloc((size_t)NN * 512 * 4);
  bf16*  hbf     = (bf16*)alloc((size_t)NN * 512 * 2);
  float* bvo     = (float*)alloc(2 * 512 * 4);
  float* pbufA   = (float*)alloc((size_t)NN * 512 * 4);   // split-K partials
  float* pbufB   = (float*)alloc((size_t)NN * 512 * 4);
  long   pdz     = pbufB - pbufA;   // element stride between partials
  // aliases into dead h1 region (40 MB): tmp (8 MB) + fbuf (16 MB)
  float* tmp  = (float*)h1;
  bf16*  fbuf = (bf16*)((char*)h1 + (size_t)NN * 512 * 4);

  float* out_pool = (float*)d_out;
  float* alpha2   = out_pool + 64 * 512;

  hipMemsetAsync(deg, 0, NN * 4, stream);
  hipMemsetAsync(esum, 0, NN * 11 * 4, stream);
  hipMemsetAsync(cursor, 0, NN * 4, stream);

  // graph prep + logit folds
  k_deg_esum<<<EE / 256, 256, 0, stream>>>(dst0, eattr, deg, esum);
  k_loop_attr<<<NN / 256, 256, 0, stream>>>(esum, deg, lattr);
  k_scan<<<1, 256, 0, stream>>>(deg, offsets);
  k_scatter<<<(EE + NN) / 256, 256, 0, stream>>>(src0, dst0, offsets, cursor, csr_src, csr_eid);
  k_fold1<<<5, 256, 0, stream>>>(W1, as1, ad1, We1, ae1, wse1, wsd1, wee1);
  k_fold2<<<21, 256, 0, stream>>>(W2, as2, ad2, We2, ae2, w2s, w2d, we2e);
  k_logits1<<<160, 256, 0, stream>>>(x1, wse1, wsd1, S1, D1b);

  // weight preps
  k_t2b<<<dim3(160, 3, 1), dim3(32, 8), 0, stream>>>(W1, W1t, 93, 5120, 96, 0, 0);
  k_t2b<<<dim3(16, 160, 1), dim3(32, 8), 0, stream>>>(W2, W2t, 5120, 512, 5120, 0, 0);
  k_t2b<<<dim3(64, 16, 2), dim3(32, 8), 0, stream>>>(f1w, f1wt, 512, 2048, 512,
                                                     512L * 2048, 2048L * 512);
  k_t2b<<<dim3(16, 64, 2), dim3(32, 8), 0, stream>>>(f2w, f2wt, 2048, 512, 2048,
                                                     2048L * 512, 512L * 2048);
  k_prep_wv<<<2048, 256, 0, stream>>>(in_w, Wvb);
  k_t2b<<<dim3(16, 16, 2), dim3(32, 8), 0, stream>>>(out_w, WoT, 512, 512, 512,
                                                     262144, 262144);
  // Wvot[n][k] = sum_j WoT[n][j] * Wvb[k][j]  (bf16 out, = (Wv@Wo)^T)
  k_mm<4, 4, 0, false, false, bf16><<<dim3(4, 4, 2), 256, 0, stream>>>(
      WoT, Wvb, nullptr, nullptr, Wvot, 512, 512, 512, 512, 512,
      262144, 262144, 262144, 0);
  k_bvo<<<4, 256, 0, stream>>>(in_b, out_w, out_b, bvo);

  // GAT-1: aggregate 93-wide (all heads per wave), then project per-head with MFMA
  k_gat1<<<NN / 4, 256, 0, stream>>>(offsets, csr_src, csr_eid, eattr, lattr,
                                     S1, D1b, wee1, x1, xaggp);
  // h1 = elu(xagg @ W1 + b1): z=10 heads, M=4096, N=512, K=96
  k_mm<4, 4, 2, true, false, bf16><<<dim3(4, 32, 10), 256, 0, stream>>>(
      xaggp, W1t, b1, nullptr, h1, NN, 96, 960, 96, 5120, 96, 512L * 96, 512, 512);

  k_logits2<<<NN / 4, 256, 0, stream>>>(h1, w2s, w2d, s2, d2v);
  // xs2 = h1 @ W2 via split-K=2 (z in {0,1}, K-window 2560 each) -> f32 partials
  k_mm<2, 4, 0, false, false, float><<<dim3(4, 64, 2), 256, 0, stream>>>(
      h1, W2t, nullptr, nullptr, pbufA, NN, 2560, 5120, 5120, 512,
      2560, 2560, pdz, 0);
  k_red2bf<<<2048, 256, 0, stream>>>(pbufA, pbufB, xs2);
  k_gat2<<<NN / 4, 256, 0, stream>>>(offsets, csr_src, csr_eid, eattr, lattr,
                                     s2, d2v, we2e, xs2, b2, h2f, hbf, alpha2);

  for (int i = 0; i < 2; i++){
    // tmp = h2 + h2 @ Wvo + bvo   (BN=64 tiles: 512 blocks = 2/CU)
    k_mm<2, 2, 0, true, true, float><<<dim3(8, 64, 1), 256, 0, stream>>>(
        hbf, Wvot + (size_t)i * 262144, bvo + i * 512, h2f, tmp,
        NN, 512, 512, 512, 512, 0, 0, 0, 0);
    k_ln<<<NN / 4, 256, 0, stream>>>(tmp, ln1g + i * 512, ln1b + i * 512, h2f, hbf);
    // fbuf = relu(h @ f1w + f1b): N=2048, K=512
    k_mm<4, 4, 1, true, false, bf16><<<dim3(16, 32, 1), 256, 0, stream>>>(
        hbf, f1wt + (size_t)i * 2048 * 512, f1b + i * 2048, nullptr, fbuf,
        NN, 512, 512, 512, 2048, 0, 0, 0, 0);
    // FFN2 split-K=2: partials (K-window 1024 each), reduce fused into LN
    k_mm<2, 4, 0, false, false, float><<<dim3(4, 64, 2), 256, 0, stream>>>(
        fbuf, f2wt + (size_t)i * 512 * 2048, nullptr, nullptr, pbufA,
        NN, 1024, 2048, 2048, 512, 1024, 1024, pdz, 0);
    k_ln_fr<<<NN / 4, 256, 0, stream>>>(pbufA, pbufB, f2b + i * 512, h2f,
                                        ln2g + i * 512, ln2b + i * 512, h2f, hbf);
  }

  k_pool<<<64, 512, 0, stream>>>(h2f, out_pool);
}

// Round 8
// 495.347 us; speedup vs baseline: 5.1514x; 1.0950x over previous
//
#include <hip/hip_runtime.h>
#include <hip/hip_bf16.h>

#define NN 4096
#define EE 16384
#define ET 20480   // EE + NN

typedef __hip_bfloat16 bf16;
typedef __bf16 bfv8 __attribute__((ext_vector_type(8)));
typedef float fv4 __attribute__((ext_vector_type(4)));

__device__ __forceinline__ float warp_max(float v){
#pragma unroll
  for (int o = 32; o; o >>= 1) v = fmaxf(v, __shfl_xor(v, o));
  return v;
}
__device__ __forceinline__ float warp_sum(float v){
#pragma unroll
  for (int o = 32; o; o >>= 1) v += __shfl_xor(v, o);
  return v;
}
__device__ __forceinline__ float bf2f(unsigned short u){
  return __uint_as_float((unsigned)u << 16);
}

// async global->LDS, 16B per lane. lbase = wave-uniform LDS base (lane*16 added by HW).
__device__ __forceinline__ void gl_lds16(const void* g, void* lbase, int lane){
#if __has_builtin(__builtin_amdgcn_global_load_lds)
  __builtin_amdgcn_global_load_lds(
      (const __attribute__((address_space(1))) unsigned int*)g,
      (__attribute__((address_space(3))) unsigned int*)lbase, 16, 0, 0);
#else
  *(uint4*)((char*)lbase + lane * 16) = *(const uint4*)g;
#endif
}

// ---------------- graph preprocessing ----------------

__global__ void k_deg_esum(const int* __restrict__ dst0, const float* __restrict__ eattr,
                           int* deg, float* esum){
  int e = blockIdx.x * 256 + threadIdx.x;
  if (e >= EE) return;
  int d = dst0[e];
  atomicAdd(&deg[d], 1);
  const float* ar = eattr + (size_t)e * 11;
  float* er = esum + (size_t)d * 11;
#pragma unroll
  for (int j = 0; j < 11; j++) atomicAdd(&er[j], ar[j]);
}

__global__ void k_loop_attr(const float* __restrict__ esum, const int* __restrict__ deg,
                            float* lattr){
  int n = blockIdx.x * 256 + threadIdx.x;
  if (n >= NN) return;
  float c = fmaxf((float)deg[n], 1.0f);
#pragma unroll
  for (int j = 0; j < 11; j++) lattr[n * 11 + j] = esum[n * 11 + j] / c;
}

__global__ void k_scan(const int* __restrict__ deg, int* offsets){
  __shared__ int sums[256];
  int t = threadIdx.x;
  int base = t * 16;
  int vals[16];
  int s = 0;
#pragma unroll
  for (int j = 0; j < 16; j++){ vals[j] = s; s += deg[base + j] + 1; }
  sums[t] = s;
  __syncthreads();
  for (int off = 1; off < 256; off <<= 1){
    int v = (t >= off) ? sums[t - off] : 0;
    __syncthreads();
    sums[t] += v;
    __syncthreads();
  }
  int pre = (t == 0) ? 0 : sums[t - 1];
#pragma unroll
  for (int j = 0; j < 16; j++) offsets[base + j] = pre + vals[j];
  if (t == 255) offsets[NN] = sums[255];
}

__global__ void k_scatter(const int* __restrict__ src0, const int* __restrict__ dst0,
                          const int* __restrict__ offsets, int* cursor,
                          int* csr_src, int* csr_eid){
  int t = blockIdx.x * 256 + threadIdx.x;
  if (t < EE){
    int d = dst0[t];
    int pos = offsets[d] + atomicAdd(&cursor[d], 1);
    csr_src[pos] = src0[t];
    csr_eid[pos] = t;
  } else if (t < EE + NN){
    int n = t - EE;
    int pos = offsets[n + 1] - 1;
    csr_src[pos] = n;
    csr_eid[pos] = EE + n;
  }
}

// ---------------- merged weight folds: fold1 + fold2 + bvo ----------------

__global__ void k_folds(const float* __restrict__ W1, const float* __restrict__ as1,
                        const float* __restrict__ ad1, const float* __restrict__ We1,
                        const float* __restrict__ ae1,
                        const float* __restrict__ W2, const float* __restrict__ as2,
                        const float* __restrict__ ad2, const float* __restrict__ We2,
                        const float* __restrict__ ae2,
                        const float* __restrict__ in_b, const float* __restrict__ out_w,
                        const float* __restrict__ out_b,
                        float* wse1, float* wsd1, float* wee1,
                        float* w2s, float* w2d, float* we2e, float* bvo){
  int blk = blockIdx.x;
  if (blk < 5){
    int t = blk * 256 + threadIdx.x;
    if (t < 930){
      int k = t / 10, h = t % 10;
      const float* wr = W1 + (size_t)k * 5120 + h * 512;
      const float* asr = as1 + h * 512;
      const float* adr = ad1 + h * 512;
      float ss = 0, sd = 0;
      for (int c = 0; c < 512; c++){ float w = wr[c]; ss += w * asr[c]; sd += w * adr[c]; }
      wse1[t] = ss; wsd1[t] = sd;
    } else if (t < 1040){
      int u = t - 930;
      int k = u / 10, h = u % 10;
      const float* wr = We1 + (size_t)k * 5120 + h * 512;
      const float* aer = ae1 + h * 512;
      float se = 0;
      for (int c = 0; c < 512; c++) se += wr[c] * aer[c];
      wee1[u] = se;
    }
  } else if (blk < 26){
    int t = (blk - 5) * 256 + threadIdx.x;
    if (t < 5120){
      const float* wr = W2 + (size_t)t * 512;
      float ss = 0, sd = 0;
      for (int c = 0; c < 512; c++){ float w = wr[c]; ss += w * as2[c]; sd += w * ad2[c]; }
      w2s[t] = ss; w2d[t] = sd;
    } else if (t < 5131){
      int k = t - 5120;
      const float* wr = We2 + (size_t)k * 512;
      float se = 0;
      for (int c = 0; c < 512; c++) se += wr[c] * ae2[c];
      we2e[k] = se;
    }
  } else {
    int t = (blk - 26) * 256 + threadIdx.x;
    if (t < 1024){
      int i = t >> 9, c = t & 511;
      const float* ib = in_b + i * 1536 + 1024;
      const float* ow = out_w + (size_t)i * 262144;
      float s = out_b[i * 512 + c];
      for (int k = 0; k < 512; k++) s += ib[k] * ow[(size_t)k * 512 + c];
      bvo[t] = s;
    }
  }
}

__global__ void k_logits1(const float* __restrict__ x1, const float* __restrict__ wse1,
                          const float* __restrict__ wsd1, float* S1, float* D1){
  int t = blockIdx.x * 256 + threadIdx.x;
  int n = t / 10, h = t % 10;
  const float* xr = x1 + (size_t)n * 93;
  float s = 0, d = 0;
  for (int k = 0; k < 93; k++){ float x = xr[k]; s += x * wse1[k * 10 + h]; d += x * wsd1[k * 10 + h]; }
  S1[t] = s; D1[t] = d;
}

// ---------------- weight prep ----------------

// dst[n][k(dK)] = bf16(src[k][n]) for k<K (0 for K<=k<dK); src [K][N] f32
__global__ void k_t2b(const float* __restrict__ src, bf16* __restrict__ dst,
                      int K, int N, int dK, long sZ, long dZ){
  __shared__ float t[32][33];
  src += (size_t)blockIdx.z * sZ;
  dst += (size_t)blockIdx.z * dZ;
  int k0 = blockIdx.y * 32, n0 = blockIdx.x * 32;
  int x = threadIdx.x, y = threadIdx.y;   // 32 x 8
#pragma unroll
  for (int yy = y; yy < 32; yy += 8){
    int k = k0 + yy, n = n0 + x;
    t[yy][x] = (k < K && n < N) ? src[(size_t)k * N + n] : 0.f;
  }
  __syncthreads();
#pragma unroll
  for (int yy = y; yy < 32; yy += 8){
    int n = n0 + yy, k = k0 + x;
    if (n < N && k < dK) dst[(size_t)n * dK + k] = __float2bfloat16(t[x][yy]);
  }
}

// Wvb[i][k][j] = bf16(in_w[i][k][1024+j])   (512x512 slice, row-major)
__global__ void k_prep_wv(const float* __restrict__ in_w, bf16* __restrict__ Wvb){
  int t = blockIdx.x * 256 + threadIdx.x;   // < 2*512*512
  int i = t >> 18, rem = t & 262143, k = rem >> 9, j = rem & 511;
  Wvb[t] = __float2bfloat16(in_w[(size_t)i * 786432 + (size_t)k * 1536 + 1024 + j]);
}

// ---------------- GAT layer 1: one wave per node, all 10 heads ----------------

__global__ __launch_bounds__(256) void k_gat1(
    const int* __restrict__ offsets, const int* __restrict__ csr_src,
    const int* __restrict__ csr_eid, const float* __restrict__ eattr,
    const float* __restrict__ lattr, const float* __restrict__ S1,
    const float* __restrict__ D1, const float* __restrict__ wee1,
    const float* __restrict__ x1, bf16* __restrict__ xaggp){
  int n = (blockIdx.x * 256 + threadIdx.x) >> 6;
  int lane = threadIdx.x & 63;
  int start = offsets[n], end = offsets[n + 1];
  int deg = end - start;

  if (deg <= 64){
    bool act = lane < deg;
    int s = 0, eid = 0;
    float ea[11];
#pragma unroll
    for (int j = 0; j < 11; j++) ea[j] = 0.f;
    if (act){
      s = csr_src[start + lane];
      eid = csr_eid[start + lane];
      const float* eap = (eid < EE) ? eattr + (size_t)eid * 11
                                    : lattr + (size_t)(eid - EE) * 11;
#pragma unroll
      for (int j = 0; j < 11; j++) ea[j] = eap[j];
    }
    float alpha[10];
#pragma unroll
    for (int h = 0; h < 10; h++){
      float eel = 0;
#pragma unroll
      for (int j = 0; j < 11; j++) eel += ea[j] * wee1[j * 10 + h];
      float lg = -1e30f;
      if (act){
        lg = S1[s * 10 + h] + D1[n * 10 + h] + eel;
        lg = lg > 0.f ? lg : 0.2f * lg;
      }
      float m = warp_max(lg);
      float pv = act ? __expf(lg - m) : 0.f;
      float sum = warp_sum(pv);
      alpha[h] = pv / sum;
    }
    float acc0[10], acc1[10];
#pragma unroll
    for (int h = 0; h < 10; h++){ acc0[h] = 0.f; acc1[h] = 0.f; }
    for (int e = 0; e < deg; e++){
      int se = __shfl(s, e);
      const float* xr = x1 + (size_t)se * 93;
      float xv0 = xr[lane];
      float xv1 = (lane < 29) ? xr[64 + lane] : 0.f;
#pragma unroll
      for (int h = 0; h < 10; h++){
        float al = __shfl(alpha[h], e);
        acc0[h] += al * xv0;
        acc1[h] += al * xv1;
      }
    }
#pragma unroll
    for (int h = 0; h < 10; h++){
      bf16* o = xaggp + (size_t)(n * 10 + h) * 96;
      o[lane] = __float2bfloat16(acc0[h]);
      if (lane < 29) o[64 + lane] = __float2bfloat16(acc1[h]);
      else if (lane < 32) o[64 + lane] = __float2bfloat16(0.f);
    }
  } else {
    // general fallback (3-pass per head)
    for (int h = 0; h < 10; h++){
      float dl = D1[n * 10 + h];
      float wl[11];
#pragma unroll
      for (int j = 0; j < 11; j++) wl[j] = wee1[j * 10 + h];
      float m = -1e30f;
      for (int pos = start + lane; pos < end; pos += 64){
        int s = csr_src[pos]; int eid = csr_eid[pos];
        const float* ea = (eid < EE) ? eattr + (size_t)eid * 11 : lattr + (size_t)(eid - EE) * 11;
        float eel = 0;
#pragma unroll
        for (int j = 0; j < 11; j++) eel += ea[j] * wl[j];
        float lg = S1[s * 10 + h] + dl + eel;
        lg = lg > 0.f ? lg : 0.2f * lg;
        m = fmaxf(m, lg);
      }
      m = warp_max(m);
      float ps = 0;
      for (int pos = start + lane; pos < end; pos += 64){
        int s = csr_src[pos]; int eid = csr_eid[pos];
        const float* ea = (eid < EE) ? eattr + (size_t)eid * 11 : lattr + (size_t)(eid - EE) * 11;
        float eel = 0;
#pragma unroll
        for (int j = 0; j < 11; j++) eel += ea[j] * wl[j];
        float lg = S1[s * 10 + h] + dl + eel;
        lg = lg > 0.f ? lg : 0.2f * lg;
        ps += __expf(lg - m);
      }
      ps = warp_sum(ps);
      float inv = 1.0f / ps;
      float acc0 = 0, acc1 = 0;
      for (int pos = start; pos < end; pos++){
        int s = csr_src[pos]; int eid = csr_eid[pos];
        const float* ea = (eid < EE) ? eattr + (size_t)eid * 11 : lattr + (size_t)(eid - EE) * 11;
        float eel = 0;
#pragma unroll
        for (int j = 0; j < 11; j++) eel += ea[j] * wl[j];
        float lg = S1[s * 10 + h] + dl + eel;
        lg = lg > 0.f ? lg : 0.2f * lg;
        float alpha = __expf(lg - m) * inv;
        const float* xr = x1 + (size_t)s * 93;
        acc0 += alpha * xr[lane];
        if (lane < 29) acc1 += alpha * xr[64 + lane];
      }
      bf16* o = xaggp + (size_t)(n * 10 + h) * 96;
      o[lane] = __float2bfloat16(acc0);
      if (lane < 29) o[64 + lane] = __float2bfloat16(acc1);
      else if (lane < 32) o[64 + lane] = __float2bfloat16(0.f);
    }
  }
}

// ---------------- GAT layer 2: one wave per node, lane-parallel softmax ----------------

__global__ __launch_bounds__(256) void k_gat2(
    const int* __restrict__ offsets, const int* __restrict__ csr_src,
    const int* __restrict__ csr_eid, const float* __restrict__ eattr,
    const float* __restrict__ lattr, const float* __restrict__ s2,
    const float* __restrict__ d2, const float* __restrict__ we2e,
    const bf16* __restrict__ xs2, const float* __restrict__ b2,
    float* __restrict__ h2f, bf16* __restrict__ hbf, float* __restrict__ alpha_out){
  int n = (blockIdx.x * 256 + threadIdx.x) >> 6;
  int lane = threadIdx.x & 63;
  int start = offsets[n], end = offsets[n + 1];
  int deg = end - start;
  float dl = d2[n];

  float acc[8] = {0, 0, 0, 0, 0, 0, 0, 0};

  if (deg <= 64){
    bool act = lane < deg;
    int s = 0, eid = 0;
    float eel = 0.f;
    if (act){
      s = csr_src[start + lane];
      eid = csr_eid[start + lane];
      const float* eap = (eid < EE) ? eattr + (size_t)eid * 11
                                    : lattr + (size_t)(eid - EE) * 11;
#pragma unroll
      for (int j = 0; j < 11; j++) eel += eap[j] * we2e[j];
    }
    float lg = -1e30f;
    if (act){
      lg = s2[s] + dl + eel;
      lg = lg > 0.f ? lg : 0.2f * lg;
    }
    float m = warp_max(lg);
    float pv = act ? __expf(lg - m) : 0.f;
    float sum = warp_sum(pv);
    float alpha = pv / sum;
    if (act) alpha_out[eid] = alpha;

    for (int e = 0; e < deg; e++){
      int se = __shfl(s, e);
      float al = __shfl(alpha, e);
      union { uint4 u; unsigned short sh[8]; } xv;
      xv.u = *(const uint4*)&xs2[(size_t)se * 512 + lane * 8];
#pragma unroll
      for (int jj = 0; jj < 8; jj++) acc[jj] += al * bf2f(xv.sh[jj]);
    }
  } else {
    // general fallback (3-pass)
    float wl[11];
#pragma unroll
    for (int j = 0; j < 11; j++) wl[j] = we2e[j];
    float m = -1e30f;
    for (int pos = start + lane; pos < end; pos += 64){
      int s = csr_src[pos]; int eid = csr_eid[pos];
      const float* ea = (eid < EE) ? eattr + (size_t)eid * 11 : lattr + (size_t)(eid - EE) * 11;
      float eel = 0;
#pragma unroll
      for (int j = 0; j < 11; j++) eel += ea[j] * wl[j];
      float lg = s2[s] + dl + eel;
      lg = lg > 0.f ? lg : 0.2f * lg;
      m = fmaxf(m, lg);
    }
    m = warp_max(m);
    float ps = 0;
    for (int pos = start + lane; pos < end; pos += 64){
      int s = csr_src[pos]; int eid = csr_eid[pos];
      const float* ea = (eid < EE) ? eattr + (size_t)eid * 11 : lattr + (size_t)(eid - EE) * 11;
      float eel = 0;
#pragma unroll
      for (int j = 0; j < 11; j++) eel += ea[j] * wl[j];
      float lg = s2[s] + dl + eel;
      lg = lg > 0.f ? lg : 0.2f * lg;
      ps += __expf(lg - m);
    }
    ps = warp_sum(ps);
    float inv = 1.0f / ps;
    for (int pos = start; pos < end; pos++){
      int s = csr_src[pos]; int eid = csr_eid[pos];
      const float* ea = (eid < EE) ? eattr + (size_t)eid * 11 : lattr + (size_t)(eid - EE) * 11;
      float eel = 0;
#pragma unroll
      for (int j = 0; j < 11; j++) eel += ea[j] * wl[j];
      float lg = s2[s] + dl + eel;
      lg = lg > 0.f ? lg : 0.2f * lg;
      float alpha = __expf(lg - m) * inv;
      if (lane == 0) alpha_out[eid] = alpha;
      union { uint4 u; unsigned short sh[8]; } xv;
      xv.u = *(const uint4*)&xs2[(size_t)s * 512 + lane * 8];
#pragma unroll
      for (int jj = 0; jj < 8; jj++) acc[jj] += alpha * bf2f(xv.sh[jj]);
    }
  }

#pragma unroll
  for (int jj = 0; jj < 8; jj++){
    int c = lane * 8 + jj;
    float v = acc[jj] + b2[c];
    v = v > 0.f ? v : (__expf(v) - 1.f);
    h2f[(size_t)n * 512 + c] = v;
    hbf[(size_t)n * 512 + c] = __float2bfloat16(v);
  }
}

// ---------------- MFMA bf16 GEMM: C = act(A @ Bt^T + bias + res) ----------------
// A [M,K+] bf16 (row stride lda), Bt [N,K+] bf16 (row stride ldb), C [M,ldc].
// K%32==0. z-dim: aZ/bZ shift A/Bt (batching AND split-K), cZ shifts C.
// Double-buffered LDS, one barrier per K-step. LDS XOR swizzle (both-sides:
// pre-swizzled global source col + swizzled ds_read col). Bijective XCD
// swizzle over 2D grid (gridDim.x*gridDim.y % 8 == 0).
// LOG: epilogue also atomically accumulates s2 += C·w2s, d2 += C·w2d per row
// (w2s/w2d shifted by z*biasZ like bias).

__device__ __forceinline__ void stC_elem(float* p, float v){ *p = v; }
__device__ __forceinline__ void stC_elem(bf16* p, float v){ *p = __float2bfloat16(v); }

template <int BMF, int BNF, int ACT, bool BIAS, bool RES, bool LOG, typename TC>
__global__ __launch_bounds__(256) void k_mm(
    const bf16* __restrict__ A, const bf16* __restrict__ Bt,
    const float* __restrict__ bias, const float* __restrict__ res,
    TC* __restrict__ C, int M, int K, int lda, int ldb, int ldc,
    long aZ, long bZ, long cZ, long biasZ,
    const float* __restrict__ w2s, const float* __restrict__ w2d,
    float* __restrict__ s2, float* __restrict__ d2){
  constexpr int BM = BMF * 32, BN = BNF * 32;
  __shared__ __align__(16) bf16 As[2][BM * 32];
  __shared__ __align__(16) bf16 Bs[2][BN * 32];
  const int tid = threadIdx.x, wave = tid >> 6, lane = tid & 63;

  const int nwg = gridDim.x * gridDim.y;
  const int id = blockIdx.y * gridDim.x + blockIdx.x;
  const int cpx = nwg >> 3;
  const int swz = (id & 7) * cpx + (id >> 3);
  const int bm = (swz / gridDim.x) * BM, bn = (swz % gridDim.x) * BN;

  const int z = blockIdx.z;
  A  += (size_t)z * aZ;
  Bt += (size_t)z * bZ;
  C  += (size_t)z * cZ;
  const float* bp = BIAS ? bias + (size_t)z * biasZ : nullptr;

  const int trow = tid >> 2;
  const int stk = ((tid & 3) * 8) ^ ((trow & 3) << 3);   // pre-swizzled source col
  const int wr = (wave >> 1) * (BMF * 16), wc = (wave & 1) * (BNF * 16);
  const int r = lane & 15, kq = lane >> 4;
  const int swcol = ((kq ^ (r & 3)) << 3);               // swizzled ds_read col

  fv4 acc[BMF][BNF] = {};

  auto STAGE = [&](int buf, int k0){
#pragma unroll
    for (int s = 0; s < BM / 64; s++)
      gl_lds16(A + (size_t)(bm + s * 64 + trow) * lda + k0 + stk,
               (char*)&As[buf][0] + s * 4096 + wave * 1024, lane);
#pragma unroll
    for (int s = 0; s < BN / 64; s++)
      gl_lds16(Bt + (size_t)(bn + s * 64 + trow) * ldb + k0 + stk,
               (char*)&Bs[buf][0] + s * 4096 + wave * 1024, lane);
  };

  STAGE(0, 0);
  int cur = 0;
  for (int k0 = 0; k0 < K; k0 += 32){
    __syncthreads();
    if (k0 + 32 < K) STAGE(cur ^ 1, k0 + 32);

    bfv8 a[BMF], b[BNF];
#pragma unroll
    for (int i = 0; i < BMF; i++)
      a[i] = *(const bfv8*)&As[cur][(wr + i * 16 + r) * 32 + swcol];
#pragma unroll
    for (int j = 0; j < BNF; j++)
      b[j] = *(const bfv8*)&Bs[cur][(wc + j * 16 + r) * 32 + swcol];
#pragma unroll
    for (int i = 0; i < BMF; i++)
#pragma unroll
      for (int j = 0; j < BNF; j++)
        acc[i][j] = __builtin_amdgcn_mfma_f32_16x16x32_bf16(a[i], b[j], acc[i][j], 0, 0, 0);
    cur ^= 1;
  }

  const int rb = bm + wr + (lane >> 4) * 4;
  const int cb = bn + wc + (lane & 15);
  float ls[BMF][4], ld[BMF][4];
  if (LOG){
#pragma unroll
    for (int i = 0; i < BMF; i++)
#pragma unroll
      for (int q = 0; q < 4; q++){ ls[i][q] = 0.f; ld[i][q] = 0.f; }
  }
  const float* wsp = LOG ? w2s + (size_t)z * biasZ : nullptr;
  const float* wdp = LOG ? w2d + (size_t)z * biasZ : nullptr;

#pragma unroll
  for (int i = 0; i < BMF; i++)
#pragma unroll
    for (int j = 0; j < BNF; j++){
      int gn = cb + j * 16;
      float bv = BIAS ? bp[gn] : 0.f;
#pragma unroll
      for (int q = 0; q < 4; q++){
        int gm = rb + i * 16 + q;
        float v = acc[i][j][q] + bv;
        if (RES) v += res[(size_t)gm * ldc + gn];
        if (ACT == 1) v = fmaxf(v, 0.f);
        if (ACT == 2) v = v > 0.f ? v : (__expf(v) - 1.f);
        if (LOG){ ls[i][q] += v * wsp[gn]; ld[i][q] += v * wdp[gn]; }
        stC_elem(&C[(size_t)gm * ldc + gn], v);
      }
    }

  if (LOG){
#pragma unroll
    for (int i = 0; i < BMF; i++)
#pragma unroll
      for (int q = 0; q < 4; q++){
        float a = ls[i][q], b = ld[i][q];
#pragma unroll
        for (int o = 1; o < 16; o <<= 1){ a += __shfl_xor(a, o); b += __shfl_xor(b, o); }
        if ((lane & 15) == 0){
          int gm = rb + i * 16 + q;
          atomicAdd(&s2[gm], a);
          atomicAdd(&d2[gm], b);
        }
      }
  }
}

// ---------------- split-K reduces ----------------

__global__ void k_red2bf(const float* __restrict__ pA, const float* __restrict__ pB,
                         bf16* __restrict__ out){
  int t = (blockIdx.x * 256 + threadIdx.x) * 4;
  float4 a = *(const float4*)&pA[t];
  float4 b = *(const float4*)&pB[t];
  out[t]     = __float2bfloat16(a.x + b.x);
  out[t + 1] = __float2bfloat16(a.y + b.y);
  out[t + 2] = __float2bfloat16(a.z + b.z);
  out[t + 3] = __float2bfloat16(a.w + b.w);
}

__global__ void k_red4bf(const float* __restrict__ p, long st, bf16* __restrict__ out){
  int t = (blockIdx.x * 256 + threadIdx.x) * 4;
  float4 a = *(const float4*)&p[t];
  float4 b = *(const float4*)&p[st + t];
  float4 c = *(const float4*)&p[2 * st + t];
  float4 d = *(const float4*)&p[3 * st + t];
  out[t]     = __float2bfloat16(a.x + b.x + c.x + d.x);
  out[t + 1] = __float2bfloat16(a.y + b.y + c.y + d.y);
  out[t + 2] = __float2bfloat16(a.z + b.z + c.z + d.z);
  out[t + 3] = __float2bfloat16(a.w + b.w + c.w + d.w);
}

// ---------------- layernorm variants, pool ----------------

__device__ __forceinline__ void ln_body(float v[8], int lane,
                                        const float* g, const float* b,
                                        float* yf, bf16* ybf, size_t row){
  float s = 0;
#pragma unroll
  for (int j = 0; j < 8; j++) s += v[j];
  s = warp_sum(s);
  float mu = s * (1.0f / 512.0f);
  float var = 0;
#pragma unroll
  for (int j = 0; j < 8; j++){ float d = v[j] - mu; var += d * d; }
  var = warp_sum(var) * (1.0f / 512.0f);
  float inv = rsqrtf(var + 1e-5f);
#pragma unroll
  for (int j = 0; j < 8; j++){
    int c = lane + j * 64;
    float o = (v[j] - mu) * inv * g[c] + b[c];
    yf[row * 512 + c] = o;
    ybf[row * 512 + c] = __float2bfloat16(o);
  }
}

__global__ __launch_bounds__(256) void k_ln(const float* __restrict__ x,
                                            const float* __restrict__ g,
                                            const float* __restrict__ b,
                                            float* __restrict__ yf,
                                            bf16* __restrict__ ybf){
  int wid = (blockIdx.x * 256 + threadIdx.x) >> 6;
  int lane = threadIdx.x & 63;
  const float* xr = x + (size_t)wid * 512;
  float v[8];
#pragma unroll
  for (int j = 0; j < 8; j++) v[j] = xr[lane + j * 64];
  ln_body(v, lane, g, b, yf, ybf, (size_t)wid);
}

// fused split-K reduce + bias + residual + LN
__global__ __launch_bounds__(256) void k_ln_fr(const float* __restrict__ pA,
                                               const float* __restrict__ pB,
                                               const float* __restrict__ bias,
                                               const float* __restrict__ res,
                                               const float* __restrict__ g,
                                               const float* __restrict__ b,
                                               float* __restrict__ yf,
                                               bf16* __restrict__ ybf){
  int wid = (blockIdx.x * 256 + threadIdx.x) >> 6;
  int lane = threadIdx.x & 63;
  size_t base = (size_t)wid * 512;
  float v[8];
#pragma unroll
  for (int j = 0; j < 8; j++){
    int c = lane + j * 64;
    v[j] = pA[base + c] + pB[base + c] + bias[c] + res[base + c];
  }
  ln_body(v, lane, g, b, yf, ybf, (size_t)wid);
}

__global__ void k_pool(const float* __restrict__ h, float* __restrict__ out){
  int b = blockIdx.x;
  int c = threadIdx.x;   // 512 threads
  const float* hr = h + (size_t)b * 64 * 512;
  float m = -1e30f;
  for (int i = 0; i < 64; i++) m = fmaxf(m, hr[i * 512 + c]);
  out[(size_t)b * 512 + c] = m;
}

// ---------------- launcher ----------------

extern "C" void kernel_launch(void* const* d_in, const int* in_sizes, int n_in,
                              void* d_out, int out_size, void* d_ws, size_t ws_size,
                              hipStream_t stream){
  const float* x1    = (const float*)d_in[0];
  const int*   ei    = (const int*)d_in[1];
  const float* eattr = (const float*)d_in[2];
  const float* W1    = (const float*)d_in[4];
  const float* as1   = (const float*)d_in[5];
  const float* ad1   = (const float*)d_in[6];
  const float* We1   = (const float*)d_in[7];
  const float* ae1   = (const float*)d_in[8];
  const float* b1    = (const float*)d_in[9];
  const float* W2    = (const float*)d_in[10];
  const float* as2   = (const float*)d_in[11];
  const float* ad2   = (const float*)d_in[12];
  const float* We2   = (const float*)d_in[13];
  const float* ae2   = (const float*)d_in[14];
  const float* b2    = (const float*)d_in[15];
  const float* in_w  = (const float*)d_in[16];
  const float* in_b  = (const float*)d_in[17];
  const float* out_w = (const float*)d_in[18];
  const float* out_b = (const float*)d_in[19];
  const float* ln1g  = (const float*)d_in[20];
  const float* ln1b  = (const float*)d_in[21];
  const float* f1w   = (const float*)d_in[22];
  const float* f1b   = (const float*)d_in[23];
  const float* f2w   = (const float*)d_in[24];
  const float* f2b   = (const float*)d_in[25];
  const float* ln2g  = (const float*)d_in[26];
  const float* ln2b  = (const float*)d_in[27];

  const int* src0 = ei;
  const int* dst0 = ei + EE;

  char* p = (char*)d_ws;
  auto alloc = [&](size_t bytes) -> void* {
    void* r = p;
    p += (bytes + 255) & ~(size_t)255;
    return r;
  };
  // contiguous zero-init region: deg, cursor, s2, d2v, esum  (one memset)
  int*   deg     = (int*)alloc(NN * 4);
  int*   cursor  = (int*)alloc(NN * 4);
  float* s2      = (float*)alloc(NN * 4);
  float* d2v     = (float*)alloc(NN * 4);
  float* esum    = (float*)alloc(NN * 11 * 4);
  size_t zbytes  = (char*)p - (char*)deg;

  float* lattr   = (float*)alloc(NN * 11 * 4);
  int*   offsets = (int*)alloc((NN + 1) * 4);
  int*   csr_src = (int*)alloc(ET * 4);
  int*   csr_eid = (int*)alloc(ET * 4);
  float* wse1    = (float*)alloc(930 * 4);
  float* wsd1    = (float*)alloc(930 * 4);
  float* wee1    = (float*)alloc(110 * 4);
  float* S1      = (float*)alloc(NN * 10 * 4);
  float* D1b     = (float*)alloc(NN * 10 * 4);
  bf16*  xaggp   = (bf16*)alloc((size_t)NN * 10 * 96 * 2);
  bf16*  W1t     = (bf16*)alloc((size_t)5120 * 96 * 2);
  bf16*  W2t     = (bf16*)alloc((size_t)512 * 5120 * 2);
  bf16*  f1wt    = (bf16*)alloc((size_t)2 * 2048 * 512 * 2);
  bf16*  f2wt    = (bf16*)alloc((size_t)2 * 512 * 2048 * 2);
  bf16*  Wvb     = (bf16*)alloc((size_t)2 * 512 * 512 * 2);
  bf16*  WoT     = (bf16*)alloc((size_t)2 * 512 * 512 * 2);
  bf16*  Wvot    = (bf16*)alloc((size_t)2 * 512 * 512 * 2);
  bf16*  h1      = (bf16*)alloc((size_t)NN * 5120 * 2);   // dead after xs2; reused below
  float* w2s     = (float*)alloc(5120 * 4);
  float* w2d     = (float*)alloc(5120 * 4);
  float* we2e    = (float*)alloc(16 * 4);
  bf16*  xs2     = (bf16*)alloc((size_t)NN * 512 * 2);
  float* h2f     = (float*)alloc((size_t)NN * 512 * 4);
  bf16*  hbf     = (bf16*)alloc((size_t)NN * 512 * 2);
  float* bvo     = (float*)alloc(2 * 512 * 4);
  float* pbuf    = (float*)alloc((size_t)NN * 512 * 4 * 2);   // 2 split-K partials (always)
  long   pdz     = (long)NN * 512;
  // optional 2 more partials for split-K=4, if workspace allows
  size_t used2   = (char*)p - (char*)d_ws;
  bool   sk4     = (used2 + 2 * (size_t)NN * 512 * 4 + 256 <= ws_size);
  float* pbufHi  = sk4 ? (float*)alloc((size_t)NN * 512 * 4 * 2) : nullptr;
  (void)pbufHi;
  // aliases into dead h1 region (40 MB): tmp (8 MB) + fbuf (16 MB)
  float* tmp  = (float*)h1;
  bf16*  fbuf = (bf16*)((char*)h1 + (size_t)NN * 512 * 4);

  float* out_pool = (float*)d_out;
  float* alpha2   = out_pool + 64 * 512;

  hipMemsetAsync(deg, 0, zbytes, stream);

  // graph prep + folds
  k_deg_esum<<<EE / 256, 256, 0, stream>>>(dst0, eattr, deg, esum);
  k_loop_attr<<<NN / 256, 256, 0, stream>>>(esum, deg, lattr);
  k_scan<<<1, 256, 0, stream>>>(deg, offsets);
  k_scatter<<<(EE + NN) / 256, 256, 0, stream>>>(src0, dst0, offsets, cursor, csr_src, csr_eid);
  k_folds<<<30, 256, 0, stream>>>(W1, as1, ad1, We1, ae1, W2, as2, ad2, We2, ae2,
                                  in_b, out_w, out_b,
                                  wse1, wsd1, wee1, w2s, w2d, we2e, bvo);
  k_logits1<<<160, 256, 0, stream>>>(x1, wse1, wsd1, S1, D1b);

  // weight preps
  k_t2b<<<dim3(160, 3, 1), dim3(32, 8), 0, stream>>>(W1, W1t, 93, 5120, 96, 0, 0);
  k_t2b<<<dim3(16, 160, 1), dim3(32, 8), 0, stream>>>(W2, W2t, 5120, 512, 5120, 0, 0);
  k_t2b<<<dim3(64, 16, 2), dim3(32, 8), 0, stream>>>(f1w, f1wt, 512, 2048, 512,
                                                     512L * 2048, 2048L * 512);
  k_t2b<<<dim3(16, 64, 2), dim3(32, 8), 0, stream>>>(f2w, f2wt, 2048, 512, 2048,
                                                     2048L * 512, 512L * 2048);
  k_prep_wv<<<2048, 256, 0, stream>>>(in_w, Wvb);
  k_t2b<<<dim3(16, 16, 2), dim3(32, 8), 0, stream>>>(out_w, WoT, 512, 512, 512,
                                                     262144, 262144);
  // Wvot[n][k] = sum_j WoT[n][j] * Wvb[k][j]  (= (Wv@Wo)^T, bf16)
  k_mm<4, 4, 0, false, false, false, bf16><<<dim3(4, 4, 2), 256, 0, stream>>>(
      WoT, Wvb, nullptr, nullptr, Wvot, 512, 512, 512, 512, 512,
      262144, 262144, 262144, 0, nullptr, nullptr, nullptr, nullptr);

  // GAT-1 aggregate, then per-head MFMA projection with fused logits2 epilogue
  k_gat1<<<NN / 4, 256, 0, stream>>>(offsets, csr_src, csr_eid, eattr, lattr,
                                     S1, D1b, wee1, x1, xaggp);
  // h1 = elu(xagg @ W1 + b1); epilogue: s2 += h1·w2s, d2v += h1·w2d
  k_mm<4, 4, 2, true, false, true, bf16><<<dim3(4, 32, 10), 256, 0, stream>>>(
      xaggp, W1t, b1, nullptr, h1, NN, 96, 960, 96, 5120, 96, 512L * 96, 512, 512,
      w2s, w2d, s2, d2v);

  // xs2 = h1 @ W2, split-K (4 if ws allows, else 2)
  if (sk4){
    k_mm<2, 4, 0, false, false, false, float><<<dim3(4, 64, 4), 256, 0, stream>>>(
        h1, W2t, nullptr, nullptr, pbuf, NN, 1280, 5120, 5120, 512,
        1280, 1280, pdz, 0, nullptr, nullptr, nullptr, nullptr);
    k_red4bf<<<2048, 256, 0, stream>>>(pbuf, pdz, xs2);
  } else {
    k_mm<2, 4, 0, false, false, false, float><<<dim3(4, 64, 2), 256, 0, stream>>>(
        h1, W2t, nullptr, nullptr, pbuf, NN, 2560, 5120, 5120, 512,
        2560, 2560, pdz, 0, nullptr, nullptr, nullptr, nullptr);
    k_red2bf<<<2048, 256, 0, stream>>>(pbuf, pbuf + pdz, xs2);
  }
  k_gat2<<<NN / 4, 256, 0, stream>>>(offsets, csr_src, csr_eid, eattr, lattr,
                                     s2, d2v, we2e, xs2, b2, h2f, hbf, alpha2);

  for (int i = 0; i < 2; i++){
    // tmp = h2 + h2 @ Wvo + bvo   (BN=64 tiles: 512 blocks = 2/CU)
    k_mm<2, 2, 0, true, true, false, float><<<dim3(8, 64, 1), 256, 0, stream>>>(
        hbf, Wvot + (size_t)i * 262144, bvo + i * 512, h2f, tmp,
        NN, 512, 512, 512, 512, 0, 0, 0, 0, nullptr, nullptr, nullptr, nullptr);
    k_ln<<<NN / 4, 256, 0, stream>>>(tmp, ln1g + i * 512, ln1b + i * 512, h2f, hbf);
    // fbuf = relu(h @ f1w + f1b): N=2048, K=512
    k_mm<4, 4, 1, true, false, false, bf16><<<dim3(16, 32, 1), 256, 0, stream>>>(
        hbf, f1wt + (size_t)i * 2048 * 512, f1b + i * 2048, nullptr, fbuf,
        NN, 512, 512, 512, 2048, 0, 0, 0, 0, nullptr, nullptr, nullptr, nullptr);
    // FFN2 split-K=2: partials (K-window 1024 each), reduce fused into LN
    k_mm<2, 4, 0, false, false, false, float><<<dim3(4, 64, 2), 256, 0, stream>>>(
        fbuf, f2wt + (size_t)i * 512 * 2048, nullptr, nullptr, pbuf,
        NN, 1024, 2048, 2048, 512, 1024, 1024, pdz, 0,
        nullptr, nullptr, nullptr, nullptr);
    k_ln_fr<<<NN / 4, 256, 0, stream>>>(pbuf, pbuf + pdz, f2b + i * 512, h2f,
                                        ln2g + i * 512, ln2b + i * 512, h2f, hbf);
  }

  k_pool<<<64, 512, 0, stream>>>(h2f, out_pool);
}

// Round 9
// 453.830 us; speedup vs baseline: 5.6227x; 1.0915x over previous
//
#include <hip/hip_runtime.h>
#include <hip/hip_bf16.h>

#define NN 4096
#define EE 16384
#define ET 20480   // EE + NN

typedef __hip_bfloat16 bf16;
typedef __bf16 bfv8 __attribute__((ext_vector_type(8)));
typedef float fv4 __attribute__((ext_vector_type(4)));

__device__ __forceinline__ float warp_max(float v){
#pragma unroll
  for (int o = 32; o; o >>= 1) v = fmaxf(v, __shfl_xor(v, o));
  return v;
}
__device__ __forceinline__ float warp_sum(float v){
#pragma unroll
  for (int o = 32; o; o >>= 1) v += __shfl_xor(v, o);
  return v;
}
__device__ __forceinline__ float bf2f(unsigned short u){
  return __uint_as_float((unsigned)u << 16);
}

// async global->LDS, 16B per lane. lbase = wave-uniform LDS base (lane*16 added by HW).
__device__ __forceinline__ void gl_lds16(const void* g, void* lbase, int lane){
#if __has_builtin(__builtin_amdgcn_global_load_lds)
  __builtin_amdgcn_global_load_lds(
      (const __attribute__((address_space(1))) unsigned int*)g,
      (__attribute__((address_space(3))) unsigned int*)lbase, 16, 0, 0);
#else
  *(uint4*)((char*)lbase + lane * 16) = *(const uint4*)g;
#endif
}

// ---------------- graph preprocessing ----------------

__global__ void k_deg_esum(const int* __restrict__ dst0, const float* __restrict__ eattr,
                           int* deg, float* esum){
  int e = blockIdx.x * 256 + threadIdx.x;
  if (e >= EE) return;
  int d = dst0[e];
  atomicAdd(&deg[d], 1);
  const float* ar = eattr + (size_t)e * 11;
  float* er = esum + (size_t)d * 11;
#pragma unroll
  for (int j = 0; j < 11; j++) atomicAdd(&er[j], ar[j]);
}

__global__ void k_loop_attr(const float* __restrict__ esum, const int* __restrict__ deg,
                            float* lattr){
  int n = blockIdx.x * 256 + threadIdx.x;
  if (n >= NN) return;
  float c = fmaxf((float)deg[n], 1.0f);
#pragma unroll
  for (int j = 0; j < 11; j++) lattr[n * 11 + j] = esum[n * 11 + j] / c;
}

__global__ void k_scan(const int* __restrict__ deg, int* offsets){
  __shared__ int sums[256];
  int t = threadIdx.x;
  int base = t * 16;
  int vals[16];
  int s = 0;
#pragma unroll
  for (int j = 0; j < 16; j++){ vals[j] = s; s += deg[base + j] + 1; }
  sums[t] = s;
  __syncthreads();
  for (int off = 1; off < 256; off <<= 1){
    int v = (t >= off) ? sums[t - off] : 0;
    __syncthreads();
    sums[t] += v;
    __syncthreads();
  }
  int pre = (t == 0) ? 0 : sums[t - 1];
#pragma unroll
  for (int j = 0; j < 16; j++) offsets[base + j] = pre + vals[j];
  if (t == 255) offsets[NN] = sums[255];
}

__global__ void k_scatter(const int* __restrict__ src0, const int* __restrict__ dst0,
                          const int* __restrict__ offsets, int* cursor,
                          int* csr_src, int* csr_eid){
  int t = blockIdx.x * 256 + threadIdx.x;
  if (t < EE){
    int d = dst0[t];
    int pos = offsets[d] + atomicAdd(&cursor[d], 1);
    csr_src[pos] = src0[t];
    csr_eid[pos] = t;
  } else if (t < EE + NN){
    int n = t - EE;
    int pos = offsets[n + 1] - 1;
    csr_src[pos] = n;
    csr_eid[pos] = EE + n;
  }
}

// ---------------- wave-parallel weight folds: one wave per dot product ----------------
// waves: [0,930) wse1/wsd1 | [930,1040) wee1 | [1040,6160) w2s/w2d |
//        [6160,6171) we2e | [6171,6299) bvo (i x cblock x kchunk, atomicAdd)

__device__ __forceinline__ float dot512(const float* __restrict__ a,
                                        const float* __restrict__ b, int lane){
  float4 a0 = *(const float4*)&a[lane * 8];
  float4 a1 = *(const float4*)&a[lane * 8 + 4];
  float4 b0 = *(const float4*)&b[lane * 8];
  float4 b1 = *(const float4*)&b[lane * 8 + 4];
  return a0.x * b0.x + a0.y * b0.y + a0.z * b0.z + a0.w * b0.w
       + a1.x * b1.x + a1.y * b1.y + a1.z * b1.z + a1.w * b1.w;
}

__global__ __launch_bounds__(256) void k_foldsw(
    const float* __restrict__ W1, const float* __restrict__ as1,
    const float* __restrict__ ad1, const float* __restrict__ We1,
    const float* __restrict__ ae1,
    const float* __restrict__ W2, const float* __restrict__ as2,
    const float* __restrict__ ad2, const float* __restrict__ We2,
    const float* __restrict__ ae2,
    const float* __restrict__ in_b, const float* __restrict__ out_w,
    const float* __restrict__ out_b,
    float* wse1, float* wsd1, float* wee1,
    float* w2s, float* w2d, float* we2e, float* bvo){
  int w = blockIdx.x * 4 + (threadIdx.x >> 6);
  int lane = threadIdx.x & 63;

  if (w < 930){
    int k = w / 10, h = w % 10;
    const float* wr = W1 + (size_t)k * 5120 + h * 512;
    float ss = warp_sum(dot512(wr, as1 + h * 512, lane));
    float sd = warp_sum(dot512(wr, ad1 + h * 512, lane));
    if (lane == 0){ wse1[w] = ss; wsd1[w] = sd; }
  } else if (w < 1040){
    int u = w - 930;
    int k = u / 10, h = u % 10;
    const float* wr = We1 + (size_t)k * 5120 + h * 512;
    float se = warp_sum(dot512(wr, ae1 + h * 512, lane));
    if (lane == 0) wee1[u] = se;
  } else if (w < 6160){
    int t = w - 1040;
    const float* wr = W2 + (size_t)t * 512;
    float ss = warp_sum(dot512(wr, as2, lane));
    float sd = warp_sum(dot512(wr, ad2, lane));
    if (lane == 0){ w2s[t] = ss; w2d[t] = sd; }
  } else if (w < 6171){
    int k = w - 6160;
    float se = warp_sum(dot512(We2 + (size_t)k * 512, ae2, lane));
    if (lane == 0) we2e[k] = se;
  } else if (w < 6299){
    int idx = w - 6171;           // i(2) x cblock(8) x kchunk(8)
    int i = idx >> 6;
    int cblk = (idx >> 3) & 7;
    int kch = idx & 7;
    int c = cblk * 64 + lane;
    const float* ib = in_b + i * 1536 + 1024;
    const float* ow = out_w + (size_t)i * 262144;
    float acc = 0.f;
    int k0 = kch * 64;
#pragma unroll 8
    for (int k = k0; k < k0 + 64; k++) acc += ib[k] * ow[(size_t)k * 512 + c];
    if (kch == 0) acc += out_b[i * 512 + c] ;
    atomicAdd(&bvo[i * 512 + c], acc);
  }
}

__global__ void k_logits1(const float* __restrict__ x1, const float* __restrict__ wse1,
                          const float* __restrict__ wsd1, float* S1, float* D1){
  int t = blockIdx.x * 256 + threadIdx.x;
  int n = t / 10, h = t % 10;
  const float* xr = x1 + (size_t)n * 93;
  float s = 0, d = 0;
  for (int k = 0; k < 93; k++){ float x = xr[k]; s += x * wse1[k * 10 + h]; d += x * wsd1[k * 10 + h]; }
  S1[t] = s; D1[t] = d;
}

// ---------------- weight prep ----------------

// dst[n][k(dK)] = bf16(src[k][n]) for k<K (0 for K<=k<dK); src [K][N] f32
__global__ void k_t2b(const float* __restrict__ src, bf16* __restrict__ dst,
                      int K, int N, int dK, long sZ, long dZ){
  __shared__ float t[32][33];
  src += (size_t)blockIdx.z * sZ;
  dst += (size_t)blockIdx.z * dZ;
  int k0 = blockIdx.y * 32, n0 = blockIdx.x * 32;
  int x = threadIdx.x, y = threadIdx.y;   // 32 x 8
#pragma unroll
  for (int yy = y; yy < 32; yy += 8){
    int k = k0 + yy, n = n0 + x;
    t[yy][x] = (k < K && n < N) ? src[(size_t)k * N + n] : 0.f;
  }
  __syncthreads();
#pragma unroll
  for (int yy = y; yy < 32; yy += 8){
    int n = n0 + yy, k = k0 + x;
    if (n < N && k < dK) dst[(size_t)n * dK + k] = __float2bfloat16(t[x][yy]);
  }
}

// Wvb[i][k][j] = bf16(in_w[i][k][1024+j])   (512x512 slice, row-major)
__global__ void k_prep_wv(const float* __restrict__ in_w, bf16* __restrict__ Wvb){
  int t = blockIdx.x * 256 + threadIdx.x;   // < 2*512*512
  int i = t >> 18, rem = t & 262143, k = rem >> 9, j = rem & 511;
  Wvb[t] = __float2bfloat16(in_w[(size_t)i * 786432 + (size_t)k * 1536 + 1024 + j]);
}

// ---------------- GAT layer 1: one wave per node, all 10 heads ----------------

__global__ __launch_bounds__(256) void k_gat1(
    const int* __restrict__ offsets, const int* __restrict__ csr_src,
    const int* __restrict__ csr_eid, const float* __restrict__ eattr,
    const float* __restrict__ lattr, const float* __restrict__ S1,
    const float* __restrict__ D1, const float* __restrict__ wee1,
    const float* __restrict__ x1, bf16* __restrict__ xaggp){
  int n = (blockIdx.x * 256 + threadIdx.x) >> 6;
  int lane = threadIdx.x & 63;
  int start = offsets[n], end = offsets[n + 1];
  int deg = end - start;

  if (deg <= 64){
    bool act = lane < deg;
    int s = 0, eid = 0;
    float ea[11];
#pragma unroll
    for (int j = 0; j < 11; j++) ea[j] = 0.f;
    if (act){
      s = csr_src[start + lane];
      eid = csr_eid[start + lane];
      const float* eap = (eid < EE) ? eattr + (size_t)eid * 11
                                    : lattr + (size_t)(eid - EE) * 11;
#pragma unroll
      for (int j = 0; j < 11; j++) ea[j] = eap[j];
    }
    float alpha[10];
#pragma unroll
    for (int h = 0; h < 10; h++){
      float eel = 0;
#pragma unroll
      for (int j = 0; j < 11; j++) eel += ea[j] * wee1[j * 10 + h];
      float lg = -1e30f;
      if (act){
        lg = S1[s * 10 + h] + D1[n * 10 + h] + eel;
        lg = lg > 0.f ? lg : 0.2f * lg;
      }
      float m = warp_max(lg);
      float pv = act ? __expf(lg - m) : 0.f;
      float sum = warp_sum(pv);
      alpha[h] = pv / sum;
    }
    float acc0[10], acc1[10];
#pragma unroll
    for (int h = 0; h < 10; h++){ acc0[h] = 0.f; acc1[h] = 0.f; }
    for (int e = 0; e < deg; e++){
      int se = __shfl(s, e);
      const float* xr = x1 + (size_t)se * 93;
      float xv0 = xr[lane];
      float xv1 = (lane < 29) ? xr[64 + lane] : 0.f;
#pragma unroll
      for (int h = 0; h < 10; h++){
        float al = __shfl(alpha[h], e);
        acc0[h] += al * xv0;
        acc1[h] += al * xv1;
      }
    }
#pragma unroll
    for (int h = 0; h < 10; h++){
      bf16* o = xaggp + (size_t)(n * 10 + h) * 96;
      o[lane] = __float2bfloat16(acc0[h]);
      if (lane < 29) o[64 + lane] = __float2bfloat16(acc1[h]);
      else if (lane < 32) o[64 + lane] = __float2bfloat16(0.f);
    }
  } else {
    // general fallback (3-pass per head)
    for (int h = 0; h < 10; h++){
      float dl = D1[n * 10 + h];
      float wl[11];
#pragma unroll
      for (int j = 0; j < 11; j++) wl[j] = wee1[j * 10 + h];
      float m = -1e30f;
      for (int pos = start + lane; pos < end; pos += 64){
        int s = csr_src[pos]; int eid = csr_eid[pos];
        const float* ea = (eid < EE) ? eattr + (size_t)eid * 11 : lattr + (size_t)(eid - EE) * 11;
        float eel = 0;
#pragma unroll
        for (int j = 0; j < 11; j++) eel += ea[j] * wl[j];
        float lg = S1[s * 10 + h] + dl + eel;
        lg = lg > 0.f ? lg : 0.2f * lg;
        m = fmaxf(m, lg);
      }
      m = warp_max(m);
      float ps = 0;
      for (int pos = start + lane; pos < end; pos += 64){
        int s = csr_src[pos]; int eid = csr_eid[pos];
        const float* ea = (eid < EE) ? eattr + (size_t)eid * 11 : lattr + (size_t)(eid - EE) * 11;
        float eel = 0;
#pragma unroll
        for (int j = 0; j < 11; j++) eel += ea[j] * wl[j];
        float lg = S1[s * 10 + h] + dl + eel;
        lg = lg > 0.f ? lg : 0.2f * lg;
        ps += __expf(lg - m);
      }
      ps = warp_sum(ps);
      float inv = 1.0f / ps;
      float acc0 = 0, acc1 = 0;
      for (int pos = start; pos < end; pos++){
        int s = csr_src[pos]; int eid = csr_eid[pos];
        const float* ea = (eid < EE) ? eattr + (size_t)eid * 11 : lattr + (size_t)(eid - EE) * 11;
        float eel = 0;
#pragma unroll
        for (int j = 0; j < 11; j++) eel += ea[j] * wl[j];
        float lg = S1[s * 10 + h] + dl + eel;
        lg = lg > 0.f ? lg : 0.2f * lg;
        float alpha = __expf(lg - m) * inv;
        const float* xr = x1 + (size_t)s * 93;
        acc0 += alpha * xr[lane];
        if (lane < 29) acc1 += alpha * xr[64 + lane];
      }
      bf16* o = xaggp + (size_t)(n * 10 + h) * 96;
      o[lane] = __float2bfloat16(acc0);
      if (lane < 29) o[64 + lane] = __float2bfloat16(acc1);
      else if (lane < 32) o[64 + lane] = __float2bfloat16(0.f);
    }
  }
}

// ---------------- GAT layer 2: one wave per node, lane-parallel softmax ----------------

__global__ __launch_bounds__(256) void k_gat2(
    const int* __restrict__ offsets, const int* __restrict__ csr_src,
    const int* __restrict__ csr_eid, const float* __restrict__ eattr,
    const float* __restrict__ lattr, const float* __restrict__ s2,
    const float* __restrict__ d2, const float* __restrict__ we2e,
    const bf16* __restrict__ xs2, const float* __restrict__ b2,
    float* __restrict__ h2f, bf16* __restrict__ hbf, float* __restrict__ alpha_out){
  int n = (blockIdx.x * 256 + threadIdx.x) >> 6;
  int lane = threadIdx.x & 63;
  int start = offsets[n], end = offsets[n + 1];
  int deg = end - start;
  float dl = d2[n];

  float acc[8] = {0, 0, 0, 0, 0, 0, 0, 0};

  if (deg <= 64){
    bool act = lane < deg;
    int s = 0, eid = 0;
    float eel = 0.f;
    if (act){
      s = csr_src[start + lane];
      eid = csr_eid[start + lane];
      const float* eap = (eid < EE) ? eattr + (size_t)eid * 11
                                    : lattr + (size_t)(eid - EE) * 11;
#pragma unroll
      for (int j = 0; j < 11; j++) eel += eap[j] * we2e[j];
    }
    float lg = -1e30f;
    if (act){
      lg = s2[s] + dl + eel;
      lg = lg > 0.f ? lg : 0.2f * lg;
    }
    float m = warp_max(lg);
    float pv = act ? __expf(lg - m) : 0.f;
    float sum = warp_sum(pv);
    float alpha = pv / sum;
    if (act) alpha_out[eid] = alpha;

    for (int e = 0; e < deg; e++){
      int se = __shfl(s, e);
      float al = __shfl(alpha, e);
      union { uint4 u; unsigned short sh[8]; } xv;
      xv.u = *(const uint4*)&xs2[(size_t)se * 512 + lane * 8];
#pragma unroll
      for (int jj = 0; jj < 8; jj++) acc[jj] += al * bf2f(xv.sh[jj]);
    }
  } else {
    // general fallback (3-pass)
    float wl[11];
#pragma unroll
    for (int j = 0; j < 11; j++) wl[j] = we2e[j];
    float m = -1e30f;
    for (int pos = start + lane; pos < end; pos += 64){
      int s = csr_src[pos]; int eid = csr_eid[pos];
      const float* ea = (eid < EE) ? eattr + (size_t)eid * 11 : lattr + (size_t)(eid - EE) * 11;
      float eel = 0;
#pragma unroll
      for (int j = 0; j < 11; j++) eel += ea[j] * wl[j];
      float lg = s2[s] + dl + eel;
      lg = lg > 0.f ? lg : 0.2f * lg;
      m = fmaxf(m, lg);
    }
    m = warp_max(m);
    float ps = 0;
    for (int pos = start + lane; pos < end; pos += 64){
      int s = csr_src[pos]; int eid = csr_eid[pos];
      const float* ea = (eid < EE) ? eattr + (size_t)eid * 11 : lattr + (size_t)(eid - EE) * 11;
      float eel = 0;
#pragma unroll
      for (int j = 0; j < 11; j++) eel += ea[j] * wl[j];
      float lg = s2[s] + dl + eel;
      lg = lg > 0.f ? lg : 0.2f * lg;
      ps += __expf(lg - m);
    }
    ps = warp_sum(ps);
    float inv = 1.0f / ps;
    for (int pos = start; pos < end; pos++){
      int s = csr_src[pos]; int eid = csr_eid[pos];
      const float* ea = (eid < EE) ? eattr + (size_t)eid * 11 : lattr + (size_t)(eid - EE) * 11;
      float eel = 0;
#pragma unroll
      for (int j = 0; j < 11; j++) eel += ea[j] * wl[j];
      float lg = s2[s] + dl + eel;
      lg = lg > 0.f ? lg : 0.2f * lg;
      float alpha = __expf(lg - m) * inv;
      if (lane == 0) alpha_out[eid] = alpha;
      union { uint4 u; unsigned short sh[8]; } xv;
      xv.u = *(const uint4*)&xs2[(size_t)s * 512 + lane * 8];
#pragma unroll
      for (int jj = 0; jj < 8; jj++) acc[jj] += alpha * bf2f(xv.sh[jj]);
    }
  }

#pragma unroll
  for (int jj = 0; jj < 8; jj++){
    int c = lane * 8 + jj;
    float v = acc[jj] + b2[c];
    v = v > 0.f ? v : (__expf(v) - 1.f);
    h2f[(size_t)n * 512 + c] = v;
    hbf[(size_t)n * 512 + c] = __float2bfloat16(v);
  }
}

// ---------------- MFMA bf16 GEMM: C = act(A @ Bt^T + bias + res) ----------------
// A [M,K+] bf16 (row stride lda), Bt [N,K+] bf16 (row stride ldb), C [M,ldc].
// K%32==0. z-dim: aZ/bZ shift A/Bt (batching AND split-K), cZ shifts C.
// Double-buffered LDS, one barrier per K-step. LDS XOR swizzle (both-sides:
// pre-swizzled global source col + swizzled ds_read col). Bijective XCD
// swizzle over 2D grid (gridDim.x*gridDim.y % 8 == 0).
// LOG: epilogue also atomically accumulates s2 += C·w2s, d2 += C·w2d per row.

__device__ __forceinline__ void stC_elem(float* p, float v){ *p = v; }
__device__ __forceinline__ void stC_elem(bf16* p, float v){ *p = __float2bfloat16(v); }

template <int BMF, int BNF, int ACT, bool BIAS, bool RES, bool LOG, typename TC>
__global__ __launch_bounds__(256) void k_mm(
    const bf16* __restrict__ A, const bf16* __restrict__ Bt,
    const float* __restrict__ bias, const float* __restrict__ res,
    TC* __restrict__ C, int M, int K, int lda, int ldb, int ldc,
    long aZ, long bZ, long cZ, long biasZ,
    const float* __restrict__ w2s, const float* __restrict__ w2d,
    float* __restrict__ s2, float* __restrict__ d2){
  constexpr int BM = BMF * 32, BN = BNF * 32;
  __shared__ __align__(16) bf16 As[2][BM * 32];
  __shared__ __align__(16) bf16 Bs[2][BN * 32];
  const int tid = threadIdx.x, wave = tid >> 6, lane = tid & 63;

  const int nwg = gridDim.x * gridDim.y;
  const int id = blockIdx.y * gridDim.x + blockIdx.x;
  const int cpx = nwg >> 3;
  const int swz = (id & 7) * cpx + (id >> 3);
  const int bm = (swz / gridDim.x) * BM, bn = (swz % gridDim.x) * BN;

  const int z = blockIdx.z;
  A  += (size_t)z * aZ;
  Bt += (size_t)z * bZ;
  C  += (size_t)z * cZ;
  const float* bp = BIAS ? bias + (size_t)z * biasZ : nullptr;

  const int trow = tid >> 2;
  const int stk = ((tid & 3) * 8) ^ ((trow & 3) << 3);   // pre-swizzled source col
  const int wr = (wave >> 1) * (BMF * 16), wc = (wave & 1) * (BNF * 16);
  const int r = lane & 15, kq = lane >> 4;
  const int swcol = ((kq ^ (r & 3)) << 3);               // swizzled ds_read col

  fv4 acc[BMF][BNF] = {};

  auto STAGE = [&](int buf, int k0){
#pragma unroll
    for (int s = 0; s < BM / 64; s++)
      gl_lds16(A + (size_t)(bm + s * 64 + trow) * lda + k0 + stk,
               (char*)&As[buf][0] + s * 4096 + wave * 1024, lane);
#pragma unroll
    for (int s = 0; s < BN / 64; s++)
      gl_lds16(Bt + (size_t)(bn + s * 64 + trow) * ldb + k0 + stk,
               (char*)&Bs[buf][0] + s * 4096 + wave * 1024, lane);
  };

  STAGE(0, 0);
  int cur = 0;
  for (int k0 = 0; k0 < K; k0 += 32){
    __syncthreads();
    if (k0 + 32 < K) STAGE(cur ^ 1, k0 + 32);

    bfv8 a[BMF], b[BNF];
#pragma unroll
    for (int i = 0; i < BMF; i++)
      a[i] = *(const bfv8*)&As[cur][(wr + i * 16 + r) * 32 + swcol];
#pragma unroll
    for (int j = 0; j < BNF; j++)
      b[j] = *(const bfv8*)&Bs[cur][(wc + j * 16 + r) * 32 + swcol];
#pragma unroll
    for (int i = 0; i < BMF; i++)
#pragma unroll
      for (int j = 0; j < BNF; j++)
        acc[i][j] = __builtin_amdgcn_mfma_f32_16x16x32_bf16(a[i], b[j], acc[i][j], 0, 0, 0);
    cur ^= 1;
  }

  const int rb = bm + wr + (lane >> 4) * 4;
  const int cb = bn + wc + (lane & 15);
  float ls[BMF][4], ld[BMF][4];
  if (LOG){
#pragma unroll
    for (int i = 0; i < BMF; i++)
#pragma unroll
      for (int q = 0; q < 4; q++){ ls[i][q] = 0.f; ld[i][q] = 0.f; }
  }
  const float* wsp = LOG ? w2s + (size_t)z * biasZ : nullptr;
  const float* wdp = LOG ? w2d + (size_t)z * biasZ : nullptr;

#pragma unroll
  for (int i = 0; i < BMF; i++)
#pragma unroll
    for (int j = 0; j < BNF; j++){
      int gn = cb + j * 16;
      float bv = BIAS ? bp[gn] : 0.f;
#pragma unroll
      for (int q = 0; q < 4; q++){
        int gm = rb + i * 16 + q;
        float v = acc[i][j][q] + bv;
        if (RES) v += res[(size_t)gm * ldc + gn];
        if (ACT == 1) v = fmaxf(v, 0.f);
        if (ACT == 2) v = v > 0.f ? v : (__expf(v) - 1.f);
        if (LOG){ ls[i][q] += v * wsp[gn]; ld[i][q] += v * wdp[gn]; }
        stC_elem(&C[(size_t)gm * ldc + gn], v);
      }
    }

  if (LOG){
#pragma unroll
    for (int i = 0; i < BMF; i++)
#pragma unroll
      for (int q = 0; q < 4; q++){
        float a = ls[i][q], b = ld[i][q];
#pragma unroll
        for (int o = 1; o < 16; o <<= 1){ a += __shfl_xor(a, o); b += __shfl_xor(b, o); }
        if ((lane & 15) == 0){
          int gm = rb + i * 16 + q;
          atomicAdd(&s2[gm], a);
          atomicAdd(&d2[gm], b);
        }
      }
  }
}

// ---------------- split-K reduces ----------------

__global__ void k_red2bf(const float* __restrict__ pA, const float* __restrict__ pB,
                         bf16* __restrict__ out){
  int t = (blockIdx.x * 256 + threadIdx.x) * 4;
  float4 a = *(const float4*)&pA[t];
  float4 b = *(const float4*)&pB[t];
  out[t]     = __float2bfloat16(a.x + b.x);
  out[t + 1] = __float2bfloat16(a.y + b.y);
  out[t + 2] = __float2bfloat16(a.z + b.z);
  out[t + 3] = __float2bfloat16(a.w + b.w);
}

__global__ void k_red4bf(const float* __restrict__ p, long st, bf16* __restrict__ out){
  int t = (blockIdx.x * 256 + threadIdx.x) * 4;
  float4 a = *(const float4*)&p[t];
  float4 b = *(const float4*)&p[st + t];
  float4 c = *(const float4*)&p[2 * st + t];
  float4 d = *(const float4*)&p[3 * st + t];
  out[t]     = __float2bfloat16(a.x + b.x + c.x + d.x);
  out[t + 1] = __float2bfloat16(a.y + b.y + c.y + d.y);
  out[t + 2] = __float2bfloat16(a.z + b.z + c.z + d.z);
  out[t + 3] = __float2bfloat16(a.w + b.w + c.w + d.w);
}

// ---------------- layernorm variants, pool ----------------

__device__ __forceinline__ void ln_body(float v[8], int lane,
                                        const float* g, const float* b,
                                        float* yf, bf16* ybf, size_t row){
  float s = 0;
#pragma unroll
  for (int j = 0; j < 8; j++) s += v[j];
  s = warp_sum(s);
  float mu = s * (1.0f / 512.0f);
  float var = 0;
#pragma unroll
  for (int j = 0; j < 8; j++){ float d = v[j] - mu; var += d * d; }
  var = warp_sum(var) * (1.0f / 512.0f);
  float inv = rsqrtf(var + 1e-5f);
#pragma unroll
  for (int j = 0; j < 8; j++){
    int c = lane + j * 64;
    float o = (v[j] - mu) * inv * g[c] + b[c];
    yf[row * 512 + c] = o;
    ybf[row * 512 + c] = __float2bfloat16(o);
  }
}

__global__ __launch_bounds__(256) void k_ln(const float* __restrict__ x,
                                            const float* __restrict__ g,
                                            const float* __restrict__ b,
                                            float* __restrict__ yf,
                                            bf16* __restrict__ ybf){
  int wid = (blockIdx.x * 256 + threadIdx.x) >> 6;
  int lane = threadIdx.x & 63;
  const float* xr = x + (size_t)wid * 512;
  float v[8];
#pragma unroll
  for (int j = 0; j < 8; j++) v[j] = xr[lane + j * 64];
  ln_body(v, lane, g, b, yf, ybf, (size_t)wid);
}

// fused split-K reduce + bias + residual + LN
__global__ __launch_bounds__(256) void k_ln_fr(const float* __restrict__ pA,
                                               const float* __restrict__ pB,
                                               const float* __restrict__ bias,
                                               const float* __restrict__ res,
                                               const float* __restrict__ g,
                                               const float* __restrict__ b,
                                               float* __restrict__ yf,
                                               bf16* __restrict__ ybf){
  int wid = (blockIdx.x * 256 + threadIdx.x) >> 6;
  int lane = threadIdx.x & 63;
  size_t base = (size_t)wid * 512;
  float v[8];
#pragma unroll
  for (int j = 0; j < 8; j++){
    int c = lane + j * 64;
    v[j] = pA[base + c] + pB[base + c] + bias[c] + res[base + c];
  }
  ln_body(v, lane, g, b, yf, ybf, (size_t)wid);
}

__global__ void k_pool(const float* __restrict__ h, float* __restrict__ out){
  int b = blockIdx.x;
  int c = threadIdx.x;   // 512 threads
  const float* hr = h + (size_t)b * 64 * 512;
  float m = -1e30f;
  for (int i = 0; i < 64; i++) m = fmaxf(m, hr[i * 512 + c]);
  out[(size_t)b * 512 + c] = m;
}

// ---------------- launcher ----------------

extern "C" void kernel_launch(void* const* d_in, const int* in_sizes, int n_in,
                              void* d_out, int out_size, void* d_ws, size_t ws_size,
                              hipStream_t stream){
  const float* x1    = (const float*)d_in[0];
  const int*   ei    = (const int*)d_in[1];
  const float* eattr = (const float*)d_in[2];
  const float* W1    = (const float*)d_in[4];
  const float* as1   = (const float*)d_in[5];
  const float* ad1   = (const float*)d_in[6];
  const float* We1   = (const float*)d_in[7];
  const float* ae1   = (const float*)d_in[8];
  const float* b1    = (const float*)d_in[9];
  const float* W2    = (const float*)d_in[10];
  const float* as2   = (const float*)d_in[11];
  const float* ad2   = (const float*)d_in[12];
  const float* We2   = (const float*)d_in[13];
  const float* ae2   = (const float*)d_in[14];
  const float* b2    = (const float*)d_in[15];
  const float* in_w  = (const float*)d_in[16];
  const float* in_b  = (const float*)d_in[17];
  const float* out_w = (const float*)d_in[18];
  const float* out_b = (const float*)d_in[19];
  const float* ln1g  = (const float*)d_in[20];
  const float* ln1b  = (const float*)d_in[21];
  const float* f1w   = (const float*)d_in[22];
  const float* f1b   = (const float*)d_in[23];
  const float* f2w   = (const float*)d_in[24];
  const float* f2b   = (const float*)d_in[25];
  const float* ln2g  = (const float*)d_in[26];
  const float* ln2b  = (const float*)d_in[27];

  const int* src0 = ei;
  const int* dst0 = ei + EE;

  char* p = (char*)d_ws;
  auto alloc = [&](size_t bytes) -> void* {
    void* r = p;
    p += (bytes + 255) & ~(size_t)255;
    return r;
  };
  // contiguous zero-init region: deg, cursor, s2, d2v, bvo, esum  (one memset)
  int*   deg     = (int*)alloc(NN * 4);
  int*   cursor  = (int*)alloc(NN * 4);
  float* s2      = (float*)alloc(NN * 4);
  float* d2v     = (float*)alloc(NN * 4);
  float* bvo     = (float*)alloc(2 * 512 * 4);
  float* esum    = (float*)alloc(NN * 11 * 4);
  size_t zbytes  = (char*)p - (char*)deg;

  float* lattr   = (float*)alloc(NN * 11 * 4);
  int*   offsets = (int*)alloc((NN + 1) * 4);
  int*   csr_src = (int*)alloc(ET * 4);
  int*   csr_eid = (int*)alloc(ET * 4);
  float* wse1    = (float*)alloc(930 * 4);
  float* wsd1    = (float*)alloc(930 * 4);
  float* wee1    = (float*)alloc(110 * 4);
  float* S1      = (float*)alloc(NN * 10 * 4);
  float* D1b     = (float*)alloc(NN * 10 * 4);
  bf16*  xaggp   = (bf16*)alloc((size_t)NN * 10 * 96 * 2);
  bf16*  W1t     = (bf16*)alloc((size_t)5120 * 96 * 2);
  bf16*  W2t     = (bf16*)alloc((size_t)512 * 5120 * 2);
  bf16*  f1wt    = (bf16*)alloc((size_t)2 * 2048 * 512 * 2);
  bf16*  f2wt    = (bf16*)alloc((size_t)2 * 512 * 2048 * 2);
  bf16*  Wvb     = (bf16*)alloc((size_t)2 * 512 * 512 * 2);
  bf16*  WoT     = (bf16*)alloc((size_t)2 * 512 * 512 * 2);
  bf16*  Wvot    = (bf16*)alloc((size_t)2 * 512 * 512 * 2);
  bf16*  h1      = (bf16*)alloc((size_t)NN * 5120 * 2);   // dead after xs2; reused below
  float* w2s     = (float*)alloc(5120 * 4);
  float* w2d     = (float*)alloc(5120 * 4);
  float* we2e    = (float*)alloc(16 * 4);
  bf16*  xs2     = (bf16*)alloc((size_t)NN * 512 * 2);
  float* h2f     = (float*)alloc((size_t)NN * 512 * 4);
  bf16*  hbf     = (bf16*)alloc((size_t)NN * 512 * 2);
  float* pbuf    = (float*)alloc((size_t)NN * 512 * 4 * 2);   // 2 split-K partials (always)
  long   pdz     = (long)NN * 512;
  // optional 2 more partials for split-K=4, if workspace allows
  size_t used2   = (char*)p - (char*)d_ws;
  bool   sk4     = (used2 + 2 * (size_t)NN * 512 * 4 + 256 <= ws_size);
  float* pbufHi  = sk4 ? (float*)alloc((size_t)NN * 512 * 4 * 2) : nullptr;
  (void)pbufHi;
  // aliases into dead h1 region (40 MB): tmp (8 MB) + fbuf (16 MB)
  float* tmp  = (float*)h1;
  bf16*  fbuf = (bf16*)((char*)h1 + (size_t)NN * 512 * 4);

  float* out_pool = (float*)d_out;
  float* alpha2   = out_pool + 64 * 512;

  hipMemsetAsync(deg, 0, zbytes, stream);

  // graph prep + folds (wave-parallel)
  k_deg_esum<<<EE / 256, 256, 0, stream>>>(dst0, eattr, deg, esum);
  k_loop_attr<<<NN / 256, 256, 0, stream>>>(esum, deg, lattr);
  k_scan<<<1, 256, 0, stream>>>(deg, offsets);
  k_scatter<<<(EE + NN) / 256, 256, 0, stream>>>(src0, dst0, offsets, cursor, csr_src, csr_eid);
  k_foldsw<<<1575, 256, 0, stream>>>(W1, as1, ad1, We1, ae1, W2, as2, ad2, We2, ae2,
                                     in_b, out_w, out_b,
                                     wse1, wsd1, wee1, w2s, w2d, we2e, bvo);
  k_logits1<<<160, 256, 0, stream>>>(x1, wse1, wsd1, S1, D1b);

  // weight preps
  k_t2b<<<dim3(160, 3, 1), dim3(32, 8), 0, stream>>>(W1, W1t, 93, 5120, 96, 0, 0);
  k_t2b<<<dim3(16, 160, 1), dim3(32, 8), 0, stream>>>(W2, W2t, 5120, 512, 5120, 0, 0);
  k_t2b<<<dim3(64, 16, 2), dim3(32, 8), 0, stream>>>(f1w, f1wt, 512, 2048, 512,
                                                     512L * 2048, 2048L * 512);
  k_t2b<<<dim3(16, 64, 2), dim3(32, 8), 0, stream>>>(f2w, f2wt, 2048, 512, 2048,
                                                     2048L * 512, 512L * 2048);
  k_prep_wv<<<2048, 256, 0, stream>>>(in_w, Wvb);
  k_t2b<<<dim3(16, 16, 2), dim3(32, 8), 0, stream>>>(out_w, WoT, 512, 512, 512,
                                                     262144, 262144);
  // Wvot[n][k] = sum_j WoT[n][j] * Wvb[k][j]  (= (Wv@Wo)^T, bf16)
  k_mm<4, 4, 0, false, false, false, bf16><<<dim3(4, 4, 2), 256, 0, stream>>>(
      WoT, Wvb, nullptr, nullptr, Wvot, 512, 512, 512, 512, 512,
      262144, 262144, 262144, 0, nullptr, nullptr, nullptr, nullptr);

  // GAT-1 aggregate, then per-head MFMA projection with fused logits2 epilogue
  k_gat1<<<NN / 4, 256, 0, stream>>>(offsets, csr_src, csr_eid, eattr, lattr,
                                     S1, D1b, wee1, x1, xaggp);
  // h1 = elu(xagg @ W1 + b1); epilogue: s2 += h1·w2s, d2v += h1·w2d
  k_mm<4, 4, 2, true, false, true, bf16><<<dim3(4, 32, 10), 256, 0, stream>>>(
      xaggp, W1t, b1, nullptr, h1, NN, 96, 960, 96, 5120, 96, 512L * 96, 512, 512,
      w2s, w2d, s2, d2v);

  // xs2 = h1 @ W2, split-K (4 if ws allows, else 2)
  if (sk4){
    k_mm<2, 4, 0, false, false, false, float><<<dim3(4, 64, 4), 256, 0, stream>>>(
        h1, W2t, nullptr, nullptr, pbuf, NN, 1280, 5120, 5120, 512,
        1280, 1280, pdz, 0, nullptr, nullptr, nullptr, nullptr);
    k_red4bf<<<2048, 256, 0, stream>>>(pbuf, pdz, xs2);
  } else {
    k_mm<2, 4, 0, false, false, false, float><<<dim3(4, 64, 2), 256, 0, stream>>>(
        h1, W2t, nullptr, nullptr, pbuf, NN, 2560, 5120, 5120, 512,
        2560, 2560, pdz, 0, nullptr, nullptr, nullptr, nullptr);
    k_red2bf<<<2048, 256, 0, stream>>>(pbuf, pbuf + pdz, xs2);
  }
  k_gat2<<<NN / 4, 256, 0, stream>>>(offsets, csr_src, csr_eid, eattr, lattr,
                                     s2, d2v, we2e, xs2, b2, h2f, hbf, alpha2);

  for (int i = 0; i < 2; i++){
    // tmp = h2 + h2 @ Wvo + bvo   (BN=64 tiles: 512 blocks = 2/CU)
    k_mm<2, 2, 0, true, true, false, float><<<dim3(8, 64, 1), 256, 0, stream>>>(
        hbf, Wvot + (size_t)i * 262144, bvo + i * 512, h2f, tmp,
        NN, 512, 512, 512, 512, 0, 0, 0, 0, nullptr, nullptr, nullptr, nullptr);
    k_ln<<<NN / 4, 256, 0, stream>>>(tmp, ln1g + i * 512, ln1b + i * 512, h2f, hbf);
    // fbuf = relu(h @ f1w + f1b): N=2048, K=512
    k_mm<4, 4, 1, true, false, false, bf16><<<dim3(16, 32, 1), 256, 0, stream>>>(
        hbf, f1wt + (size_t)i * 2048 * 512, f1b + i * 2048, nullptr, fbuf,
        NN, 512, 512, 512, 2048, 0, 0, 0, 0, nullptr, nullptr, nullptr, nullptr);
    // FFN2 split-K=2: partials (K-window 1024 each), reduce fused into LN
    k_mm<2, 4, 0, false, false, false, float><<<dim3(4, 64, 2), 256, 0, stream>>>(
        fbuf, f2wt + (size_t)i * 512 * 2048, nullptr, nullptr, pbuf,
        NN, 1024, 2048, 2048, 512, 1024, 1024, pdz, 0,
        nullptr, nullptr, nullptr, nullptr);
    k_ln_fr<<<NN / 4, 256, 0, stream>>>(pbuf, pbuf + pdz, f2b + i * 512, h2f,
                                        ln2g + i * 512, ln2b + i * 512, h2f, hbf);
  }

  k_pool<<<64, 512, 0, stream>>>(h2f, out_pool);
}

// Round 10
// 451.326 us; speedup vs baseline: 5.6539x; 1.0055x over previous
//
#include <hip/hip_runtime.h>
#include <hip/hip_bf16.h>

#define NN 4096
#define EE 16384
#define ET 20480   // EE + NN

typedef __hip_bfloat16 bf16;
typedef __bf16 bfv8 __attribute__((ext_vector_type(8)));
typedef float fv4 __attribute__((ext_vector_type(4)));

__device__ __forceinline__ float warp_max(float v){
#pragma unroll
  for (int o = 32; o; o >>= 1) v = fmaxf(v, __shfl_xor(v, o));
  return v;
}
__device__ __forceinline__ float warp_sum(float v){
#pragma unroll
  for (int o = 32; o; o >>= 1) v += __shfl_xor(v, o);
  return v;
}
__device__ __forceinline__ float bf2f(unsigned short u){
  return __uint_as_float((unsigned)u << 16);
}

// async global->LDS, 16B per lane. lbase = wave-uniform LDS base (lane*16 added by HW).
__device__ __forceinline__ void gl_lds16(const void* g, void* lbase, int lane){
#if __has_builtin(__builtin_amdgcn_global_load_lds)
  __builtin_amdgcn_global_load_lds(
      (const __attribute__((address_space(1))) unsigned int*)g,
      (__attribute__((address_space(3))) unsigned int*)lbase, 16, 0, 0);
#else
  *(uint4*)((char*)lbase + lane * 16) = *(const uint4*)g;
#endif
}

// ---------------- graph preprocessing ----------------

__global__ void k_deg_esum(const int* __restrict__ dst0, const float* __restrict__ eattr,
                           int* deg, float* esum){
  int e = blockIdx.x * 256 + threadIdx.x;
  if (e >= EE) return;
  int d = dst0[e];
  atomicAdd(&deg[d], 1);
  const float* ar = eattr + (size_t)e * 11;
  float* er = esum + (size_t)d * 11;
#pragma unroll
  for (int j = 0; j < 11; j++) atomicAdd(&er[j], ar[j]);
}

__global__ void k_loop_attr(const float* __restrict__ esum, const int* __restrict__ deg,
                            float* lattr){
  int n = blockIdx.x * 256 + threadIdx.x;
  if (n >= NN) return;
  float c = fmaxf((float)deg[n], 1.0f);
#pragma unroll
  for (int j = 0; j < 11; j++) lattr[n * 11 + j] = esum[n * 11 + j] / c;
}

__global__ void k_scan(const int* __restrict__ deg, int* offsets){
  __shared__ int sums[256];
  int t = threadIdx.x;
  int base = t * 16;
  int vals[16];
  int s = 0;
#pragma unroll
  for (int j = 0; j < 16; j++){ vals[j] = s; s += deg[base + j] + 1; }
  sums[t] = s;
  __syncthreads();
  for (int off = 1; off < 256; off <<= 1){
    int v = (t >= off) ? sums[t - off] : 0;
    __syncthreads();
    sums[t] += v;
    __syncthreads();
  }
  int pre = (t == 0) ? 0 : sums[t - 1];
#pragma unroll
  for (int j = 0; j < 16; j++) offsets[base + j] = pre + vals[j];
  if (t == 255) offsets[NN] = sums[255];
}

__global__ void k_scatter(const int* __restrict__ src0, const int* __restrict__ dst0,
                          const int* __restrict__ offsets, int* cursor,
                          int* csr_src, int* csr_eid){
  int t = blockIdx.x * 256 + threadIdx.x;
  if (t < EE){
    int d = dst0[t];
    int pos = offsets[d] + atomicAdd(&cursor[d], 1);
    csr_src[pos] = src0[t];
    csr_eid[pos] = t;
  } else if (t < EE + NN){
    int n = t - EE;
    int pos = offsets[n + 1] - 1;
    csr_src[pos] = n;
    csr_eid[pos] = EE + n;
  }
}

// ---------------- wave-parallel weight folds: one wave per dot product ----------------

__device__ __forceinline__ float dot512(const float* __restrict__ a,
                                        const float* __restrict__ b, int lane){
  float4 a0 = *(const float4*)&a[lane * 8];
  float4 a1 = *(const float4*)&a[lane * 8 + 4];
  float4 b0 = *(const float4*)&b[lane * 8];
  float4 b1 = *(const float4*)&b[lane * 8 + 4];
  return a0.x * b0.x + a0.y * b0.y + a0.z * b0.z + a0.w * b0.w
       + a1.x * b1.x + a1.y * b1.y + a1.z * b1.z + a1.w * b1.w;
}

__global__ __launch_bounds__(256) void k_foldsw(
    const float* __restrict__ W1, const float* __restrict__ as1,
    const float* __restrict__ ad1, const float* __restrict__ We1,
    const float* __restrict__ ae1,
    const float* __restrict__ W2, const float* __restrict__ as2,
    const float* __restrict__ ad2, const float* __restrict__ We2,
    const float* __restrict__ ae2,
    const float* __restrict__ in_b, const float* __restrict__ out_w,
    const float* __restrict__ out_b,
    float* wse1, float* wsd1, float* wee1,
    float* w2s, float* w2d, float* we2e, float* bvo){
  int w = blockIdx.x * 4 + (threadIdx.x >> 6);
  int lane = threadIdx.x & 63;

  if (w < 930){
    int k = w / 10, h = w % 10;
    const float* wr = W1 + (size_t)k * 5120 + h * 512;
    float ss = warp_sum(dot512(wr, as1 + h * 512, lane));
    float sd = warp_sum(dot512(wr, ad1 + h * 512, lane));
    if (lane == 0){ wse1[w] = ss; wsd1[w] = sd; }
  } else if (w < 1040){
    int u = w - 930;
    int k = u / 10, h = u % 10;
    const float* wr = We1 + (size_t)k * 5120 + h * 512;
    float se = warp_sum(dot512(wr, ae1 + h * 512, lane));
    if (lane == 0) wee1[u] = se;
  } else if (w < 6160){
    int t = w - 1040;
    const float* wr = W2 + (size_t)t * 512;
    float ss = warp_sum(dot512(wr, as2, lane));
    float sd = warp_sum(dot512(wr, ad2, lane));
    if (lane == 0){ w2s[t] = ss; w2d[t] = sd; }
  } else if (w < 6171){
    int k = w - 6160;
    float se = warp_sum(dot512(We2 + (size_t)k * 512, ae2, lane));
    if (lane == 0) we2e[k] = se;
  } else if (w < 6299){
    int idx = w - 6171;           // i(2) x cblock(8) x kchunk(8)
    int i = idx >> 6;
    int cblk = (idx >> 3) & 7;
    int kch = idx & 7;
    int c = cblk * 64 + lane;
    const float* ib = in_b + i * 1536 + 1024;
    const float* ow = out_w + (size_t)i * 262144;
    float acc = 0.f;
    int k0 = kch * 64;
#pragma unroll 8
    for (int k = k0; k < k0 + 64; k++) acc += ib[k] * ow[(size_t)k * 512 + c];
    if (kch == 0) acc += out_b[i * 512 + c];
    atomicAdd(&bvo[i * 512 + c], acc);
  }
}

__global__ void k_logits1(const float* __restrict__ x1, const float* __restrict__ wse1,
                          const float* __restrict__ wsd1, float* S1, float* D1){
  int t = blockIdx.x * 256 + threadIdx.x;
  int n = t / 10, h = t % 10;
  const float* xr = x1 + (size_t)n * 93;
  float s = 0, d = 0;
  for (int k = 0; k < 93; k++){ float x = xr[k]; s += x * wse1[k * 10 + h]; d += x * wsd1[k * 10 + h]; }
  S1[t] = s; D1[t] = d;
}

// ---------------- weight prep ----------------

// dst[n][k(dK)] = bf16(src[k][n]) for k<K (0 for K<=k<dK); src [K][N] f32
__global__ void k_t2b(const float* __restrict__ src, bf16* __restrict__ dst,
                      int K, int N, int dK, long sZ, long dZ){
  __shared__ float t[32][33];
  src += (size_t)blockIdx.z * sZ;
  dst += (size_t)blockIdx.z * dZ;
  int k0 = blockIdx.y * 32, n0 = blockIdx.x * 32;
  int x = threadIdx.x, y = threadIdx.y;   // 32 x 8
#pragma unroll
  for (int yy = y; yy < 32; yy += 8){
    int k = k0 + yy, n = n0 + x;
    t[yy][x] = (k < K && n < N) ? src[(size_t)k * N + n] : 0.f;
  }
  __syncthreads();
#pragma unroll
  for (int yy = y; yy < 32; yy += 8){
    int n = n0 + yy, k = k0 + x;
    if (n < N && k < dK) dst[(size_t)n * dK + k] = __float2bfloat16(t[x][yy]);
  }
}

// Wvb[i][k][j] = bf16(in_w[i][k][1024+j])   (512x512 slice, row-major)
__global__ void k_prep_wv(const float* __restrict__ in_w, bf16* __restrict__ Wvb){
  int t = blockIdx.x * 256 + threadIdx.x;   // < 2*512*512
  int i = t >> 18, rem = t & 262143, k = rem >> 9, j = rem & 511;
  Wvb[t] = __float2bfloat16(in_w[(size_t)i * 786432 + (size_t)k * 1536 + 1024 + j]);
}

// ---------------- GAT layer 1: one wave per node, all 10 heads ----------------

__global__ __launch_bounds__(256) void k_gat1(
    const int* __restrict__ offsets, const int* __restrict__ csr_src,
    const int* __restrict__ csr_eid, const float* __restrict__ eattr,
    const float* __restrict__ lattr, const float* __restrict__ S1,
    const float* __restrict__ D1, const float* __restrict__ wee1,
    const float* __restrict__ x1, bf16* __restrict__ xaggp){
  int n = (blockIdx.x * 256 + threadIdx.x) >> 6;
  int lane = threadIdx.x & 63;
  int start = offsets[n], end = offsets[n + 1];
  int deg = end - start;

  if (deg <= 64){
    bool act = lane < deg;
    int s = 0, eid = 0;
    float ea[11];
#pragma unroll
    for (int j = 0; j < 11; j++) ea[j] = 0.f;
    if (act){
      s = csr_src[start + lane];
      eid = csr_eid[start + lane];
      const float* eap = (eid < EE) ? eattr + (size_t)eid * 11
                                    : lattr + (size_t)(eid - EE) * 11;
#pragma unroll
      for (int j = 0; j < 11; j++) ea[j] = eap[j];
    }
    float alpha[10];
#pragma unroll
    for (int h = 0; h < 10; h++){
      float eel = 0;
#pragma unroll
      for (int j = 0; j < 11; j++) eel += ea[j] * wee1[j * 10 + h];
      float lg = -1e30f;
      if (act){
        lg = S1[s * 10 + h] + D1[n * 10 + h] + eel;
        lg = lg > 0.f ? lg : 0.2f * lg;
      }
      float m = warp_max(lg);
      float pv = act ? __expf(lg - m) : 0.f;
      float sum = warp_sum(pv);
      alpha[h] = pv / sum;
    }
    float acc0[10], acc1[10];
#pragma unroll
    for (int h = 0; h < 10; h++){ acc0[h] = 0.f; acc1[h] = 0.f; }
    for (int e = 0; e < deg; e++){
      int se = __shfl(s, e);
      const float* xr = x1 + (size_t)se * 93;
      float xv0 = xr[lane];
      float xv1 = (lane < 29) ? xr[64 + lane] : 0.f;
#pragma unroll
      for (int h = 0; h < 10; h++){
        float al = __shfl(alpha[h], e);
        acc0[h] += al * xv0;
        acc1[h] += al * xv1;
      }
    }
#pragma unroll
    for (int h = 0; h < 10; h++){
      bf16* o = xaggp + (size_t)(n * 10 + h) * 96;
      o[lane] = __float2bfloat16(acc0[h]);
      if (lane < 29) o[64 + lane] = __float2bfloat16(acc1[h]);
      else if (lane < 32) o[64 + lane] = __float2bfloat16(0.f);
    }
  } else {
    // general fallback (3-pass per head)
    for (int h = 0; h < 10; h++){
      float dl = D1[n * 10 + h];
      float wl[11];
#pragma unroll
      for (int j = 0; j < 11; j++) wl[j] = wee1[j * 10 + h];
      float m = -1e30f;
      for (int pos = start + lane; pos < end; pos += 64){
        int s = csr_src[pos]; int eid = csr_eid[pos];
        const float* ea = (eid < EE) ? eattr + (size_t)eid * 11 : lattr + (size_t)(eid - EE) * 11;
        float eel = 0;
#pragma unroll
        for (int j = 0; j < 11; j++) eel += ea[j] * wl[j];
        float lg = S1[s * 10 + h] + dl + eel;
        lg = lg > 0.f ? lg : 0.2f * lg;
        m = fmaxf(m, lg);
      }
      m = warp_max(m);
      float ps = 0;
      for (int pos = start + lane; pos < end; pos += 64){
        int s = csr_src[pos]; int eid = csr_eid[pos];
        const float* ea = (eid < EE) ? eattr + (size_t)eid * 11 : lattr + (size_t)(eid - EE) * 11;
        float eel = 0;
#pragma unroll
        for (int j = 0; j < 11; j++) eel += ea[j] * wl[j];
        float lg = S1[s * 10 + h] + dl + eel;
        lg = lg > 0.f ? lg : 0.2f * lg;
        ps += __expf(lg - m);
      }
      ps = warp_sum(ps);
      float inv = 1.0f / ps;
      float acc0 = 0, acc1 = 0;
      for (int pos = start; pos < end; pos++){
        int s = csr_src[pos]; int eid = csr_eid[pos];
        const float* ea = (eid < EE) ? eattr + (size_t)eid * 11 : lattr + (size_t)(eid - EE) * 11;
        float eel = 0;
#pragma unroll
        for (int j = 0; j < 11; j++) eel += ea[j] * wl[j];
        float lg = S1[s * 10 + h] + dl + eel;
        lg = lg > 0.f ? lg : 0.2f * lg;
        float alpha = __expf(lg - m) * inv;
        const float* xr = x1 + (size_t)s * 93;
        acc0 += alpha * xr[lane];
        if (lane < 29) acc1 += alpha * xr[64 + lane];
      }
      bf16* o = xaggp + (size_t)(n * 10 + h) * 96;
      o[lane] = __float2bfloat16(acc0);
      if (lane < 29) o[64 + lane] = __float2bfloat16(acc1);
      else if (lane < 32) o[64 + lane] = __float2bfloat16(0.f);
    }
  }
}

// ---------------- GAT layer 2: one wave per node, lane-parallel softmax ----------------

__global__ __launch_bounds__(256) void k_gat2(
    const int* __restrict__ offsets, const int* __restrict__ csr_src,
    const int* __restrict__ csr_eid, const float* __restrict__ eattr,
    const float* __restrict__ lattr, const float* __restrict__ s2,
    const float* __restrict__ d2, const float* __restrict__ we2e,
    const bf16* __restrict__ xs2, const float* __restrict__ b2,
    float* __restrict__ h2f, bf16* __restrict__ hbf, float* __restrict__ alpha_out){
  int n = (blockIdx.x * 256 + threadIdx.x) >> 6;
  int lane = threadIdx.x & 63;
  int start = offsets[n], end = offsets[n + 1];
  int deg = end - start;
  float dl = d2[n];

  float acc[8] = {0, 0, 0, 0, 0, 0, 0, 0};

  if (deg <= 64){
    bool act = lane < deg;
    int s = 0, eid = 0;
    float eel = 0.f;
    if (act){
      s = csr_src[start + lane];
      eid = csr_eid[start + lane];
      const float* eap = (eid < EE) ? eattr + (size_t)eid * 11
                                    : lattr + (size_t)(eid - EE) * 11;
#pragma unroll
      for (int j = 0; j < 11; j++) eel += eap[j] * we2e[j];
    }
    float lg = -1e30f;
    if (act){
      lg = s2[s] + dl + eel;
      lg = lg > 0.f ? lg : 0.2f * lg;
    }
    float m = warp_max(lg);
    float pv = act ? __expf(lg - m) : 0.f;
    float sum = warp_sum(pv);
    float alpha = pv / sum;
    if (act) alpha_out[eid] = alpha;

    for (int e = 0; e < deg; e++){
      int se = __shfl(s, e);
      float al = __shfl(alpha, e);
      union { uint4 u; unsigned short sh[8]; } xv;
      xv.u = *(const uint4*)&xs2[(size_t)se * 512 + lane * 8];
#pragma unroll
      for (int jj = 0; jj < 8; jj++) acc[jj] += al * bf2f(xv.sh[jj]);
    }
  } else {
    // general fallback (3-pass)
    float wl[11];
#pragma unroll
    for (int j = 0; j < 11; j++) wl[j] = we2e[j];
    float m = -1e30f;
    for (int pos = start + lane; pos < end; pos += 64){
      int s = csr_src[pos]; int eid = csr_eid[pos];
      const float* ea = (eid < EE) ? eattr + (size_t)eid * 11 : lattr + (size_t)(eid - EE) * 11;
      float eel = 0;
#pragma unroll
      for (int j = 0; j < 11; j++) eel += ea[j] * wl[j];
      float lg = s2[s] + dl + eel;
      lg = lg > 0.f ? lg : 0.2f * lg;
      m = fmaxf(m, lg);
    }
    m = warp_max(m);
    float ps = 0;
    for (int pos = start + lane; pos < end; pos += 64){
      int s = csr_src[pos]; int eid = csr_eid[pos];
      const float* ea = (eid < EE) ? eattr + (size_t)eid * 11 : lattr + (size_t)(eid - EE) * 11;
      float eel = 0;
#pragma unroll
      for (int j = 0; j < 11; j++) eel += ea[j] * wl[j];
      float lg = s2[s] + dl + eel;
      lg = lg > 0.f ? lg : 0.2f * lg;
      ps += __expf(lg - m);
    }
    ps = warp_sum(ps);
    float inv = 1.0f / ps;
    for (int pos = start; pos < end; pos++){
      int s = csr_src[pos]; int eid = csr_eid[pos];
      const float* ea = (eid < EE) ? eattr + (size_t)eid * 11 : lattr + (size_t)(eid - EE) * 11;
      float eel = 0;
#pragma unroll
      for (int j = 0; j < 11; j++) eel += ea[j] * wl[j];
      float lg = s2[s] + dl + eel;
      lg = lg > 0.f ? lg : 0.2f * lg;
      float alpha = __expf(lg - m) * inv;
      if (lane == 0) alpha_out[eid] = alpha;
      union { uint4 u; unsigned short sh[8]; } xv;
      xv.u = *(const uint4*)&xs2[(size_t)s * 512 + lane * 8];
#pragma unroll
      for (int jj = 0; jj < 8; jj++) acc[jj] += alpha * bf2f(xv.sh[jj]);
    }
  }

#pragma unroll
  for (int jj = 0; jj < 8; jj++){
    int c = lane * 8 + jj;
    float v = acc[jj] + b2[c];
    v = v > 0.f ? v : (__expf(v) - 1.f);
    h2f[(size_t)n * 512 + c] = v;
    hbf[(size_t)n * 512 + c] = __float2bfloat16(v);
  }
}

// ---------------- MFMA bf16 GEMM: C = act(A @ Bt^T + bias + res) ----------------
// A [M,K+] bf16 (row stride lda), Bt [N,K+] bf16 (row stride ldb), C [M,ldc].
// K%32==0. z-dim: aZ/bZ shift A/Bt (batching AND split-K), cZ shifts C.
// Double-buffered LDS, one barrier per K-step. LDS XOR swizzle: col block
// f = c ^ ((row>>1)&3) spreads each 16-lane ds_read_b128 group across all 8
// bank-quads (2 lanes/quad = free per m136). Same involution on source addr
// (LDS write stays linear for global_load_lds) and ds_read col.
// Bijective XCD swizzle over 2D grid (gridDim.x*gridDim.y % 8 == 0).
// LOG: epilogue also atomically accumulates s2 += C·w2s, d2 += C·w2d per row.

__device__ __forceinline__ void stC_elem(float* p, float v){ *p = v; }
__device__ __forceinline__ void stC_elem(bf16* p, float v){ *p = __float2bfloat16(v); }

template <int BMF, int BNF, int ACT, bool BIAS, bool RES, bool LOG, typename TC>
__global__ __launch_bounds__(256) void k_mm(
    const bf16* __restrict__ A, const bf16* __restrict__ Bt,
    const float* __restrict__ bias, const float* __restrict__ res,
    TC* __restrict__ C, int M, int K, int lda, int ldb, int ldc,
    long aZ, long bZ, long cZ, long biasZ,
    const float* __restrict__ w2s, const float* __restrict__ w2d,
    float* __restrict__ s2, float* __restrict__ d2){
  constexpr int BM = BMF * 32, BN = BNF * 32;
  __shared__ __align__(16) bf16 As[2][BM * 32];
  __shared__ __align__(16) bf16 Bs[2][BN * 32];
  const int tid = threadIdx.x, wave = tid >> 6, lane = tid & 63;

  const int nwg = gridDim.x * gridDim.y;
  const int id = blockIdx.y * gridDim.x + blockIdx.x;
  const int cpx = nwg >> 3;
  const int swz = (id & 7) * cpx + (id >> 3);
  const int bm = (swz / gridDim.x) * BM, bn = (swz % gridDim.x) * BN;

  const int z = blockIdx.z;
  A  += (size_t)z * aZ;
  Bt += (size_t)z * bZ;
  C  += (size_t)z * cZ;
  const float* bp = BIAS ? bias + (size_t)z * biasZ : nullptr;

  const int trow = tid >> 2;
  const int stk = (((tid & 3) ^ ((trow >> 1) & 3)) << 3);  // pre-swizzled source col
  const int wr = (wave >> 1) * (BMF * 16), wc = (wave & 1) * (BNF * 16);
  const int r = lane & 15, kq = lane >> 4;
  const int swcol = ((kq ^ ((r >> 1) & 3)) << 3);          // swizzled ds_read col

  fv4 acc[BMF][BNF] = {};

  auto STAGE = [&](int buf, int k0){
#pragma unroll
    for (int s = 0; s < BM / 64; s++)
      gl_lds16(A + (size_t)(bm + s * 64 + trow) * lda + k0 + stk,
               (char*)&As[buf][0] + s * 4096 + wave * 1024, lane);
#pragma unroll
    for (int s = 0; s < BN / 64; s++)
      gl_lds16(Bt + (size_t)(bn + s * 64 + trow) * ldb + k0 + stk,
               (char*)&Bs[buf][0] + s * 4096 + wave * 1024, lane);
  };

  STAGE(0, 0);
  int cur = 0;
  for (int k0 = 0; k0 < K; k0 += 32){
    __syncthreads();
    if (k0 + 32 < K) STAGE(cur ^ 1, k0 + 32);

    bfv8 a[BMF], b[BNF];
#pragma unroll
    for (int i = 0; i < BMF; i++)
      a[i] = *(const bfv8*)&As[cur][(wr + i * 16 + r) * 32 + swcol];
#pragma unroll
    for (int j = 0; j < BNF; j++)
      b[j] = *(const bfv8*)&Bs[cur][(wc + j * 16 + r) * 32 + swcol];
#pragma unroll
    for (int i = 0; i < BMF; i++)
#pragma unroll
      for (int j = 0; j < BNF; j++)
        acc[i][j] = __builtin_amdgcn_mfma_f32_16x16x32_bf16(a[i], b[j], acc[i][j], 0, 0, 0);
    cur ^= 1;
  }

  const int rb = bm + wr + (lane >> 4) * 4;
  const int cb = bn + wc + (lane & 15);
  float ls[BMF][4], ld[BMF][4];
  if (LOG){
#pragma unroll
    for (int i = 0; i < BMF; i++)
#pragma unroll
      for (int q = 0; q < 4; q++){ ls[i][q] = 0.f; ld[i][q] = 0.f; }
  }
  const float* wsp = LOG ? w2s + (size_t)z * biasZ : nullptr;
  const float* wdp = LOG ? w2d + (size_t)z * biasZ : nullptr;

#pragma unroll
  for (int i = 0; i < BMF; i++)
#pragma unroll
    for (int j = 0; j < BNF; j++){
      int gn = cb + j * 16;
      float bv = BIAS ? bp[gn] : 0.f;
#pragma unroll
      for (int q = 0; q < 4; q++){
        int gm = rb + i * 16 + q;
        float v = acc[i][j][q] + bv;
        if (RES) v += res[(size_t)gm * ldc + gn];
        if (ACT == 1) v = fmaxf(v, 0.f);
        if (ACT == 2) v = v > 0.f ? v : (__expf(v) - 1.f);
        if (LOG){ ls[i][q] += v * wsp[gn]; ld[i][q] += v * wdp[gn]; }
        stC_elem(&C[(size_t)gm * ldc + gn], v);
      }
    }

  if (LOG){
#pragma unroll
    for (int i = 0; i < BMF; i++)
#pragma unroll
      for (int q = 0; q < 4; q++){
        float a = ls[i][q], b = ld[i][q];
#pragma unroll
        for (int o = 1; o < 16; o <<= 1){ a += __shfl_xor(a, o); b += __shfl_xor(b, o); }
        if ((lane & 15) == 0){
          int gm = rb + i * 16 + q;
          atomicAdd(&s2[gm], a);
          atomicAdd(&d2[gm], b);
        }
      }
  }
}

// ---------------- split-K reduces ----------------

__global__ void k_red2bf(const float* __restrict__ pA, const float* __restrict__ pB,
                         bf16* __restrict__ out){
  int t = (blockIdx.x * 256 + threadIdx.x) * 4;
  float4 a = *(const float4*)&pA[t];
  float4 b = *(const float4*)&pB[t];
  out[t]     = __float2bfloat16(a.x + b.x);
  out[t + 1] = __float2bfloat16(a.y + b.y);
  out[t + 2] = __float2bfloat16(a.z + b.z);
  out[t + 3] = __float2bfloat16(a.w + b.w);
}

__global__ void k_red4bf(const float* __restrict__ p, long st, bf16* __restrict__ out){
  int t = (blockIdx.x * 256 + threadIdx.x) * 4;
  float4 a = *(const float4*)&p[t];
  float4 b = *(const float4*)&p[st + t];
  float4 c = *(const float4*)&p[2 * st + t];
  float4 d = *(const float4*)&p[3 * st + t];
  out[t]     = __float2bfloat16(a.x + b.x + c.x + d.x);
  out[t + 1] = __float2bfloat16(a.y + b.y + c.y + d.y);
  out[t + 2] = __float2bfloat16(a.z + b.z + c.z + d.z);
  out[t + 3] = __float2bfloat16(a.w + b.w + c.w + d.w);
}

// ---------------- layernorm variants, pool ----------------

__device__ __forceinline__ void ln_body(float v[8], int lane,
                                        const float* g, const float* b,
                                        float* yf, bf16* ybf, size_t row){
  float s = 0;
#pragma unroll
  for (int j = 0; j < 8; j++) s += v[j];
  s = warp_sum(s);
  float mu = s * (1.0f / 512.0f);
  float var = 0;
#pragma unroll
  for (int j = 0; j < 8; j++){ float d = v[j] - mu; var += d * d; }
  var = warp_sum(var) * (1.0f / 512.0f);
  float inv = rsqrtf(var + 1e-5f);
#pragma unroll
  for (int j = 0; j < 8; j++){
    int c = lane + j * 64;
    float o = (v[j] - mu) * inv * g[c] + b[c];
    yf[row * 512 + c] = o;
    ybf[row * 512 + c] = __float2bfloat16(o);
  }
}

__global__ __launch_bounds__(256) void k_ln(const float* __restrict__ x,
                                            const float* __restrict__ g,
                                            const float* __restrict__ b,
                                            float* __restrict__ yf,
                                            bf16* __restrict__ ybf){
  int wid = (blockIdx.x * 256 + threadIdx.x) >> 6;
  int lane = threadIdx.x & 63;
  const float* xr = x + (size_t)wid * 512;
  float v[8];
#pragma unroll
  for (int j = 0; j < 8; j++) v[j] = xr[lane + j * 64];
  ln_body(v, lane, g, b, yf, ybf, (size_t)wid);
}

// fused split-K reduce + bias + residual + LN
__global__ __launch_bounds__(256) void k_ln_fr(const float* __restrict__ pA,
                                               const float* __restrict__ pB,
                                               const float* __restrict__ bias,
                                               const float* __restrict__ res,
                                               const float* __restrict__ g,
                                               const float* __restrict__ b,
                                               float* __restrict__ yf,
                                               bf16* __restrict__ ybf){
  int wid = (blockIdx.x * 256 + threadIdx.x) >> 6;
  int lane = threadIdx.x & 63;
  size_t base = (size_t)wid * 512;
  float v[8];
#pragma unroll
  for (int j = 0; j < 8; j++){
    int c = lane + j * 64;
    v[j] = pA[base + c] + pB[base + c] + bias[c] + res[base + c];
  }
  ln_body(v, lane, g, b, yf, ybf, (size_t)wid);
}

__global__ void k_pool(const float* __restrict__ h, float* __restrict__ out){
  int b = blockIdx.x;
  int c = threadIdx.x;   // 512 threads
  const float* hr = h + (size_t)b * 64 * 512;
  float m = -1e30f;
  for (int i = 0; i < 64; i++) m = fmaxf(m, hr[i * 512 + c]);
  out[(size_t)b * 512 + c] = m;
}

// ---------------- launcher ----------------

extern "C" void kernel_launch(void* const* d_in, const int* in_sizes, int n_in,
                              void* d_out, int out_size, void* d_ws, size_t ws_size,
                              hipStream_t stream){
  const float* x1    = (const float*)d_in[0];
  const int*   ei    = (const int*)d_in[1];
  const float* eattr = (const float*)d_in[2];
  const float* W1    = (const float*)d_in[4];
  const float* as1   = (const float*)d_in[5];
  const float* ad1   = (const float*)d_in[6];
  const float* We1   = (const float*)d_in[7];
  const float* ae1   = (const float*)d_in[8];
  const float* b1    = (const float*)d_in[9];
  const float* W2    = (const float*)d_in[10];
  const float* as2   = (const float*)d_in[11];
  const float* ad2   = (const float*)d_in[12];
  const float* We2   = (const float*)d_in[13];
  const float* ae2   = (const float*)d_in[14];
  const float* b2    = (const float*)d_in[15];
  const float* in_w  = (const float*)d_in[16];
  const float* in_b  = (const float*)d_in[17];
  const float* out_w = (const float*)d_in[18];
  const float* out_b = (const float*)d_in[19];
  const float* ln1g  = (const float*)d_in[20];
  const float* ln1b  = (const float*)d_in[21];
  const float* f1w   = (const float*)d_in[22];
  const float* f1b   = (const float*)d_in[23];
  const float* f2w   = (const float*)d_in[24];
  const float* f2b   = (const float*)d_in[25];
  const float* ln2g  = (const float*)d_in[26];
  const float* ln2b  = (const float*)d_in[27];

  const int* src0 = ei;
  const int* dst0 = ei + EE;

  char* p = (char*)d_ws;
  auto alloc = [&](size_t bytes) -> void* {
    void* r = p;
    p += (bytes + 255) & ~(size_t)255;
    return r;
  };
  // contiguous zero-init region: deg, cursor, s2, d2v, bvo, esum  (one memset)
  int*   deg     = (int*)alloc(NN * 4);
  int*   cursor  = (int*)alloc(NN * 4);
  float* s2      = (float*)alloc(NN * 4);
  float* d2v     = (float*)alloc(NN * 4);
  float* bvo     = (float*)alloc(2 * 512 * 4);
  float* esum    = (float*)alloc(NN * 11 * 4);
  size_t zbytes  = (char*)p - (char*)deg;

  float* lattr   = (float*)alloc(NN * 11 * 4);
  int*   offsets = (int*)alloc((NN + 1) * 4);
  int*   csr_src = (int*)alloc(ET * 4);
  int*   csr_eid = (int*)alloc(ET * 4);
  float* wse1    = (float*)alloc(930 * 4);
  float* wsd1    = (float*)alloc(930 * 4);
  float* wee1    = (float*)alloc(110 * 4);
  float* S1      = (float*)alloc(NN * 10 * 4);
  float* D1b     = (float*)alloc(NN * 10 * 4);
  bf16*  xaggp   = (bf16*)alloc((size_t)NN * 10 * 96 * 2);
  bf16*  W1t     = (bf16*)alloc((size_t)5120 * 96 * 2);
  bf16*  W2t     = (bf16*)alloc((size_t)512 * 5120 * 2);
  bf16*  f1wt    = (bf16*)alloc((size_t)2 * 2048 * 512 * 2);
  bf16*  f2wt    = (bf16*)alloc((size_t)2 * 512 * 2048 * 2);
  bf16*  Wvb     = (bf16*)alloc((size_t)2 * 512 * 512 * 2);
  bf16*  WoT     = (bf16*)alloc((size_t)2 * 512 * 512 * 2);
  bf16*  Wvot    = (bf16*)alloc((size_t)2 * 512 * 512 * 2);
  bf16*  h1      = (bf16*)alloc((size_t)NN * 5120 * 2);   // dead after xs2; reused below
  float* w2s     = (float*)alloc(5120 * 4);
  float* w2d     = (float*)alloc(5120 * 4);
  float* we2e    = (float*)alloc(16 * 4);
  bf16*  xs2     = (bf16*)alloc((size_t)NN * 512 * 2);
  float* h2f     = (float*)alloc((size_t)NN * 512 * 4);
  bf16*  hbf     = (bf16*)alloc((size_t)NN * 512 * 2);
  float* pbuf    = (float*)alloc((size_t)NN * 512 * 4 * 2);   // 2 split-K partials (always)
  long   pdz     = (long)NN * 512;
  // optional 2 more partials for split-K=4, if workspace allows
  size_t used2   = (char*)p - (char*)d_ws;
  bool   sk4     = (used2 + 2 * (size_t)NN * 512 * 4 + 256 <= ws_size);
  float* pbufHi  = sk4 ? (float*)alloc((size_t)NN * 512 * 4 * 2) : nullptr;
  (void)pbufHi;
  // aliases into dead h1 region (40 MB): tmp (8 MB) + fbuf (16 MB)
  float* tmp  = (float*)h1;
  bf16*  fbuf = (bf16*)((char*)h1 + (size_t)NN * 512 * 4);

  float* out_pool = (float*)d_out;
  float* alpha2   = out_pool + 64 * 512;

  hipMemsetAsync(deg, 0, zbytes, stream);

  // graph prep + folds (wave-parallel)
  k_deg_esum<<<EE / 256, 256, 0, stream>>>(dst0, eattr, deg, esum);
  k_loop_attr<<<NN / 256, 256, 0, stream>>>(esum, deg, lattr);
  k_scan<<<1, 256, 0, stream>>>(deg, offsets);
  k_scatter<<<(EE + NN) / 256, 256, 0, stream>>>(src0, dst0, offsets, cursor, csr_src, csr_eid);
  k_foldsw<<<1575, 256, 0, stream>>>(W1, as1, ad1, We1, ae1, W2, as2, ad2, We2, ae2,
                                     in_b, out_w, out_b,
                                     wse1, wsd1, wee1, w2s, w2d, we2e, bvo);
  k_logits1<<<160, 256, 0, stream>>>(x1, wse1, wsd1, S1, D1b);

  // weight preps
  k_t2b<<<dim3(160, 3, 1), dim3(32, 8), 0, stream>>>(W1, W1t, 93, 5120, 96, 0, 0);
  k_t2b<<<dim3(16, 160, 1), dim3(32, 8), 0, stream>>>(W2, W2t, 5120, 512, 5120, 0, 0);
  k_t2b<<<dim3(64, 16, 2), dim3(32, 8), 0, stream>>>(f1w, f1wt, 512, 2048, 512,
                                                     512L * 2048, 2048L * 512);
  k_t2b<<<dim3(16, 64, 2), dim3(32, 8), 0, stream>>>(f2w, f2wt, 2048, 512, 2048,
                                                     2048L * 512, 512L * 2048);
  k_prep_wv<<<2048, 256, 0, stream>>>(in_w, Wvb);
  k_t2b<<<dim3(16, 16, 2), dim3(32, 8), 0, stream>>>(out_w, WoT, 512, 512, 512,
                                                     262144, 262144);
  // Wvot[n][k] = sum_j WoT[n][j] * Wvb[k][j]  (= (Wv@Wo)^T, bf16)
  k_mm<4, 4, 0, false, false, false, bf16><<<dim3(4, 4, 2), 256, 0, stream>>>(
      WoT, Wvb, nullptr, nullptr, Wvot, 512, 512, 512, 512, 512,
      262144, 262144, 262144, 0, nullptr, nullptr, nullptr, nullptr);

  // GAT-1 aggregate, then per-head MFMA projection with fused logits2 epilogue
  k_gat1<<<NN / 4, 256, 0, stream>>>(offsets, csr_src, csr_eid, eattr, lattr,
                                     S1, D1b, wee1, x1, xaggp);
  // h1 = elu(xagg @ W1 + b1); epilogue: s2 += h1·w2s, d2v += h1·w2d
  k_mm<4, 4, 2, true, false, true, bf16><<<dim3(4, 32, 10), 256, 0, stream>>>(
      xaggp, W1t, b1, nullptr, h1, NN, 96, 960, 96, 5120, 96, 512L * 96, 512, 512,
      w2s, w2d, s2, d2v);

  // xs2 = h1 @ W2, split-K (4 if ws allows, else 2), 128x128 tiles
  if (sk4){
    k_mm<4, 4, 0, false, false, false, float><<<dim3(4, 32, 4), 256, 0, stream>>>(
        h1, W2t, nullptr, nullptr, pbuf, NN, 1280, 5120, 5120, 512,
        1280, 1280, pdz, 0, nullptr, nullptr, nullptr, nullptr);
    k_red4bf<<<2048, 256, 0, stream>>>(pbuf, pdz, xs2);
  } else {
    k_mm<4, 4, 0, false, false, false, float><<<dim3(4, 32, 2), 256, 0, stream>>>(
        h1, W2t, nullptr, nullptr, pbuf, NN, 2560, 5120, 5120, 512,
        2560, 2560, pdz, 0, nullptr, nullptr, nullptr, nullptr);
    k_red2bf<<<2048, 256, 0, stream>>>(pbuf, pbuf + pdz, xs2);
  }
  k_gat2<<<NN / 4, 256, 0, stream>>>(offsets, csr_src, csr_eid, eattr, lattr,
                                     s2, d2v, we2e, xs2, b2, h2f, hbf, alpha2);

  for (int i = 0; i < 2; i++){
    // tmp = h2 + h2 @ Wvo + bvo   (BN=64 tiles: 512 blocks = 2/CU)
    k_mm<2, 2, 0, true, true, false, float><<<dim3(8, 64, 1), 256, 0, stream>>>(
        hbf, Wvot + (size_t)i * 262144, bvo + i * 512, h2f, tmp,
        NN, 512, 512, 512, 512, 0, 0, 0, 0, nullptr, nullptr, nullptr, nullptr);
    k_ln<<<NN / 4, 256, 0, stream>>>(tmp, ln1g + i * 512, ln1b + i * 512, h2f, hbf);
    // fbuf = relu(h @ f1w + f1b): N=2048, K=512
    k_mm<4, 4, 1, true, false, false, bf16><<<dim3(16, 32, 1), 256, 0, stream>>>(
        hbf, f1wt + (size_t)i * 2048 * 512, f1b + i * 2048, nullptr, fbuf,
        NN, 512, 512, 512, 2048, 0, 0, 0, 0, nullptr, nullptr, nullptr, nullptr);
    // FFN2 split-K=2: partials (K-window 1024 each), reduce fused into LN
    k_mm<2, 4, 0, false, false, false, float><<<dim3(4, 64, 2), 256, 0, stream>>>(
        fbuf, f2wt + (size_t)i * 512 * 2048, nullptr, nullptr, pbuf,
        NN, 1024, 2048, 2048, 512, 1024, 1024, pdz, 0,
        nullptr, nullptr, nullptr, nullptr);
    k_ln_fr<<<NN / 4, 256, 0, stream>>>(pbuf, pbuf + pdz, f2b + i * 512, h2f,
                                        ln2g + i * 512, ln2b + i * 512, h2f, hbf);
  }

  k_pool<<<64, 512, 0, stream>>>(h2f, out_pool);
}

// Round 11
// 429.092 us; speedup vs baseline: 5.9469x; 1.0518x over previous
//
#include <hip/hip_runtime.h>
#include <hip/hip_bf16.h>

#define NN 4096
#define EE 16384
#define ET 20480   // EE + NN

typedef __hip_bfloat16 bf16;
typedef __bf16 bfv8 __attribute__((ext_vector_type(8)));
typedef float fv4 __attribute__((ext_vector_type(4)));

__device__ __forceinline__ float warp_max(float v){
#pragma unroll
  for (int o = 32; o; o >>= 1) v = fmaxf(v, __shfl_xor(v, o));
  return v;
}
__device__ __forceinline__ float warp_sum(float v){
#pragma unroll
  for (int o = 32; o; o >>= 1) v += __shfl_xor(v, o);
  return v;
}
__device__ __forceinline__ float bf2f(unsigned short u){
  return __uint_as_float((unsigned)u << 16);
}

// async global->LDS, 16B per lane. lbase = wave-uniform LDS base (lane*16 added by HW).
__device__ __forceinline__ void gl_lds16(const void* g, void* lbase, int lane){
#if __has_builtin(__builtin_amdgcn_global_load_lds)
  __builtin_amdgcn_global_load_lds(
      (const __attribute__((address_space(1))) unsigned int*)g,
      (__attribute__((address_space(3))) unsigned int*)lbase, 16, 0, 0);
#else
  *(uint4*)((char*)lbase + lane * 16) = *(const uint4*)g;
#endif
}

// ---------------- graph preprocessing ----------------

__global__ void k_deg_esum(const int* __restrict__ dst0, const float* __restrict__ eattr,
                           int* deg, float* esum){
  int e = blockIdx.x * 256 + threadIdx.x;
  if (e >= EE) return;
  int d = dst0[e];
  atomicAdd(&deg[d], 1);
  const float* ar = eattr + (size_t)e * 11;
  float* er = esum + (size_t)d * 11;
#pragma unroll
  for (int j = 0; j < 11; j++) atomicAdd(&er[j], ar[j]);
}

__global__ void k_loop_attr(const float* __restrict__ esum, const int* __restrict__ deg,
                            float* lattr){
  int n = blockIdx.x * 256 + threadIdx.x;
  if (n >= NN) return;
  float c = fmaxf((float)deg[n], 1.0f);
#pragma unroll
  for (int j = 0; j < 11; j++) lattr[n * 11 + j] = esum[n * 11 + j] / c;
}

__global__ void k_scan(const int* __restrict__ deg, int* offsets){
  __shared__ int sums[256];
  int t = threadIdx.x;
  int base = t * 16;
  int vals[16];
  int s = 0;
#pragma unroll
  for (int j = 0; j < 16; j++){ vals[j] = s; s += deg[base + j] + 1; }
  sums[t] = s;
  __syncthreads();
  for (int off = 1; off < 256; off <<= 1){
    int v = (t >= off) ? sums[t - off] : 0;
    __syncthreads();
    sums[t] += v;
    __syncthreads();
  }
  int pre = (t == 0) ? 0 : sums[t - 1];
#pragma unroll
  for (int j = 0; j < 16; j++) offsets[base + j] = pre + vals[j];
  if (t == 255) offsets[NN] = sums[255];
}

__global__ void k_scatter(const int* __restrict__ src0, const int* __restrict__ dst0,
                          const int* __restrict__ offsets, int* cursor,
                          int* csr_src, int* csr_eid){
  int t = blockIdx.x * 256 + threadIdx.x;
  if (t < EE){
    int d = dst0[t];
    int pos = offsets[d] + atomicAdd(&cursor[d], 1);
    csr_src[pos] = src0[t];
    csr_eid[pos] = t;
  } else if (t < EE + NN){
    int n = t - EE;
    int pos = offsets[n + 1] - 1;
    csr_src[pos] = n;
    csr_eid[pos] = EE + n;
  }
}

// ---------------- wave-parallel weight folds: one wave per dot product ----------------

__device__ __forceinline__ float dot512(const float* __restrict__ a,
                                        const float* __restrict__ b, int lane){
  float4 a0 = *(const float4*)&a[lane * 8];
  float4 a1 = *(const float4*)&a[lane * 8 + 4];
  float4 b0 = *(const float4*)&b[lane * 8];
  float4 b1 = *(const float4*)&b[lane * 8 + 4];
  return a0.x * b0.x + a0.y * b0.y + a0.z * b0.z + a0.w * b0.w
       + a1.x * b1.x + a1.y * b1.y + a1.z * b1.z + a1.w * b1.w;
}

__global__ __launch_bounds__(256) void k_foldsw(
    const float* __restrict__ W1, const float* __restrict__ as1,
    const float* __restrict__ ad1, const float* __restrict__ We1,
    const float* __restrict__ ae1,
    const float* __restrict__ W2, const float* __restrict__ as2,
    const float* __restrict__ ad2, const float* __restrict__ We2,
    const float* __restrict__ ae2,
    const float* __restrict__ in_b, const float* __restrict__ out_w,
    const float* __restrict__ out_b,
    float* wse1, float* wsd1, float* wee1,
    float* w2s, float* w2d, float* we2e, float* bvo){
  int w = blockIdx.x * 4 + (threadIdx.x >> 6);
  int lane = threadIdx.x & 63;

  if (w < 930){
    int k = w / 10, h = w % 10;
    const float* wr = W1 + (size_t)k * 5120 + h * 512;
    float ss = warp_sum(dot512(wr, as1 + h * 512, lane));
    float sd = warp_sum(dot512(wr, ad1 + h * 512, lane));
    if (lane == 0){ wse1[w] = ss; wsd1[w] = sd; }
  } else if (w < 1040){
    int u = w - 930;
    int k = u / 10, h = u % 10;
    const float* wr = We1 + (size_t)k * 5120 + h * 512;
    float se = warp_sum(dot512(wr, ae1 + h * 512, lane));
    if (lane == 0) wee1[u] = se;
  } else if (w < 6160){
    int t = w - 1040;
    const float* wr = W2 + (size_t)t * 512;
    float ss = warp_sum(dot512(wr, as2, lane));
    float sd = warp_sum(dot512(wr, ad2, lane));
    if (lane == 0){ w2s[t] = ss; w2d[t] = sd; }
  } else if (w < 6171){
    int k = w - 6160;
    float se = warp_sum(dot512(We2 + (size_t)k * 512, ae2, lane));
    if (lane == 0) we2e[k] = se;
  } else if (w < 6299){
    int idx = w - 6171;           // i(2) x cblock(8) x kchunk(8)
    int i = idx >> 6;
    int cblk = (idx >> 3) & 7;
    int kch = idx & 7;
    int c = cblk * 64 + lane;
    const float* ib = in_b + i * 1536 + 1024;
    const float* ow = out_w + (size_t)i * 262144;
    float acc = 0.f;
    int k0 = kch * 64;
#pragma unroll 8
    for (int k = k0; k < k0 + 64; k++) acc += ib[k] * ow[(size_t)k * 512 + c];
    if (kch == 0) acc += out_b[i * 512 + c];
    atomicAdd(&bvo[i * 512 + c], acc);
  }
}

__global__ void k_logits1(const float* __restrict__ x1, const float* __restrict__ wse1,
                          const float* __restrict__ wsd1, float* S1, float* D1){
  int t = blockIdx.x * 256 + threadIdx.x;
  int n = t / 10, h = t % 10;
  const float* xr = x1 + (size_t)n * 93;
  float s = 0, d = 0;
  for (int k = 0; k < 93; k++){ float x = xr[k]; s += x * wse1[k * 10 + h]; d += x * wsd1[k * 10 + h]; }
  S1[t] = s; D1[t] = d;
}

// ---------------- weight prep ----------------

// dst[n][k(dK)] = bf16(src[k][n]) for k<K (0 for K<=k<dK); src [K][N] f32
__global__ void k_t2b(const float* __restrict__ src, bf16* __restrict__ dst,
                      int K, int N, int dK, long sZ, long dZ){
  __shared__ float t[32][33];
  src += (size_t)blockIdx.z * sZ;
  dst += (size_t)blockIdx.z * dZ;
  int k0 = blockIdx.y * 32, n0 = blockIdx.x * 32;
  int x = threadIdx.x, y = threadIdx.y;   // 32 x 8
#pragma unroll
  for (int yy = y; yy < 32; yy += 8){
    int k = k0 + yy, n = n0 + x;
    t[yy][x] = (k < K && n < N) ? src[(size_t)k * N + n] : 0.f;
  }
  __syncthreads();
#pragma unroll
  for (int yy = y; yy < 32; yy += 8){
    int n = n0 + yy, k = k0 + x;
    if (n < N && k < dK) dst[(size_t)n * dK + k] = __float2bfloat16(t[x][yy]);
  }
}

// Wvb[i][k][j] = bf16(in_w[i][k][1024+j])   (512x512 slice, row-major)
__global__ void k_prep_wv(const float* __restrict__ in_w, bf16* __restrict__ Wvb){
  int t = blockIdx.x * 256 + threadIdx.x;   // < 2*512*512
  int i = t >> 18, rem = t & 262143, k = rem >> 9, j = rem & 511;
  Wvb[t] = __float2bfloat16(in_w[(size_t)i * 786432 + (size_t)k * 1536 + 1024 + j]);
}

// ---------------- GAT layer 1: one wave per node, all 10 heads ----------------

__global__ __launch_bounds__(256) void k_gat1(
    const int* __restrict__ offsets, const int* __restrict__ csr_src,
    const int* __restrict__ csr_eid, const float* __restrict__ eattr,
    const float* __restrict__ lattr, const float* __restrict__ S1,
    const float* __restrict__ D1, const float* __restrict__ wee1,
    const float* __restrict__ x1, bf16* __restrict__ xaggp){
  int n = (blockIdx.x * 256 + threadIdx.x) >> 6;
  int lane = threadIdx.x & 63;
  int start = offsets[n], end = offsets[n + 1];
  int deg = end - start;

  if (deg <= 64){
    bool act = lane < deg;
    int s = 0, eid = 0;
    float ea[11];
#pragma unroll
    for (int j = 0; j < 11; j++) ea[j] = 0.f;
    if (act){
      s = csr_src[start + lane];
      eid = csr_eid[start + lane];
      const float* eap = (eid < EE) ? eattr + (size_t)eid * 11
                                    : lattr + (size_t)(eid - EE) * 11;
#pragma unroll
      for (int j = 0; j < 11; j++) ea[j] = eap[j];
    }
    float alpha[10];
#pragma unroll
    for (int h = 0; h < 10; h++){
      float eel = 0;
#pragma unroll
      for (int j = 0; j < 11; j++) eel += ea[j] * wee1[j * 10 + h];
      float lg = -1e30f;
      if (act){
        lg = S1[s * 10 + h] + D1[n * 10 + h] + eel;
        lg = lg > 0.f ? lg : 0.2f * lg;
      }
      float m = warp_max(lg);
      float pv = act ? __expf(lg - m) : 0.f;
      float sum = warp_sum(pv);
      alpha[h] = pv / sum;
    }
    float acc0[10], acc1[10];
#pragma unroll
    for (int h = 0; h < 10; h++){ acc0[h] = 0.f; acc1[h] = 0.f; }
    for (int e = 0; e < deg; e++){
      int se = __shfl(s, e);
      const float* xr = x1 + (size_t)se * 93;
      float xv0 = xr[lane];
      float xv1 = (lane < 29) ? xr[64 + lane] : 0.f;
#pragma unroll
      for (int h = 0; h < 10; h++){
        float al = __shfl(alpha[h], e);
        acc0[h] += al * xv0;
        acc1[h] += al * xv1;
      }
    }
#pragma unroll
    for (int h = 0; h < 10; h++){
      bf16* o = xaggp + (size_t)(n * 10 + h) * 96;
      o[lane] = __float2bfloat16(acc0[h]);
      if (lane < 29) o[64 + lane] = __float2bfloat16(acc1[h]);
      else if (lane < 32) o[64 + lane] = __float2bfloat16(0.f);
    }
  } else {
    // general fallback (3-pass per head)
    for (int h = 0; h < 10; h++){
      float dl = D1[n * 10 + h];
      float wl[11];
#pragma unroll
      for (int j = 0; j < 11; j++) wl[j] = wee1[j * 10 + h];
      float m = -1e30f;
      for (int pos = start + lane; pos < end; pos += 64){
        int s = csr_src[pos]; int eid = csr_eid[pos];
        const float* ea = (eid < EE) ? eattr + (size_t)eid * 11 : lattr + (size_t)(eid - EE) * 11;
        float eel = 0;
#pragma unroll
        for (int j = 0; j < 11; j++) eel += ea[j] * wl[j];
        float lg = S1[s * 10 + h] + dl + eel;
        lg = lg > 0.f ? lg : 0.2f * lg;
        m = fmaxf(m, lg);
      }
      m = warp_max(m);
      float ps = 0;
      for (int pos = start + lane; pos < end; pos += 64){
        int s = csr_src[pos]; int eid = csr_eid[pos];
        const float* ea = (eid < EE) ? eattr + (size_t)eid * 11 : lattr + (size_t)(eid - EE) * 11;
        float eel = 0;
#pragma unroll
        for (int j = 0; j < 11; j++) eel += ea[j] * wl[j];
        float lg = S1[s * 10 + h] + dl + eel;
        lg = lg > 0.f ? lg : 0.2f * lg;
        ps += __expf(lg - m);
      }
      ps = warp_sum(ps);
      float inv = 1.0f / ps;
      float acc0 = 0, acc1 = 0;
      for (int pos = start; pos < end; pos++){
        int s = csr_src[pos]; int eid = csr_eid[pos];
        const float* ea = (eid < EE) ? eattr + (size_t)eid * 11 : lattr + (size_t)(eid - EE) * 11;
        float eel = 0;
#pragma unroll
        for (int j = 0; j < 11; j++) eel += ea[j] * wl[j];
        float lg = S1[s * 10 + h] + dl + eel;
        lg = lg > 0.f ? lg : 0.2f * lg;
        float alpha = __expf(lg - m) * inv;
        const float* xr = x1 + (size_t)s * 93;
        acc0 += alpha * xr[lane];
        if (lane < 29) acc1 += alpha * xr[64 + lane];
      }
      bf16* o = xaggp + (size_t)(n * 10 + h) * 96;
      o[lane] = __float2bfloat16(acc0);
      if (lane < 29) o[64 + lane] = __float2bfloat16(acc1);
      else if (lane < 32) o[64 + lane] = __float2bfloat16(0.f);
    }
  }
}

// ---------------- GAT layer 2: one wave per node, lane-parallel softmax ----------------

__global__ __launch_bounds__(256) void k_gat2(
    const int* __restrict__ offsets, const int* __restrict__ csr_src,
    const int* __restrict__ csr_eid, const float* __restrict__ eattr,
    const float* __restrict__ lattr, const float* __restrict__ s2,
    const float* __restrict__ d2, const float* __restrict__ we2e,
    const bf16* __restrict__ xs2, const float* __restrict__ b2,
    float* __restrict__ h2f, bf16* __restrict__ hbf, float* __restrict__ alpha_out){
  int n = (blockIdx.x * 256 + threadIdx.x) >> 6;
  int lane = threadIdx.x & 63;
  int start = offsets[n], end = offsets[n + 1];
  int deg = end - start;
  float dl = d2[n];

  float acc[8] = {0, 0, 0, 0, 0, 0, 0, 0};

  if (deg <= 64){
    bool act = lane < deg;
    int s = 0, eid = 0;
    float eel = 0.f;
    if (act){
      s = csr_src[start + lane];
      eid = csr_eid[start + lane];
      const float* eap = (eid < EE) ? eattr + (size_t)eid * 11
                                    : lattr + (size_t)(eid - EE) * 11;
#pragma unroll
      for (int j = 0; j < 11; j++) eel += eap[j] * we2e[j];
    }
    float lg = -1e30f;
    if (act){
      lg = s2[s] + dl + eel;
      lg = lg > 0.f ? lg : 0.2f * lg;
    }
    float m = warp_max(lg);
    float pv = act ? __expf(lg - m) : 0.f;
    float sum = warp_sum(pv);
    float alpha = pv / sum;
    if (act) alpha_out[eid] = alpha;

    for (int e = 0; e < deg; e++){
      int se = __shfl(s, e);
      float al = __shfl(alpha, e);
      union { uint4 u; unsigned short sh[8]; } xv;
      xv.u = *(const uint4*)&xs2[(size_t)se * 512 + lane * 8];
#pragma unroll
      for (int jj = 0; jj < 8; jj++) acc[jj] += al * bf2f(xv.sh[jj]);
    }
  } else {
    // general fallback (3-pass)
    float wl[11];
#pragma unroll
    for (int j = 0; j < 11; j++) wl[j] = we2e[j];
    float m = -1e30f;
    for (int pos = start + lane; pos < end; pos += 64){
      int s = csr_src[pos]; int eid = csr_eid[pos];
      const float* ea = (eid < EE) ? eattr + (size_t)eid * 11 : lattr + (size_t)(eid - EE) * 11;
      float eel = 0;
#pragma unroll
      for (int j = 0; j < 11; j++) eel += ea[j] * wl[j];
      float lg = s2[s] + dl + eel;
      lg = lg > 0.f ? lg : 0.2f * lg;
      m = fmaxf(m, lg);
    }
    m = warp_max(m);
    float ps = 0;
    for (int pos = start + lane; pos < end; pos += 64){
      int s = csr_src[pos]; int eid = csr_eid[pos];
      const float* ea = (eid < EE) ? eattr + (size_t)eid * 11 : lattr + (size_t)(eid - EE) * 11;
      float eel = 0;
#pragma unroll
      for (int j = 0; j < 11; j++) eel += ea[j] * wl[j];
      float lg = s2[s] + dl + eel;
      lg = lg > 0.f ? lg : 0.2f * lg;
      ps += __expf(lg - m);
    }
    ps = warp_sum(ps);
    float inv = 1.0f / ps;
    for (int pos = start; pos < end; pos++){
      int s = csr_src[pos]; int eid = csr_eid[pos];
      const float* ea = (eid < EE) ? eattr + (size_t)eid * 11 : lattr + (size_t)(eid - EE) * 11;
      float eel = 0;
#pragma unroll
      for (int j = 0; j < 11; j++) eel += ea[j] * wl[j];
      float lg = s2[s] + dl + eel;
      lg = lg > 0.f ? lg : 0.2f * lg;
      float alpha = __expf(lg - m) * inv;
      if (lane == 0) alpha_out[eid] = alpha;
      union { uint4 u; unsigned short sh[8]; } xv;
      xv.u = *(const uint4*)&xs2[(size_t)s * 512 + lane * 8];
#pragma unroll
      for (int jj = 0; jj < 8; jj++) acc[jj] += alpha * bf2f(xv.sh[jj]);
    }
  }

#pragma unroll
  for (int jj = 0; jj < 8; jj++){
    int c = lane * 8 + jj;
    float v = acc[jj] + b2[c];
    v = v > 0.f ? v : (__expf(v) - 1.f);
    h2f[(size_t)n * 512 + c] = v;
    hbf[(size_t)n * 512 + c] = __float2bfloat16(v);
  }
}

// ---------------- MFMA bf16 GEMM: C = act(A @ Bt^T + bias + res) ----------------
// A [M,K+] bf16 (row stride lda), Bt [N,K+] bf16 (row stride ldb), C [M,ldc].
// K%32==0. z-dim: aZ/bZ shift A/Bt (batching AND split-K), cZ shifts C.
// Double-buffered LDS (carved from one smem block), one barrier per K-step.
// LDS XOR swizzle (both-sides, f = c ^ ((row>>1)&3): all 8 bank-quads, verified
// SQ_LDS_BANK_CONFLICT -> 0). Bijective XCD swizzle over 2D grid.
// bf16 output: LDS-bounced coalesced epilogue (uint4 stores) — avoids the
// 1.28x partial-line write amplification of scalar 2B stores.
// LOG: epilogue also atomically accumulates s2 += C·w2s, d2 += C·w2d per row.

__device__ __forceinline__ void stC_elem(float* p, float v){ *p = v; }
__device__ __forceinline__ void stC_elem(bf16* p, float v){ *p = __float2bfloat16(v); }

template <int BMF, int BNF, int ACT, bool BIAS, bool RES, bool LOG, typename TC>
__global__ __launch_bounds__(256) void k_mm(
    const bf16* __restrict__ A, const bf16* __restrict__ Bt,
    const float* __restrict__ bias, const float* __restrict__ res,
    TC* __restrict__ C, int M, int K, int lda, int ldb, int ldc,
    long aZ, long bZ, long cZ, long biasZ,
    const float* __restrict__ w2s, const float* __restrict__ w2d,
    float* __restrict__ s2, float* __restrict__ d2){
  constexpr int BM = BMF * 32, BN = BNF * 32;
  constexpr int ABYTES = 2 * BM * 32 * 2;
  constexpr int BBYTES = 2 * BN * 32 * 2;
  __shared__ __align__(16) char smem[ABYTES + BBYTES];
  bf16* As = (bf16*)smem;              // [2][BM*32]
  bf16* Bs = (bf16*)(smem + ABYTES);   // [2][BN*32]
  const int tid = threadIdx.x, wave = tid >> 6, lane = tid & 63;

  const int nwg = gridDim.x * gridDim.y;
  const int id = blockIdx.y * gridDim.x + blockIdx.x;
  const int cpx = nwg >> 3;
  const int swz = (id & 7) * cpx + (id >> 3);
  const int bm = (swz / gridDim.x) * BM, bn = (swz % gridDim.x) * BN;

  const int z = blockIdx.z;
  A  += (size_t)z * aZ;
  Bt += (size_t)z * bZ;
  C  += (size_t)z * cZ;
  const float* bp = BIAS ? bias + (size_t)z * biasZ : nullptr;

  const int trow = tid >> 2;
  const int stk = (((tid & 3) ^ ((trow >> 1) & 3)) << 3);  // pre-swizzled source col
  const int wr = (wave >> 1) * (BMF * 16), wc = (wave & 1) * (BNF * 16);
  const int r = lane & 15, kq = lane >> 4;
  const int swcol = ((kq ^ ((r >> 1) & 3)) << 3);          // swizzled ds_read col

  fv4 acc[BMF][BNF] = {};

  auto STAGE = [&](int buf, int k0){
#pragma unroll
    for (int s = 0; s < BM / 64; s++)
      gl_lds16(A + (size_t)(bm + s * 64 + trow) * lda + k0 + stk,
               (char*)As + buf * (BM * 64) + s * 4096 + wave * 1024, lane);
#pragma unroll
    for (int s = 0; s < BN / 64; s++)
      gl_lds16(Bt + (size_t)(bn + s * 64 + trow) * ldb + k0 + stk,
               (char*)Bs + buf * (BN * 64) + s * 4096 + wave * 1024, lane);
  };

  STAGE(0, 0);
  int cur = 0;
  for (int k0 = 0; k0 < K; k0 += 32){
    __syncthreads();
    if (k0 + 32 < K) STAGE(cur ^ 1, k0 + 32);

    bfv8 a[BMF], b[BNF];
#pragma unroll
    for (int i = 0; i < BMF; i++)
      a[i] = *(const bfv8*)&As[cur * (BM * 32) + (wr + i * 16 + r) * 32 + swcol];
#pragma unroll
    for (int j = 0; j < BNF; j++)
      b[j] = *(const bfv8*)&Bs[cur * (BN * 32) + (wc + j * 16 + r) * 32 + swcol];
#pragma unroll
    for (int i = 0; i < BMF; i++)
#pragma unroll
      for (int j = 0; j < BNF; j++)
        acc[i][j] = __builtin_amdgcn_mfma_f32_16x16x32_bf16(a[i], b[j], acc[i][j], 0, 0, 0);
    cur ^= 1;
  }

  const int rb = bm + wr + (lane >> 4) * 4;
  const int cb = bn + wc + (lane & 15);
  float ls[BMF][4], ld[BMF][4];
  if (LOG){
#pragma unroll
    for (int i = 0; i < BMF; i++)
#pragma unroll
      for (int q = 0; q < 4; q++){ ls[i][q] = 0.f; ld[i][q] = 0.f; }
  }
  const float* wsp = LOG ? w2s + (size_t)z * biasZ : nullptr;
  const float* wdp = LOG ? w2d + (size_t)z * biasZ : nullptr;

  if constexpr (sizeof(TC) == 2){
    // ---- LDS-bounced coalesced epilogue (bf16 out; BM*BN*2 <= ABYTES+BBYTES) ----
    __syncthreads();                 // all ds_reads done; safe to reuse smem
    bf16* Cs = (bf16*)smem;
    const int lr0 = wr + (lane >> 4) * 4;   // local row base
    const int lc0 = wc + (lane & 15);       // local col base
#pragma unroll
    for (int i = 0; i < BMF; i++)
#pragma unroll
      for (int j = 0; j < BNF; j++){
        int gn = cb + j * 16;
        float bv = BIAS ? bp[gn] : 0.f;
#pragma unroll
        for (int q = 0; q < 4; q++){
          float v = acc[i][j][q] + bv;
          if (ACT == 1) v = fmaxf(v, 0.f);
          if (ACT == 2) v = v > 0.f ? v : (__expf(v) - 1.f);
          if (LOG){ ls[i][q] += v * wsp[gn]; ld[i][q] += v * wdp[gn]; }
          Cs[(lr0 + i * 16 + q) * BN + lc0 + j * 16] = __float2bfloat16(v);
        }
      }
    if (LOG){
#pragma unroll
      for (int i = 0; i < BMF; i++)
#pragma unroll
        for (int q = 0; q < 4; q++){
          float a = ls[i][q], b = ld[i][q];
#pragma unroll
          for (int o = 1; o < 16; o <<= 1){ a += __shfl_xor(a, o); b += __shfl_xor(b, o); }
          if ((lane & 15) == 0){
            int gm = rb + i * 16 + q;
            atomicAdd(&s2[gm], a);
            atomicAdd(&d2[gm], b);
          }
        }
    }
    __syncthreads();                 // tile complete in LDS
    constexpr int NCH = (BM * BN) / (256 * 8);
#pragma unroll
    for (int c2 = 0; c2 < NCH; c2++){
      int idx = (tid + c2 * 256) * 8;
      int row = idx / BN, col = idx % BN;
      *(uint4*)&C[(size_t)(bm + row) * ldc + bn + col] = *(const uint4*)&Cs[idx];
    }
  } else {
    // ---- direct f32 epilogue (64B segments, acceptable) ----
#pragma unroll
    for (int i = 0; i < BMF; i++)
#pragma unroll
      for (int j = 0; j < BNF; j++){
        int gn = cb + j * 16;
        float bv = BIAS ? bp[gn] : 0.f;
#pragma unroll
        for (int q = 0; q < 4; q++){
          int gm = rb + i * 16 + q;
          float v = acc[i][j][q] + bv;
          if (RES) v += res[(size_t)gm * ldc + gn];
          if (ACT == 1) v = fmaxf(v, 0.f);
          if (ACT == 2) v = v > 0.f ? v : (__expf(v) - 1.f);
          if (LOG){ ls[i][q] += v * wsp[gn]; ld[i][q] += v * wdp[gn]; }
          stC_elem(&C[(size_t)gm * ldc + gn], v);
        }
      }
    if (LOG){
#pragma unroll
      for (int i = 0; i < BMF; i++)
#pragma unroll
        for (int q = 0; q < 4; q++){
          float a = ls[i][q], b = ld[i][q];
#pragma unroll
          for (int o = 1; o < 16; o <<= 1){ a += __shfl_xor(a, o); b += __shfl_xor(b, o); }
          if ((lane & 15) == 0){
            int gm = rb + i * 16 + q;
            atomicAdd(&s2[gm], a);
            atomicAdd(&d2[gm], b);
          }
        }
    }
  }
}

// ---------------- split-K reduces ----------------

__global__ void k_red2bf(const float* __restrict__ pA, const float* __restrict__ pB,
                         bf16* __restrict__ out){
  int t = (blockIdx.x * 256 + threadIdx.x) * 4;
  float4 a = *(const float4*)&pA[t];
  float4 b = *(const float4*)&pB[t];
  out[t]     = __float2bfloat16(a.x + b.x);
  out[t + 1] = __float2bfloat16(a.y + b.y);
  out[t + 2] = __float2bfloat16(a.z + b.z);
  out[t + 3] = __float2bfloat16(a.w + b.w);
}

__global__ void k_red4bf(const float* __restrict__ p, long st, bf16* __restrict__ out){
  int t = (blockIdx.x * 256 + threadIdx.x) * 4;
  float4 a = *(const float4*)&p[t];
  float4 b = *(const float4*)&p[st + t];
  float4 c = *(const float4*)&p[2 * st + t];
  float4 d = *(const float4*)&p[3 * st + t];
  out[t]     = __float2bfloat16(a.x + b.x + c.x + d.x);
  out[t + 1] = __float2bfloat16(a.y + b.y + c.y + d.y);
  out[t + 2] = __float2bfloat16(a.z + b.z + c.z + d.z);
  out[t + 3] = __float2bfloat16(a.w + b.w + c.w + d.w);
}

// ---------------- layernorm variants, pool ----------------

__device__ __forceinline__ void ln_body(float v[8], int lane,
                                        const float* g, const float* b,
                                        float* yf, bf16* ybf, size_t row){
  float s = 0;
#pragma unroll
  for (int j = 0; j < 8; j++) s += v[j];
  s = warp_sum(s);
  float mu = s * (1.0f / 512.0f);
  float var = 0;
#pragma unroll
  for (int j = 0; j < 8; j++){ float d = v[j] - mu; var += d * d; }
  var = warp_sum(var) * (1.0f / 512.0f);
  float inv = rsqrtf(var + 1e-5f);
#pragma unroll
  for (int j = 0; j < 8; j++){
    int c = lane + j * 64;
    float o = (v[j] - mu) * inv * g[c] + b[c];
    yf[row * 512 + c] = o;
    ybf[row * 512 + c] = __float2bfloat16(o);
  }
}

__global__ __launch_bounds__(256) void k_ln(const float* __restrict__ x,
                                            const float* __restrict__ g,
                                            const float* __restrict__ b,
                                            float* __restrict__ yf,
                                            bf16* __restrict__ ybf){
  int wid = (blockIdx.x * 256 + threadIdx.x) >> 6;
  int lane = threadIdx.x & 63;
  const float* xr = x + (size_t)wid * 512;
  float v[8];
#pragma unroll
  for (int j = 0; j < 8; j++) v[j] = xr[lane + j * 64];
  ln_body(v, lane, g, b, yf, ybf, (size_t)wid);
}

// fused split-K reduce + bias + residual + LN
__global__ __launch_bounds__(256) void k_ln_fr(const float* __restrict__ pA,
                                               const float* __restrict__ pB,
                                               const float* __restrict__ bias,
                                               const float* __restrict__ res,
                                               const float* __restrict__ g,
                                               const float* __restrict__ b,
                                               float* __restrict__ yf,
                                               bf16* __restrict__ ybf){
  int wid = (blockIdx.x * 256 + threadIdx.x) >> 6;
  int lane = threadIdx.x & 63;
  size_t base = (size_t)wid * 512;
  float v[8];
#pragma unroll
  for (int j = 0; j < 8; j++){
    int c = lane + j * 64;
    v[j] = pA[base + c] + pB[base + c] + bias[c] + res[base + c];
  }
  ln_body(v, lane, g, b, yf, ybf, (size_t)wid);
}

__global__ void k_pool(const float* __restrict__ h, float* __restrict__ out){
  int b = blockIdx.x;
  int c = threadIdx.x;   // 512 threads
  const float* hr = h + (size_t)b * 64 * 512;
  float m = -1e30f;
  for (int i = 0; i < 64; i++) m = fmaxf(m, hr[i * 512 + c]);
  out[(size_t)b * 512 + c] = m;
}

// ---------------- launcher ----------------

extern "C" void kernel_launch(void* const* d_in, const int* in_sizes, int n_in,
                              void* d_out, int out_size, void* d_ws, size_t ws_size,
                              hipStream_t stream){
  const float* x1    = (const float*)d_in[0];
  const int*   ei    = (const int*)d_in[1];
  const float* eattr = (const float*)d_in[2];
  const float* W1    = (const float*)d_in[4];
  const float* as1   = (const float*)d_in[5];
  const float* ad1   = (const float*)d_in[6];
  const float* We1   = (const float*)d_in[7];
  const float* ae1   = (const float*)d_in[8];
  const float* b1    = (const float*)d_in[9];
  const float* W2    = (const float*)d_in[10];
  const float* as2   = (const float*)d_in[11];
  const float* ad2   = (const float*)d_in[12];
  const float* We2   = (const float*)d_in[13];
  const float* ae2   = (const float*)d_in[14];
  const float* b2    = (const float*)d_in[15];
  const float* in_w  = (const float*)d_in[16];
  const float* in_b  = (const float*)d_in[17];
  const float* out_w = (const float*)d_in[18];
  const float* out_b = (const float*)d_in[19];
  const float* ln1g  = (const float*)d_in[20];
  const float* ln1b  = (const float*)d_in[21];
  const float* f1w   = (const float*)d_in[22];
  const float* f1b   = (const float*)d_in[23];
  const float* f2w   = (const float*)d_in[24];
  const float* f2b   = (const float*)d_in[25];
  const float* ln2g  = (const float*)d_in[26];
  const float* ln2b  = (const float*)d_in[27];

  const int* src0 = ei;
  const int* dst0 = ei + EE;

  char* p = (char*)d_ws;
  auto alloc = [&](size_t bytes) -> void* {
    void* r = p;
    p += (bytes + 255) & ~(size_t)255;
    return r;
  };
  // contiguous zero-init region: deg, cursor, s2, d2v, bvo, esum  (one memset)
  int*   deg     = (int*)alloc(NN * 4);
  int*   cursor  = (int*)alloc(NN * 4);
  float* s2      = (float*)alloc(NN * 4);
  float* d2v     = (float*)alloc(NN * 4);
  float* bvo     = (float*)alloc(2 * 512 * 4);
  float* esum    = (float*)alloc(NN * 11 * 4);
  size_t zbytes  = (char*)p - (char*)deg;

  float* lattr   = (float*)alloc(NN * 11 * 4);
  int*   offsets = (int*)alloc((NN + 1) * 4);
  int*   csr_src = (int*)alloc(ET * 4);
  int*   csr_eid = (int*)alloc(ET * 4);
  float* wse1    = (float*)alloc(930 * 4);
  float* wsd1    = (float*)alloc(930 * 4);
  float* wee1    = (float*)alloc(110 * 4);
  float* S1      = (float*)alloc(NN * 10 * 4);
  float* D1b     = (float*)alloc(NN * 10 * 4);
  bf16*  xaggp   = (bf16*)alloc((size_t)NN * 10 * 96 * 2);
  bf16*  W1t     = (bf16*)alloc((size_t)5120 * 96 * 2);
  bf16*  W2t     = (bf16*)alloc((size_t)512 * 5120 * 2);
  bf16*  f1wt    = (bf16*)alloc((size_t)2 * 2048 * 512 * 2);
  bf16*  f2wt    = (bf16*)alloc((size_t)2 * 512 * 2048 * 2);
  bf16*  Wvb     = (bf16*)alloc((size_t)2 * 512 * 512 * 2);
  bf16*  WoT     = (bf16*)alloc((size_t)2 * 512 * 512 * 2);
  bf16*  Wvot    = (bf16*)alloc((size_t)2 * 512 * 512 * 2);
  bf16*  h1      = (bf16*)alloc((size_t)NN * 5120 * 2);   // dead after xs2; reused below
  float* w2s     = (float*)alloc(5120 * 4);
  float* w2d     = (float*)alloc(5120 * 4);
  float* we2e    = (float*)alloc(16 * 4);
  bf16*  xs2     = (bf16*)alloc((size_t)NN * 512 * 2);
  float* h2f     = (float*)alloc((size_t)NN * 512 * 4);
  bf16*  hbf     = (bf16*)alloc((size_t)NN * 512 * 2);
  float* pbuf    = (float*)alloc((size_t)NN * 512 * 4 * 2);   // 2 split-K partials (always)
  long   pdz     = (long)NN * 512;
  // optional 2 more partials for split-K=4, if workspace allows
  size_t used2   = (char*)p - (char*)d_ws;
  bool   sk4     = (used2 + 2 * (size_t)NN * 512 * 4 + 256 <= ws_size);
  float* pbufHi  = sk4 ? (float*)alloc((size_t)NN * 512 * 4 * 2) : nullptr;
  (void)pbufHi;
  // aliases into dead h1 region (40 MB): tmp (8 MB) + fbuf (16 MB)
  float* tmp  = (float*)h1;
  bf16*  fbuf = (bf16*)((char*)h1 + (size_t)NN * 512 * 4);

  float* out_pool = (float*)d_out;
  float* alpha2   = out_pool + 64 * 512;

  hipMemsetAsync(deg, 0, zbytes, stream);

  // graph prep + folds (wave-parallel)
  k_deg_esum<<<EE / 256, 256, 0, stream>>>(dst0, eattr, deg, esum);
  k_loop_attr<<<NN / 256, 256, 0, stream>>>(esum, deg, lattr);
  k_scan<<<1, 256, 0, stream>>>(deg, offsets);
  k_scatter<<<(EE + NN) / 256, 256, 0, stream>>>(src0, dst0, offsets, cursor, csr_src, csr_eid);
  k_foldsw<<<1575, 256, 0, stream>>>(W1, as1, ad1, We1, ae1, W2, as2, ad2, We2, ae2,
                                     in_b, out_w, out_b,
                                     wse1, wsd1, wee1, w2s, w2d, we2e, bvo);
  k_logits1<<<160, 256, 0, stream>>>(x1, wse1, wsd1, S1, D1b);

  // weight preps
  k_t2b<<<dim3(160, 3, 1), dim3(32, 8), 0, stream>>>(W1, W1t, 93, 5120, 96, 0, 0);
  k_t2b<<<dim3(16, 160, 1), dim3(32, 8), 0, stream>>>(W2, W2t, 5120, 512, 5120, 0, 0);
  k_t2b<<<dim3(64, 16, 2), dim3(32, 8), 0, stream>>>(f1w, f1wt, 512, 2048, 512,
                                                     512L * 2048, 2048L * 512);
  k_t2b<<<dim3(16, 64, 2), dim3(32, 8), 0, stream>>>(f2w, f2wt, 2048, 512, 2048,
                                                     2048L * 512, 512L * 2048);
  k_prep_wv<<<2048, 256, 0, stream>>>(in_w, Wvb);
  k_t2b<<<dim3(16, 16, 2), dim3(32, 8), 0, stream>>>(out_w, WoT, 512, 512, 512,
                                                     262144, 262144);
  // Wvot[n][k] = sum_j WoT[n][j] * Wvb[k][j]  (= (Wv@Wo)^T, bf16)
  k_mm<4, 4, 0, false, false, false, bf16><<<dim3(4, 4, 2), 256, 0, stream>>>(
      WoT, Wvb, nullptr, nullptr, Wvot, 512, 512, 512, 512, 512,
      262144, 262144, 262144, 0, nullptr, nullptr, nullptr, nullptr);

  // GAT-1 aggregate, then per-head MFMA projection with fused logits2 epilogue
  k_gat1<<<NN / 4, 256, 0, stream>>>(offsets, csr_src, csr_eid, eattr, lattr,
                                     S1, D1b, wee1, x1, xaggp);
  // h1 = elu(xagg @ W1 + b1); epilogue: s2 += h1·w2s, d2v += h1·w2d
  k_mm<4, 4, 2, true, false, true, bf16><<<dim3(4, 32, 10), 256, 0, stream>>>(
      xaggp, W1t, b1, nullptr, h1, NN, 96, 960, 96, 5120, 96, 512L * 96, 512, 512,
      w2s, w2d, s2, d2v);

  // xs2 = h1 @ W2, split-K (4 if ws allows, else 2), 128x128 tiles
  if (sk4){
    k_mm<4, 4, 0, false, false, false, float><<<dim3(4, 32, 4), 256, 0, stream>>>(
        h1, W2t, nullptr, nullptr, pbuf, NN, 1280, 5120, 5120, 512,
        1280, 1280, pdz, 0, nullptr, nullptr, nullptr, nullptr);
    k_red4bf<<<2048, 256, 0, stream>>>(pbuf, pdz, xs2);
  } else {
    k_mm<4, 4, 0, false, false, false, float><<<dim3(4, 32, 2), 256, 0, stream>>>(
        h1, W2t, nullptr, nullptr, pbuf, NN, 2560, 5120, 5120, 512,
        2560, 2560, pdz, 0, nullptr, nullptr, nullptr, nullptr);
    k_red2bf<<<2048, 256, 0, stream>>>(pbuf, pbuf + pdz, xs2);
  }
  k_gat2<<<NN / 4, 256, 0, stream>>>(offsets, csr_src, csr_eid, eattr, lattr,
                                     s2, d2v, we2e, xs2, b2, h2f, hbf, alpha2);

  for (int i = 0; i < 2; i++){
    // tmp = h2 + h2 @ Wvo + bvo   (BN=64 tiles: 512 blocks = 2/CU)
    k_mm<2, 2, 0, true, true, false, float><<<dim3(8, 64, 1), 256, 0, stream>>>(
        hbf, Wvot + (size_t)i * 262144, bvo + i * 512, h2f, tmp,
        NN, 512, 512, 512, 512, 0, 0, 0, 0, nullptr, nullptr, nullptr, nullptr);
    k_ln<<<NN / 4, 256, 0, stream>>>(tmp, ln1g + i * 512, ln1b + i * 512, h2f, hbf);
    // fbuf = relu(h @ f1w + f1b): N=2048, K=512
    k_mm<4, 4, 1, true, false, false, bf16><<<dim3(16, 32, 1), 256, 0, stream>>>(
        hbf, f1wt + (size_t)i * 2048 * 512, f1b + i * 2048, nullptr, fbuf,
        NN, 512, 512, 512, 2048, 0, 0, 0, 0, nullptr, nullptr, nullptr, nullptr);
    // FFN2 split-K=2: partials (K-window 1024 each), reduce fused into LN
    k_mm<2, 4, 0, false, false, false, float><<<dim3(4, 64, 2), 256, 0, stream>>>(
        fbuf, f2wt + (size_t)i * 512 * 2048, nullptr, nullptr, pbuf,
        NN, 1024, 2048, 2048, 512, 1024, 1024, pdz, 0,
        nullptr, nullptr, nullptr, nullptr);
    k_ln_fr<<<NN / 4, 256, 0, stream>>>(pbuf, pbuf + pdz, f2b + i * 512, h2f,
                                        ln2g + i * 512, ln2b + i * 512, h2f, hbf);
  }

  k_pool<<<64, 512, 0, stream>>>(h2f, out_pool);
}